// Round 2
// baseline (534.508 us; speedup 1.0000x reference)
//
#include <hip/hip_runtime.h>
#include <hip/hip_bf16.h>

// GAT 2-layer: N=50000 nodes, E=800000 edges, DN=128, D=64, H=2 heads (layer0).
// All tensors are float32 (per reference dtypes); src/dst are int32.
// Strategy: build CSR by dst once per launch (deg -> scan -> scatter), then
// node-parallel gather aggregation (no atomics on hot path), fusing
// softmax + aggregate + bias + relu + layernorm per layer.

#define NN 50000
#define EE 800000

// ---------------- layer-0 GEMM: feat0 = h @ W0, plus el0/er0 dots ----------
// grid = NN blocks x 128 threads; one node per block; h row staged in LDS.
__global__ __launch_bounds__(128) void k_gemm0(
    const float* __restrict__ h, const float* __restrict__ W0,
    const float* __restrict__ al0, const float* __restrict__ ar0,
    float* __restrict__ feat0, float* __restrict__ el0, float* __restrict__ er0)
{
    int n = blockIdx.x, j = threadIdx.x;
    __shared__ float hs[128];
    hs[j] = h[n * 128 + j];
    __syncthreads();
    float acc = 0.f;
#pragma unroll 8
    for (int k = 0; k < 128; ++k) acc += hs[k] * W0[k * 128 + j];
    feat0[n * 128 + j] = acc;
    // j = head*64 + d; wave 0 = head 0, wave 1 = head 1 (wave=64)
    float a = acc * al0[j];
    float b = acc * ar0[j];
#pragma unroll
    for (int o = 32; o > 0; o >>= 1) { a += __shfl_down(a, o); b += __shfl_down(b, o); }
    if ((j & 63) == 0) { el0[n * 2 + (j >> 6)] = a; er0[n * 2 + (j >> 6)] = b; }
}

// ---------------- CSR build ----------------
__global__ void k_deg(const int* __restrict__ dst, int* __restrict__ deg)
{
    int e = blockIdx.x * blockDim.x + threadIdx.x;
    if (e < EE) atomicAdd(&deg[dst[e]], 1);
}

#define SCB 512
// inclusive scan per 512-chunk
__global__ __launch_bounds__(SCB) void k_scan1(
    const int* __restrict__ deg, int* __restrict__ incl, int* __restrict__ bsum)
{
    __shared__ int s[SCB];
    int t = threadIdx.x;
    int i = blockIdx.x * SCB + t;
    int v = (i < NN) ? deg[i] : 0;
    s[t] = v;
    __syncthreads();
    for (int o = 1; o < SCB; o <<= 1) {
        int u = (t >= o) ? s[t - o] : 0;
        __syncthreads();
        s[t] += u;
        __syncthreads();
    }
    incl[i] = s[t];
    if (t == SCB - 1) bsum[blockIdx.x] = s[t];
}

__global__ void k_scan2(int* __restrict__ bsum, int nb)
{
    if (threadIdx.x == 0) {
        int run = 0;
        for (int i = 0; i < nb; ++i) { int t = bsum[i]; bsum[i] = run; run += t; }
    }
}

// finalize offsets (exclusive, size N+1) and init scatter cursors
__global__ void k_scan3(const int* __restrict__ incl, const int* __restrict__ bsum,
                        const int* __restrict__ deg, int* __restrict__ off,
                        int* __restrict__ cur)
{
    int i = blockIdx.x * blockDim.x + threadIdx.x;
    if (i >= NN) return;
    int v = incl[i] + bsum[i >> 9];
    off[i + 1] = v;
    cur[i] = v - deg[i];
    if (i == 0) off[0] = 0;
}

__global__ void k_scatter(const int* __restrict__ src, const int* __restrict__ dst,
                          int* __restrict__ cur, int* __restrict__ ssort)
{
    int e = blockIdx.x * blockDim.x + threadIdx.x;
    if (e < EE) {
        int p = atomicAdd(&cur[dst[e]], 1);
        ssort[p] = src[e];
    }
}

// ------------- layer-0 aggregation + bias + relu + LN -> x -----------------
// grid = NN blocks x 128 threads; wave h handles head h; lane = feature d.
__global__ __launch_bounds__(128) void k_agg0(
    const int* __restrict__ off, const int* __restrict__ ssort,
    const float* __restrict__ el0, const float* __restrict__ er0,
    const float* __restrict__ feat0, const float* __restrict__ b0,
    const float* __restrict__ g0, const float* __restrict__ be0,
    float* __restrict__ x)
{
    int n = blockIdx.x, tid = threadIdx.x;
    int hh = tid >> 6, lane = tid & 63;
    int beg = off[n], end = off[n + 1];
    float ern = er0[n * 2 + hh];
    // pass 1: segment max (lanes parallel over edges)
    float mx = -1e30f;
    for (int e = beg + lane; e < end; e += 64) {
        int s = ssort[e];
        float v = el0[s * 2 + hh] + ern;
        v = v > 0.f ? v : 0.2f * v;
        mx = fmaxf(mx, v);
    }
#pragma unroll
    for (int o = 32; o > 0; o >>= 1) mx = fmaxf(mx, __shfl_down(mx, o));
    mx = __shfl(mx, 0);
    // pass 2: accumulate sum(p) and sum(p*feat) (lanes parallel over feature d)
    float acc = 0.f, den = 0.f;
    for (int e = beg; e < end; ++e) {
        int s = ssort[e];
        float v = el0[s * 2 + hh] + ern;   // same addr per wave -> broadcast
        v = v > 0.f ? v : 0.2f * v;
        float p = __expf(v - mx);
        den += p;
        acc += p * feat0[s * 128 + hh * 64 + lane];
    }
    float val = (end > beg) ? acc / den : 0.f;
    val += b0[tid];
    val = fmaxf(val, 0.f);                 // relu
    // LN over 128 dims (cross-wave via LDS)
    float s1 = val, s2 = val * val;
#pragma unroll
    for (int o = 32; o > 0; o >>= 1) { s1 += __shfl_down(s1, o); s2 += __shfl_down(s2, o); }
    __shared__ float sh[4];
    if (lane == 0) { sh[hh] = s1; sh[2 + hh] = s2; }
    __syncthreads();
    float tot = sh[0] + sh[1], tot2 = sh[2] + sh[3];
    float mu = tot * (1.f / 128.f);
    float var = tot2 * (1.f / 128.f) - mu * mu;
    float rs = rsqrtf(var + 1e-5f);
    x[n * 128 + tid] = (val - mu) * rs * g0[tid] + be0[tid];
}

// ------------- layer-1 GEMM: feat1 = x @ W1, plus el1/er1 ------------------
// grid = NN/4 blocks x 256 threads; one node per wave.
__global__ __launch_bounds__(256) void k_gemm1(
    const float* __restrict__ x, const float* __restrict__ W1,
    const float* __restrict__ al1, const float* __restrict__ ar1,
    float* __restrict__ feat1, float* __restrict__ el1, float* __restrict__ er1)
{
    int w = threadIdx.x >> 6, lane = threadIdx.x & 63;
    int n = blockIdx.x * 4 + w;
    __shared__ float xs[4][128];
    xs[w][lane] = x[n * 128 + lane];
    xs[w][lane + 64] = x[n * 128 + 64 + lane];
    __syncthreads();
    float acc = 0.f;
#pragma unroll 8
    for (int k = 0; k < 128; ++k) acc += xs[w][k] * W1[k * 64 + lane];
    feat1[n * 64 + lane] = acc;
    float a = acc * al1[lane];
    float b = acc * ar1[lane];
#pragma unroll
    for (int o = 32; o > 0; o >>= 1) { a += __shfl_down(a, o); b += __shfl_down(b, o); }
    if (lane == 0) { el1[n] = a; er1[n] = b; }
}

// ------------- layer-1 aggregation + bias + LN -> out (f32) ----------------
// grid = NN/4 blocks x 256 threads; one node per wave (H=1, D=64).
__global__ __launch_bounds__(256) void k_agg1(
    const int* __restrict__ off, const int* __restrict__ ssort,
    const float* __restrict__ el1, const float* __restrict__ er1,
    const float* __restrict__ feat1, const float* __restrict__ b1,
    const float* __restrict__ g1, const float* __restrict__ be1,
    float* __restrict__ out)
{
    int w = threadIdx.x >> 6, lane = threadIdx.x & 63;
    int n = blockIdx.x * 4 + w;
    int beg = off[n], end = off[n + 1];
    float ern = er1[n];
    float mx = -1e30f;
    for (int e = beg + lane; e < end; e += 64) {
        int s = ssort[e];
        float v = el1[s] + ern;
        v = v > 0.f ? v : 0.2f * v;
        mx = fmaxf(mx, v);
    }
#pragma unroll
    for (int o = 32; o > 0; o >>= 1) mx = fmaxf(mx, __shfl_down(mx, o));
    mx = __shfl(mx, 0);
    float acc = 0.f, den = 0.f;
    for (int e = beg; e < end; ++e) {
        int s = ssort[e];
        float v = el1[s] + ern;
        v = v > 0.f ? v : 0.2f * v;
        float p = __expf(v - mx);
        den += p;
        acc += p * feat1[s * 64 + lane];
    }
    float val = (end > beg) ? acc / den : 0.f;
    val += b1[lane];                       // no relu in layer 1; mean over 1 head = identity
    float s1 = val, s2 = val * val;
#pragma unroll
    for (int o = 32; o > 0; o >>= 1) { s1 += __shfl_down(s1, o); s2 += __shfl_down(s2, o); }
    s1 = __shfl(s1, 0); s2 = __shfl(s2, 0);
    float mu = s1 * (1.f / 64.f);
    float var = s2 * (1.f / 64.f) - mu * mu;
    float rs = rsqrtf(var + 1e-5f);
    out[n * 64 + lane] = (val - mu) * rs * g1[lane] + be1[lane];
}

extern "C" void kernel_launch(void* const* d_in, const int* in_sizes, int n_in,
                              void* d_out, int out_size, void* d_ws, size_t ws_size,
                              hipStream_t stream)
{
    const float* h   = (const float*)d_in[0];
    const float* W0  = (const float*)d_in[1];
    const float* al0 = (const float*)d_in[2];
    const float* ar0 = (const float*)d_in[3];
    const float* b0  = (const float*)d_in[4];
    const float* W1  = (const float*)d_in[5];
    const float* al1 = (const float*)d_in[6];
    const float* ar1 = (const float*)d_in[7];
    const float* b1  = (const float*)d_in[8];
    const float* g0  = (const float*)d_in[9];
    const float* be0 = (const float*)d_in[10];
    const float* g1  = (const float*)d_in[11];
    const float* be1 = (const float*)d_in[12];
    const int*   src = (const int*)d_in[13];
    const int*   dst = (const int*)d_in[14];
    float* out = (float*)d_out;

    // workspace carve-out (256B aligned); total ~70 MB
    char* p = (char*)d_ws;
    auto alloc = [&](size_t bytes) -> char* {
        char* r = p;
        p += (bytes + 255) & ~(size_t)255;
        return r;
    };
    const int NB1 = (NN + SCB - 1) / SCB;  // 98 scan blocks
    float* feat0 = (float*)alloc((size_t)NN * 128 * sizeof(float));
    float* el0   = (float*)alloc((size_t)NN * 2 * sizeof(float));
    float* er0   = (float*)alloc((size_t)NN * 2 * sizeof(float));
    float* x     = (float*)alloc((size_t)NN * 128 * sizeof(float));
    float* feat1 = (float*)alloc((size_t)NN * 64 * sizeof(float));
    float* el1   = (float*)alloc((size_t)NN * sizeof(float));
    float* er1   = (float*)alloc((size_t)NN * sizeof(float));
    int*   deg   = (int*)alloc((size_t)NN * sizeof(int));
    int*   incl  = (int*)alloc((size_t)NB1 * SCB * sizeof(int));
    int*   bsum  = (int*)alloc((size_t)NB1 * sizeof(int));
    int*   off   = (int*)alloc((size_t)(NN + 1) * sizeof(int));
    int*   cur   = (int*)alloc((size_t)NN * sizeof(int));
    int*   ssort = (int*)alloc((size_t)EE * sizeof(int));

    hipMemsetAsync(deg, 0, (size_t)NN * sizeof(int), stream);

    k_gemm0<<<NN, 128, 0, stream>>>(h, W0, al0, ar0, feat0, el0, er0);
    k_deg<<<(EE + 255) / 256, 256, 0, stream>>>(dst, deg);
    k_scan1<<<NB1, SCB, 0, stream>>>(deg, incl, bsum);
    k_scan2<<<1, 64, 0, stream>>>(bsum, NB1);
    k_scan3<<<(NN + 255) / 256, 256, 0, stream>>>(incl, bsum, deg, off, cur);
    k_scatter<<<(EE + 255) / 256, 256, 0, stream>>>(src, dst, cur, ssort);
    k_agg0<<<NN, 128, 0, stream>>>(off, ssort, el0, er0, feat0, b0, g0, be0, x);
    k_gemm1<<<NN / 4, 256, 0, stream>>>(x, W1, al1, ar1, feat1, el1, er1);
    k_agg1<<<NN / 4, 256, 0, stream>>>(off, ssort, el1, er1, feat1, b1, g1, be1, out);
}

// Round 3
// 430.290 us; speedup vs baseline: 1.2422x; 1.2422x over previous
//
#include <hip/hip_runtime.h>
#include <hip/hip_bf16.h>

// GAT 2-layer: N=50000, E=800000, DN=128, D=64, H=2 (layer0). All f32.
// CSR-by-dst build, then node-parallel fused softmax/aggregate/LN.
// R3: no-max softmax (|e|<=~8, exp safe in f32), shfl-broadcast chunked
// aggregation with 4x-unrolled independent gathers, W-amortized GEMMs,
// parallel block-sum scan.

#define NN 50000
#define EE 800000

// ---- layer-0 GEMM: feat0 = h @ W0 (+ el0/er0 dots). 8 nodes per block. ----
// 256 thr: c = tid&31 -> cols 4c..4c+3 ; ng = tid>>5 -> node n0+ng.
__global__ __launch_bounds__(256) void k_gemm0(
    const float* __restrict__ h, const float* __restrict__ W0,
    const float* __restrict__ al0, const float* __restrict__ ar0,
    float* __restrict__ feat0, float* __restrict__ el0, float* __restrict__ er0)
{
    int tid = threadIdx.x;
    int c = tid & 31, ng = tid >> 5;
    int n = blockIdx.x * 8 + ng;
    __shared__ float hs[8][128];
    // stage h rows: thread loads float4 (coalesced per 32-lane group)
    const float4* h4 = (const float4*)(h + (size_t)n * 128);
    ((float4*)hs[ng])[c] = h4[c];
    __syncthreads();
    const float4* W4 = (const float4*)W0;      // [128][32] float4
    float4 a = {0.f, 0.f, 0.f, 0.f};
#pragma unroll 8
    for (int k = 0; k < 128; ++k) {
        float hk = hs[ng][k];
        float4 w = W4[k * 32 + c];
        a.x += hk * w.x; a.y += hk * w.y; a.z += hk * w.z; a.w += hk * w.w;
    }
    ((float4*)(feat0 + (size_t)n * 128))[c] = a;
    float4 al = ((const float4*)al0)[c];
    float4 ar = ((const float4*)ar0)[c];
    float pl = a.x * al.x + a.y * al.y + a.z * al.z + a.w * al.w;
    float pr = a.x * ar.x + a.y * ar.y + a.z * ar.z + a.w * ar.w;
    // cols 4c: c<16 -> head0, c>=16 -> head1; reduce within 16-lane halves
#pragma unroll
    for (int o = 8; o > 0; o >>= 1) { pl += __shfl_down(pl, o, 16); pr += __shfl_down(pr, o, 16); }
    if ((tid & 15) == 0) {
        int head = (tid >> 4) & 1;
        el0[n * 2 + head] = pl;
        er0[n * 2 + head] = pr;
    }
}

// ---------------- CSR build ----------------
__global__ void k_deg(const int* __restrict__ dst, int* __restrict__ deg)
{
    int e = blockIdx.x * blockDim.x + threadIdx.x;
    if (e < EE) atomicAdd(&deg[dst[e]], 1);
}

#define SCB 512
__global__ __launch_bounds__(SCB) void k_scan1(
    const int* __restrict__ deg, int* __restrict__ incl, int* __restrict__ bsum)
{
    __shared__ int s[SCB];
    int t = threadIdx.x;
    int i = blockIdx.x * SCB + t;
    int v = (i < NN) ? deg[i] : 0;
    s[t] = v;
    __syncthreads();
    for (int o = 1; o < SCB; o <<= 1) {
        int u = (t >= o) ? s[t - o] : 0;
        __syncthreads();
        s[t] += u;
        __syncthreads();
    }
    incl[i] = s[t];
    if (t == SCB - 1) bsum[blockIdx.x] = s[t];
}

// parallel exclusive scan of block sums (nb <= 128), one block
__global__ __launch_bounds__(128) void k_scan2(int* __restrict__ bsum, int nb)
{
    __shared__ int s[128];
    int t = threadIdx.x;
    int v = (t < nb) ? bsum[t] : 0;
    s[t] = v;
    __syncthreads();
    for (int o = 1; o < 128; o <<= 1) {
        int u = (t >= o) ? s[t - o] : 0;
        __syncthreads();
        s[t] += u;
        __syncthreads();
    }
    if (t < nb) bsum[t] = s[t] - v;   // exclusive
}

__global__ void k_scan3(const int* __restrict__ incl, const int* __restrict__ bsum,
                        const int* __restrict__ deg, int* __restrict__ off,
                        int* __restrict__ cur)
{
    int i = blockIdx.x * blockDim.x + threadIdx.x;
    if (i >= NN) return;
    int v = incl[i] + bsum[i >> 9];
    off[i + 1] = v;
    cur[i] = v - deg[i];
    if (i == 0) off[0] = 0;
}

__global__ void k_scatter(const int* __restrict__ src, const int* __restrict__ dst,
                          int* __restrict__ cur, int* __restrict__ ssort)
{
    int e = blockIdx.x * blockDim.x + threadIdx.x;
    if (e < EE) {
        int p = atomicAdd(&cur[dst[e]], 1);
        ssort[p] = src[e];
    }
}

// ------- layer-0 aggregation + bias + relu + LN -> x. 1 node / 128 thr. ----
// wave hh = head hh; lane = feature d. No-max softmax; shfl-broadcast chunks.
__global__ __launch_bounds__(128) void k_agg0(
    const int* __restrict__ off, const int* __restrict__ ssort,
    const float* __restrict__ el0, const float* __restrict__ er0,
    const float* __restrict__ feat0, const float* __restrict__ b0,
    const float* __restrict__ g0, const float* __restrict__ be0,
    float* __restrict__ x)
{
    int n = blockIdx.x, tid = threadIdx.x;
    int hh = tid >> 6, lane = tid & 63;
    int beg = off[n], end = off[n + 1];
    float ern = er0[n * 2 + hh];
    float acc = 0.f, den = 0.f;
    const float* fbase = feat0 + hh * 64 + lane;
    for (int cb = beg; cb < end; cb += 64) {
        // edge-parallel precompute of (s, p) into registers
        int s_reg = 0; float p_reg = 0.f;
        int e = cb + lane;
        if (e < end) {
            s_reg = ssort[e];
            float v = el0[s_reg * 2 + hh] + ern;
            v = v > 0.f ? v : 0.2f * v;
            p_reg = __expf(v);
        }
        den += p_reg;
        int m = end - cb; if (m > 64) m = 64;
        // wave-broadcast accumulate, 4 independent gathers per iter
        int i = 0;
        for (; i + 4 <= m; i += 4) {
            int s0 = __shfl(s_reg, i),     s1 = __shfl(s_reg, i + 1);
            int s2 = __shfl(s_reg, i + 2), s3 = __shfl(s_reg, i + 3);
            float q0 = __shfl(p_reg, i),     q1 = __shfl(p_reg, i + 1);
            float q2 = __shfl(p_reg, i + 2), q3 = __shfl(p_reg, i + 3);
            float f0 = fbase[(size_t)s0 * 128];
            float f1 = fbase[(size_t)s1 * 128];
            float f2 = fbase[(size_t)s2 * 128];
            float f3 = fbase[(size_t)s3 * 128];
            acc += q0 * f0 + q1 * f1 + q2 * f2 + q3 * f3;
        }
        for (; i < m; ++i) {
            int s0 = __shfl(s_reg, i);
            float q0 = __shfl(p_reg, i);
            acc += q0 * fbase[(size_t)s0 * 128];
        }
    }
    // reduce den across the wave
#pragma unroll
    for (int o = 32; o > 0; o >>= 1) den += __shfl_down(den, o);
    den = __shfl(den, 0);
    float val = (end > beg) ? acc / den : 0.f;
    val += b0[tid];
    val = fmaxf(val, 0.f);                 // relu
    // LN over 128 dims (cross-wave via LDS)
    float s1 = val, s2 = val * val;
#pragma unroll
    for (int o = 32; o > 0; o >>= 1) { s1 += __shfl_down(s1, o); s2 += __shfl_down(s2, o); }
    __shared__ float sh[4];
    if (lane == 0) { sh[hh] = s1; sh[2 + hh] = s2; }
    __syncthreads();
    float tot = sh[0] + sh[1], tot2 = sh[2] + sh[3];
    float mu = tot * (1.f / 128.f);
    float var = tot2 * (1.f / 128.f) - mu * mu;
    float rs = rsqrtf(var + 1e-5f);
    x[n * 128 + tid] = (val - mu) * rs * g0[tid] + be0[tid];
}

// ---- layer-1 GEMM: feat1 = x @ W1 (+ el1/er1). 16 nodes per block. -------
// 256 thr: c = tid&15 -> cols 4c..4c+3 ; ng = tid>>4 -> node n0+ng.
__global__ __launch_bounds__(256) void k_gemm1(
    const float* __restrict__ x, const float* __restrict__ W1,
    const float* __restrict__ al1, const float* __restrict__ ar1,
    float* __restrict__ feat1, float* __restrict__ el1, float* __restrict__ er1)
{
    int tid = threadIdx.x;
    int c = tid & 15, ng = tid >> 4;
    int n0 = blockIdx.x * 16;
    int n = n0 + ng;
    __shared__ float hs[16 * 128];
    const float4* x4 = (const float4*)(x + (size_t)n0 * 128);
    ((float4*)hs)[tid] = x4[tid];
    ((float4*)hs)[tid + 256] = x4[tid + 256];
    __syncthreads();
    const float4* W4 = (const float4*)W1;      // [128][16] float4
    float4 a = {0.f, 0.f, 0.f, 0.f};
#pragma unroll 8
    for (int k = 0; k < 128; ++k) {
        float hk = hs[ng * 128 + k];
        float4 w = W4[k * 16 + c];
        a.x += hk * w.x; a.y += hk * w.y; a.z += hk * w.z; a.w += hk * w.w;
    }
    ((float4*)(feat1 + (size_t)n * 64))[c] = a;
    float4 al = ((const float4*)al1)[c];
    float4 ar = ((const float4*)ar1)[c];
    float pl = a.x * al.x + a.y * al.y + a.z * al.z + a.w * al.w;
    float pr = a.x * ar.x + a.y * ar.y + a.z * ar.z + a.w * ar.w;
#pragma unroll
    for (int o = 8; o > 0; o >>= 1) { pl += __shfl_down(pl, o, 16); pr += __shfl_down(pr, o, 16); }
    if ((tid & 15) == 0) { el1[n] = pl; er1[n] = pr; }
}

// ------- layer-1 aggregation + bias + LN -> out. 1 node per wave. ---------
__global__ __launch_bounds__(256) void k_agg1(
    const int* __restrict__ off, const int* __restrict__ ssort,
    const float* __restrict__ el1, const float* __restrict__ er1,
    const float* __restrict__ feat1, const float* __restrict__ b1,
    const float* __restrict__ g1, const float* __restrict__ be1,
    float* __restrict__ out)
{
    int w = threadIdx.x >> 6, lane = threadIdx.x & 63;
    int n = blockIdx.x * 4 + w;
    int beg = off[n], end = off[n + 1];
    float ern = er1[n];
    float acc = 0.f, den = 0.f;
    const float* fbase = feat1 + lane;
    for (int cb = beg; cb < end; cb += 64) {
        int s_reg = 0; float p_reg = 0.f;
        int e = cb + lane;
        if (e < end) {
            s_reg = ssort[e];
            float v = el1[s_reg] + ern;
            v = v > 0.f ? v : 0.2f * v;
            p_reg = __expf(v);
        }
        den += p_reg;
        int m = end - cb; if (m > 64) m = 64;
        int i = 0;
        for (; i + 4 <= m; i += 4) {
            int s0 = __shfl(s_reg, i),     s1 = __shfl(s_reg, i + 1);
            int s2 = __shfl(s_reg, i + 2), s3 = __shfl(s_reg, i + 3);
            float q0 = __shfl(p_reg, i),     q1 = __shfl(p_reg, i + 1);
            float q2 = __shfl(p_reg, i + 2), q3 = __shfl(p_reg, i + 3);
            float f0 = fbase[(size_t)s0 * 64];
            float f1 = fbase[(size_t)s1 * 64];
            float f2 = fbase[(size_t)s2 * 64];
            float f3 = fbase[(size_t)s3 * 64];
            acc += q0 * f0 + q1 * f1 + q2 * f2 + q3 * f3;
        }
        for (; i < m; ++i) {
            int s0 = __shfl(s_reg, i);
            float q0 = __shfl(p_reg, i);
            acc += q0 * fbase[(size_t)s0 * 64];
        }
    }
#pragma unroll
    for (int o = 32; o > 0; o >>= 1) den += __shfl_down(den, o);
    den = __shfl(den, 0);
    float val = (end > beg) ? acc / den : 0.f;
    val += b1[lane];                       // no relu; mean over 1 head = identity
    float s1 = val, s2 = val * val;
#pragma unroll
    for (int o = 32; o > 0; o >>= 1) { s1 += __shfl_down(s1, o); s2 += __shfl_down(s2, o); }
    s1 = __shfl(s1, 0); s2 = __shfl(s2, 0);
    float mu = s1 * (1.f / 64.f);
    float var = s2 * (1.f / 64.f) - mu * mu;
    float rs = rsqrtf(var + 1e-5f);
    out[n * 64 + lane] = (val - mu) * rs * g1[lane] + be1[lane];
}

extern "C" void kernel_launch(void* const* d_in, const int* in_sizes, int n_in,
                              void* d_out, int out_size, void* d_ws, size_t ws_size,
                              hipStream_t stream)
{
    const float* h   = (const float*)d_in[0];
    const float* W0  = (const float*)d_in[1];
    const float* al0 = (const float*)d_in[2];
    const float* ar0 = (const float*)d_in[3];
    const float* b0  = (const float*)d_in[4];
    const float* W1  = (const float*)d_in[5];
    const float* al1 = (const float*)d_in[6];
    const float* ar1 = (const float*)d_in[7];
    const float* b1  = (const float*)d_in[8];
    const float* g0  = (const float*)d_in[9];
    const float* be0 = (const float*)d_in[10];
    const float* g1  = (const float*)d_in[11];
    const float* be1 = (const float*)d_in[12];
    const int*   src = (const int*)d_in[13];
    const int*   dst = (const int*)d_in[14];
    float* out = (float*)d_out;

    char* p = (char*)d_ws;
    auto alloc = [&](size_t bytes) -> char* {
        char* r = p;
        p += (bytes + 255) & ~(size_t)255;
        return r;
    };
    const int NB1 = (NN + SCB - 1) / SCB;  // 98 scan blocks
    float* feat0 = (float*)alloc((size_t)NN * 128 * sizeof(float));
    float* el0   = (float*)alloc((size_t)NN * 2 * sizeof(float));
    float* er0   = (float*)alloc((size_t)NN * 2 * sizeof(float));
    float* x     = (float*)alloc((size_t)NN * 128 * sizeof(float));
    float* feat1 = (float*)alloc((size_t)NN * 64 * sizeof(float));
    float* el1   = (float*)alloc((size_t)NN * sizeof(float));
    float* er1   = (float*)alloc((size_t)NN * sizeof(float));
    int*   deg   = (int*)alloc((size_t)NN * sizeof(int));
    int*   incl  = (int*)alloc((size_t)NB1 * SCB * sizeof(int));
    int*   bsum  = (int*)alloc((size_t)NB1 * sizeof(int));
    int*   off   = (int*)alloc((size_t)(NN + 1) * sizeof(int));
    int*   cur   = (int*)alloc((size_t)NN * sizeof(int));
    int*   ssort = (int*)alloc((size_t)EE * sizeof(int));

    hipMemsetAsync(deg, 0, (size_t)NN * sizeof(int), stream);

    k_gemm0<<<NN / 8, 256, 0, stream>>>(h, W0, al0, ar0, feat0, el0, er0);
    k_deg<<<(EE + 255) / 256, 256, 0, stream>>>(dst, deg);
    k_scan1<<<NB1, SCB, 0, stream>>>(deg, incl, bsum);
    k_scan2<<<1, 128, 0, stream>>>(bsum, NB1);
    k_scan3<<<(NN + 255) / 256, 256, 0, stream>>>(incl, bsum, deg, off, cur);
    k_scatter<<<(EE + 255) / 256, 256, 0, stream>>>(src, dst, cur, ssort);
    k_agg0<<<NN, 128, 0, stream>>>(off, ssort, el0, er0, feat0, b0, g0, be0, x);
    k_gemm1<<<NN / 16, 256, 0, stream>>>(x, W1, al1, ar1, feat1, el1, er1);
    k_agg1<<<NN / 4, 256, 0, stream>>>(off, ssort, el1, er1, feat1, b1, g1, be1, out);
}

// Round 4
// 338.683 us; speedup vs baseline: 1.5782x; 1.2705x over previous
//
#include <hip/hip_runtime.h>
#include <hip/hip_bf16.h>

// GAT 2-layer: N=50000, E=800000, DN=128, D=64, H=2 (layer0). All f32.
// R4: register-blocked GEMMs (8 resp. 4 nodes/thread -> 32 FMA per W float4),
// float4 edge gathers in agg kernels (1KB per gather instruction, 4 edges in
// flight), no-max softmax, CSR-by-dst build.

#define NN 50000
#define EE 800000

// ---- layer-0 GEMM: feat0 = h @ W0 (+ el0/er0). 64 nodes/block, 8/thread. --
// c = tid&31 -> float4 col (cols 4c..4c+3); g = tid>>5 -> nodes 8g..8g+7.
__global__ __launch_bounds__(256) void k_gemm0(
    const float* __restrict__ h, const float* __restrict__ W0,
    const float* __restrict__ al0, const float* __restrict__ ar0,
    float* __restrict__ feat0, float* __restrict__ el0, float* __restrict__ er0)
{
    int tid = threadIdx.x;
    int c = tid & 31, g = tid >> 5;
    int n0 = blockIdx.x * 64;
    __shared__ float hs[64][128];
    // stage 64 h rows (zero-padded past NN): 2048 float4, 8 per thread
#pragma unroll
    for (int r = 0; r < 8; ++r) {
        int f = tid + 256 * r;
        int node = f >> 5, kc = f & 31;
        int n = n0 + node;
        float4 v = {0.f, 0.f, 0.f, 0.f};
        if (n < NN) v = ((const float4*)h)[(size_t)n * 32 + kc];
        ((float4*)hs[node])[kc] = v;
    }
    __syncthreads();
    const float4* W4 = (const float4*)W0;   // [128][32] float4
    float4 acc[8] = {};
    for (int k = 0; k < 128; k += 4) {
        float4 w0 = W4[(k + 0) * 32 + c];
        float4 w1 = W4[(k + 1) * 32 + c];
        float4 w2 = W4[(k + 2) * 32 + c];
        float4 w3 = W4[(k + 3) * 32 + c];
#pragma unroll
        for (int i = 0; i < 8; ++i) {
            float4 hv = *(const float4*)&hs[g * 8 + i][k];   // broadcast (2 addrs/wave)
            acc[i].x += hv.x * w0.x + hv.y * w1.x + hv.z * w2.x + hv.w * w3.x;
            acc[i].y += hv.x * w0.y + hv.y * w1.y + hv.z * w2.y + hv.w * w3.y;
            acc[i].z += hv.x * w0.z + hv.y * w1.z + hv.z * w2.z + hv.w * w3.z;
            acc[i].w += hv.x * w0.w + hv.y * w1.w + hv.z * w2.w + hv.w * w3.w;
        }
    }
    float4 al4 = ((const float4*)al0)[c];
    float4 ar4 = ((const float4*)ar0)[c];
    int head = (tid >> 4) & 1;               // c<16 -> head0, c>=16 -> head1
#pragma unroll
    for (int i = 0; i < 8; ++i) {
        int n = n0 + g * 8 + i;
        if (n < NN) ((float4*)(feat0 + (size_t)n * 128))[c] = acc[i];
        float pl = acc[i].x * al4.x + acc[i].y * al4.y + acc[i].z * al4.z + acc[i].w * al4.w;
        float pr = acc[i].x * ar4.x + acc[i].y * ar4.y + acc[i].z * ar4.z + acc[i].w * ar4.w;
#pragma unroll
        for (int o = 8; o > 0; o >>= 1) { pl += __shfl_down(pl, o, 16); pr += __shfl_down(pr, o, 16); }
        if ((tid & 15) == 0 && n < NN) { el0[n * 2 + head] = pl; er0[n * 2 + head] = pr; }
    }
}

// ---------------- CSR build ----------------
__global__ void k_deg(const int* __restrict__ dst, int* __restrict__ deg)
{
    int e = blockIdx.x * blockDim.x + threadIdx.x;
    if (e < EE) atomicAdd(&deg[dst[e]], 1);
}

#define SCB 512
__global__ __launch_bounds__(SCB) void k_scan1(
    const int* __restrict__ deg, int* __restrict__ incl, int* __restrict__ bsum)
{
    __shared__ int s[SCB];
    int t = threadIdx.x;
    int i = blockIdx.x * SCB + t;
    int v = (i < NN) ? deg[i] : 0;
    s[t] = v;
    __syncthreads();
    for (int o = 1; o < SCB; o <<= 1) {
        int u = (t >= o) ? s[t - o] : 0;
        __syncthreads();
        s[t] += u;
        __syncthreads();
    }
    incl[i] = s[t];
    if (t == SCB - 1) bsum[blockIdx.x] = s[t];
}

__global__ __launch_bounds__(128) void k_scan2(int* __restrict__ bsum, int nb)
{
    __shared__ int s[128];
    int t = threadIdx.x;
    int v = (t < nb) ? bsum[t] : 0;
    s[t] = v;
    __syncthreads();
    for (int o = 1; o < 128; o <<= 1) {
        int u = (t >= o) ? s[t - o] : 0;
        __syncthreads();
        s[t] += u;
        __syncthreads();
    }
    if (t < nb) bsum[t] = s[t] - v;   // exclusive
}

__global__ void k_scan3(const int* __restrict__ incl, const int* __restrict__ bsum,
                        const int* __restrict__ deg, int* __restrict__ off,
                        int* __restrict__ cur)
{
    int i = blockIdx.x * blockDim.x + threadIdx.x;
    if (i >= NN) return;
    int v = incl[i] + bsum[i >> 9];
    off[i + 1] = v;
    cur[i] = v - deg[i];
    if (i == 0) off[0] = 0;
}

__global__ void k_scatter(const int* __restrict__ src, const int* __restrict__ dst,
                          int* __restrict__ cur, int* __restrict__ ssort)
{
    int e = blockIdx.x * blockDim.x + threadIdx.x;
    if (e < EE) {
        int p = atomicAdd(&cur[dst[e]], 1);
        ssort[p] = src[e];
    }
}

// ------- layer-0 agg + bias + relu + LN -> x. 1 node/128 thr, wave=head. ---
// lane: grp = lane>>4 (edge subgroup), c = lane&15 (float4 col).
__global__ __launch_bounds__(128) void k_agg0(
    const int* __restrict__ off, const int* __restrict__ ssort,
    const float* __restrict__ el0, const float* __restrict__ er0,
    const float* __restrict__ feat0, const float* __restrict__ b0,
    const float* __restrict__ g0, const float* __restrict__ be0,
    float* __restrict__ x)
{
    int n = blockIdx.x, tid = threadIdx.x;
    int hh = tid >> 6, lane = tid & 63;
    int grp = lane >> 4, c = lane & 15;
    int beg = off[n], end = off[n + 1];
    float ern = er0[n * 2 + hh];
    const float4* fb = (const float4*)feat0;
    float4 acc = {0.f, 0.f, 0.f, 0.f};
    float den = 0.f;
    for (int cb = beg; cb < end; cb += 64) {
        int m = end - cb; if (m > 64) m = 64;
        int s_reg = 0; float p_reg = 0.f;
        if (lane < m) {
            s_reg = ssort[cb + lane];
            float v = el0[s_reg * 2 + hh] + ern;
            v = v > 0.f ? v : 0.2f * v;
            p_reg = __expf(v);
        }
        den += p_reg;
        for (int i = 0; i < m; i += 4) {
            int j = i + grp;
            int   sj = __shfl(s_reg, j);     // j>=64 wraps, masked by qj=0
            float qj = __shfl(p_reg, j);
            if (j >= m) qj = 0.f;
            float4 f4 = fb[(size_t)sj * 32 + hh * 16 + c];
            acc.x += qj * f4.x; acc.y += qj * f4.y; acc.z += qj * f4.z; acc.w += qj * f4.w;
        }
    }
    // sum the 4 edge subgroups: lanes {c, c+16, c+32, c+48} -> lane c
    acc.x += __shfl_down(acc.x, 32); acc.y += __shfl_down(acc.y, 32);
    acc.z += __shfl_down(acc.z, 32); acc.w += __shfl_down(acc.w, 32);
    acc.x += __shfl_down(acc.x, 16); acc.y += __shfl_down(acc.y, 16);
    acc.z += __shfl_down(acc.z, 16); acc.w += __shfl_down(acc.w, 16);
#pragma unroll
    for (int o = 32; o > 0; o >>= 1) den += __shfl_down(den, o);
    den = __shfl(den, 0);
    float inv = (end > beg) ? 1.f / den : 0.f;
    float4 b4 = ((const float4*)b0)[hh * 16 + c];
    float4 val;
    val.x = fmaxf(acc.x * inv + b4.x, 0.f);
    val.y = fmaxf(acc.y * inv + b4.y, 0.f);
    val.z = fmaxf(acc.z * inv + b4.z, 0.f);
    val.w = fmaxf(acc.w * inv + b4.w, 0.f);
    float s1 = val.x + val.y + val.z + val.w;
    float s2 = val.x * val.x + val.y * val.y + val.z * val.z + val.w * val.w;
#pragma unroll
    for (int o = 8; o > 0; o >>= 1) { s1 += __shfl_down(s1, o, 16); s2 += __shfl_down(s2, o, 16); }
    __shared__ float sh[4];
    if (lane == 0) { sh[hh] = s1; sh[2 + hh] = s2; }
    __syncthreads();
    float tot = sh[0] + sh[1], tot2 = sh[2] + sh[3];
    float mu = tot * (1.f / 128.f);
    float var = tot2 * (1.f / 128.f) - mu * mu;
    float rs = rsqrtf(var + 1e-5f);
    if (lane < 16) {
        float4 g4 = ((const float4*)g0)[hh * 16 + c];
        float4 e4 = ((const float4*)be0)[hh * 16 + c];
        float4 o4;
        o4.x = (val.x - mu) * rs * g4.x + e4.x;
        o4.y = (val.y - mu) * rs * g4.y + e4.y;
        o4.z = (val.z - mu) * rs * g4.z + e4.z;
        o4.w = (val.w - mu) * rs * g4.w + e4.w;
        ((float4*)(x + (size_t)n * 128))[hh * 16 + c] = o4;
    }
}

// ---- layer-1 GEMM: feat1 = x @ W1 (+ el1/er1). 64 nodes/block, 4/thread. --
// c = tid&15 -> float4 col; g = tid>>4 -> nodes 4g..4g+3.
__global__ __launch_bounds__(256) void k_gemm1(
    const float* __restrict__ x, const float* __restrict__ W1,
    const float* __restrict__ al1, const float* __restrict__ ar1,
    float* __restrict__ feat1, float* __restrict__ el1, float* __restrict__ er1)
{
    int tid = threadIdx.x;
    int c = tid & 15, g = tid >> 4;
    int n0 = blockIdx.x * 64;
    __shared__ float xs[64][128];
#pragma unroll
    for (int r = 0; r < 8; ++r) {
        int f = tid + 256 * r;
        int node = f >> 5, kc = f & 31;
        int n = n0 + node;
        float4 v = {0.f, 0.f, 0.f, 0.f};
        if (n < NN) v = ((const float4*)x)[(size_t)n * 32 + kc];
        ((float4*)xs[node])[kc] = v;
    }
    __syncthreads();
    const float4* W4 = (const float4*)W1;   // [128][16] float4
    float4 acc[4] = {};
    for (int k = 0; k < 128; k += 4) {
        float4 w0 = W4[(k + 0) * 16 + c];
        float4 w1 = W4[(k + 1) * 16 + c];
        float4 w2 = W4[(k + 2) * 16 + c];
        float4 w3 = W4[(k + 3) * 16 + c];
#pragma unroll
        for (int i = 0; i < 4; ++i) {
            float4 hv = *(const float4*)&xs[g * 4 + i][k];
            acc[i].x += hv.x * w0.x + hv.y * w1.x + hv.z * w2.x + hv.w * w3.x;
            acc[i].y += hv.x * w0.y + hv.y * w1.y + hv.z * w2.y + hv.w * w3.y;
            acc[i].z += hv.x * w0.z + hv.y * w1.z + hv.z * w2.z + hv.w * w3.z;
            acc[i].w += hv.x * w0.w + hv.y * w1.w + hv.z * w2.w + hv.w * w3.w;
        }
    }
    float4 al4 = ((const float4*)al1)[c];
    float4 ar4 = ((const float4*)ar1)[c];
#pragma unroll
    for (int i = 0; i < 4; ++i) {
        int n = n0 + g * 4 + i;
        if (n < NN) ((float4*)(feat1 + (size_t)n * 64))[c] = acc[i];
        float pl = acc[i].x * al4.x + acc[i].y * al4.y + acc[i].z * al4.z + acc[i].w * al4.w;
        float pr = acc[i].x * ar4.x + acc[i].y * ar4.y + acc[i].z * ar4.z + acc[i].w * ar4.w;
#pragma unroll
        for (int o = 8; o > 0; o >>= 1) { pl += __shfl_down(pl, o, 16); pr += __shfl_down(pr, o, 16); }
        if ((tid & 15) == 0 && n < NN) { el1[n] = pl; er1[n] = pr; }
    }
}

// ------- layer-1 agg + bias + LN -> out. 1 node per wave. ------------------
__global__ __launch_bounds__(256) void k_agg1(
    const int* __restrict__ off, const int* __restrict__ ssort,
    const float* __restrict__ el1, const float* __restrict__ er1,
    const float* __restrict__ feat1, const float* __restrict__ b1,
    const float* __restrict__ g1, const float* __restrict__ be1,
    float* __restrict__ out)
{
    int w = threadIdx.x >> 6, lane = threadIdx.x & 63;
    int grp = lane >> 4, c = lane & 15;
    int n = blockIdx.x * 4 + w;
    int beg = off[n], end = off[n + 1];
    float ern = er1[n];
    const float4* fb = (const float4*)feat1;
    float4 acc = {0.f, 0.f, 0.f, 0.f};
    float den = 0.f;
    for (int cb = beg; cb < end; cb += 64) {
        int m = end - cb; if (m > 64) m = 64;
        int s_reg = 0; float p_reg = 0.f;
        if (lane < m) {
            s_reg = ssort[cb + lane];
            float v = el1[s_reg] + ern;
            v = v > 0.f ? v : 0.2f * v;
            p_reg = __expf(v);
        }
        den += p_reg;
        for (int i = 0; i < m; i += 4) {
            int j = i + grp;
            int   sj = __shfl(s_reg, j);
            float qj = __shfl(p_reg, j);
            if (j >= m) qj = 0.f;
            float4 f4 = fb[(size_t)sj * 16 + c];
            acc.x += qj * f4.x; acc.y += qj * f4.y; acc.z += qj * f4.z; acc.w += qj * f4.w;
        }
    }
    acc.x += __shfl_down(acc.x, 32); acc.y += __shfl_down(acc.y, 32);
    acc.z += __shfl_down(acc.z, 32); acc.w += __shfl_down(acc.w, 32);
    acc.x += __shfl_down(acc.x, 16); acc.y += __shfl_down(acc.y, 16);
    acc.z += __shfl_down(acc.z, 16); acc.w += __shfl_down(acc.w, 16);
#pragma unroll
    for (int o = 32; o > 0; o >>= 1) den += __shfl_down(den, o);
    den = __shfl(den, 0);
    float inv = (end > beg) ? 1.f / den : 0.f;
    float4 b4 = ((const float4*)b1)[c];
    float4 val;
    val.x = acc.x * inv + b4.x;
    val.y = acc.y * inv + b4.y;
    val.z = acc.z * inv + b4.z;
    val.w = acc.w * inv + b4.w;
    float s1 = val.x + val.y + val.z + val.w;
    float s2 = val.x * val.x + val.y * val.y + val.z * val.z + val.w * val.w;
#pragma unroll
    for (int o = 8; o > 0; o >>= 1) { s1 += __shfl_down(s1, o, 16); s2 += __shfl_down(s2, o, 16); }
    s1 = __shfl(s1, 0); s2 = __shfl(s2, 0);
    float mu = s1 * (1.f / 64.f);
    float var = s2 * (1.f / 64.f) - mu * mu;
    float rs = rsqrtf(var + 1e-5f);
    if (lane < 16) {
        float4 g4 = ((const float4*)g1)[c];
        float4 e4 = ((const float4*)be1)[c];
        float4 o4;
        o4.x = (val.x - mu) * rs * g4.x + e4.x;
        o4.y = (val.y - mu) * rs * g4.y + e4.y;
        o4.z = (val.z - mu) * rs * g4.z + e4.z;
        o4.w = (val.w - mu) * rs * g4.w + e4.w;
        ((float4*)(out + (size_t)n * 64))[c] = o4;
    }
}

extern "C" void kernel_launch(void* const* d_in, const int* in_sizes, int n_in,
                              void* d_out, int out_size, void* d_ws, size_t ws_size,
                              hipStream_t stream)
{
    const float* h   = (const float*)d_in[0];
    const float* W0  = (const float*)d_in[1];
    const float* al0 = (const float*)d_in[2];
    const float* ar0 = (const float*)d_in[3];
    const float* b0  = (const float*)d_in[4];
    const float* W1  = (const float*)d_in[5];
    const float* al1 = (const float*)d_in[6];
    const float* ar1 = (const float*)d_in[7];
    const float* b1  = (const float*)d_in[8];
    const float* g0  = (const float*)d_in[9];
    const float* be0 = (const float*)d_in[10];
    const float* g1  = (const float*)d_in[11];
    const float* be1 = (const float*)d_in[12];
    const int*   src = (const int*)d_in[13];
    const int*   dst = (const int*)d_in[14];
    float* out = (float*)d_out;

    char* p = (char*)d_ws;
    auto alloc = [&](size_t bytes) -> char* {
        char* r = p;
        p += (bytes + 255) & ~(size_t)255;
        return r;
    };
    const int NB1 = (NN + SCB - 1) / SCB;  // 98 scan blocks
    float* feat0 = (float*)alloc((size_t)NN * 128 * sizeof(float));
    float* el0   = (float*)alloc((size_t)NN * 2 * sizeof(float));
    float* er0   = (float*)alloc((size_t)NN * 2 * sizeof(float));
    float* x     = (float*)alloc((size_t)NN * 128 * sizeof(float));
    float* feat1 = (float*)alloc((size_t)NN * 64 * sizeof(float));
    float* el1   = (float*)alloc((size_t)NN * sizeof(float));
    float* er1   = (float*)alloc((size_t)NN * sizeof(float));
    int*   deg   = (int*)alloc((size_t)NN * sizeof(int));
    int*   incl  = (int*)alloc((size_t)NB1 * SCB * sizeof(int));
    int*   bsum  = (int*)alloc((size_t)NB1 * sizeof(int));
    int*   off   = (int*)alloc((size_t)(NN + 1) * sizeof(int));
    int*   cur   = (int*)alloc((size_t)NN * sizeof(int));
    int*   ssort = (int*)alloc((size_t)EE * sizeof(int));

    hipMemsetAsync(deg, 0, (size_t)NN * sizeof(int), stream);

    k_gemm0<<<(NN + 63) / 64, 256, 0, stream>>>(h, W0, al0, ar0, feat0, el0, er0);
    k_deg<<<(EE + 255) / 256, 256, 0, stream>>>(dst, deg);
    k_scan1<<<NB1, SCB, 0, stream>>>(deg, incl, bsum);
    k_scan2<<<1, 128, 0, stream>>>(bsum, NB1);
    k_scan3<<<(NN + 255) / 256, 256, 0, stream>>>(incl, bsum, deg, off, cur);
    k_scatter<<<(EE + 255) / 256, 256, 0, stream>>>(src, dst, cur, ssort);
    k_agg0<<<NN, 128, 0, stream>>>(off, ssort, el0, er0, feat0, b0, g0, be0, x);
    k_gemm1<<<(NN + 63) / 64, 256, 0, stream>>>(x, W1, al1, ar1, feat1, el1, er1);
    k_agg1<<<NN / 4, 256, 0, stream>>>(off, ssort, el1, er1, feat1, b1, g1, be1, out);
}

// Round 5
// 324.047 us; speedup vs baseline: 1.6495x; 1.0452x over previous
//
#include <hip/hip_runtime.h>
#include <hip/hip_bf16.h>

// GAT 2-layer: N=50000, E=800000, DN=128, D=64, H=2 (layer0). All f32 I/O.
// R5: feat0/feat1 stored fp16 (halves gather bytes; values O(1) so fp16 noise
// ~5e-4), agg kernels use 8 col-lanes x 8 edge-groups (1KB/gather-inst, 8
// edges in flight), k_deg fused into k_gemm0, no-max softmax, CSR-by-dst.

#define NN 50000
#define EE 800000

typedef _Float16 h4 __attribute__((ext_vector_type(4)));
typedef _Float16 h8 __attribute__((ext_vector_type(8)));

// ---- layer-0 GEMM + deg: feat0 = h @ W0 (+ el0/er0). 64 nodes/block. ------
// c = tid&31 -> float4 col (cols 4c..4c+3); g = tid>>5 -> nodes 8g..8g+7.
__global__ __launch_bounds__(256) void k_gemm0(
    const float* __restrict__ h, const float* __restrict__ W0,
    const float* __restrict__ al0, const float* __restrict__ ar0,
    const int* __restrict__ dst, int* __restrict__ deg,
    _Float16* __restrict__ feat0, float* __restrict__ el0, float* __restrict__ er0)
{
    int tid = threadIdx.x;
    // fused degree histogram (fire-and-forget atomics overlap with GEMM)
    {
        int gstride = gridDim.x * 256;
        for (int e = blockIdx.x * 256 + tid; e < EE; e += gstride)
            atomicAdd(&deg[dst[e]], 1);
    }
    int c = tid & 31, g = tid >> 5;
    int n0 = blockIdx.x * 64;
    __shared__ float hs[64][128];
#pragma unroll
    for (int r = 0; r < 8; ++r) {
        int f = tid + 256 * r;
        int node = f >> 5, kc = f & 31;
        int n = n0 + node;
        float4 v = {0.f, 0.f, 0.f, 0.f};
        if (n < NN) v = ((const float4*)h)[(size_t)n * 32 + kc];
        ((float4*)hs[node])[kc] = v;
    }
    __syncthreads();
    const float4* W4 = (const float4*)W0;   // [128][32] float4
    float4 acc[8] = {};
    for (int k = 0; k < 128; k += 4) {
        float4 w0 = W4[(k + 0) * 32 + c];
        float4 w1 = W4[(k + 1) * 32 + c];
        float4 w2 = W4[(k + 2) * 32 + c];
        float4 w3 = W4[(k + 3) * 32 + c];
#pragma unroll
        for (int i = 0; i < 8; ++i) {
            float4 hv = *(const float4*)&hs[g * 8 + i][k];
            acc[i].x += hv.x * w0.x + hv.y * w1.x + hv.z * w2.x + hv.w * w3.x;
            acc[i].y += hv.x * w0.y + hv.y * w1.y + hv.z * w2.y + hv.w * w3.y;
            acc[i].z += hv.x * w0.z + hv.y * w1.z + hv.z * w2.z + hv.w * w3.z;
            acc[i].w += hv.x * w0.w + hv.y * w1.w + hv.z * w2.w + hv.w * w3.w;
        }
    }
    float4 al4 = ((const float4*)al0)[c];
    float4 ar4 = ((const float4*)ar0)[c];
    int head = (tid >> 4) & 1;               // c<16 -> head0, c>=16 -> head1
#pragma unroll
    for (int i = 0; i < 8; ++i) {
        int n = n0 + g * 8 + i;
        if (n < NN) {
            h4 hv;
            hv[0] = (_Float16)acc[i].x; hv[1] = (_Float16)acc[i].y;
            hv[2] = (_Float16)acc[i].z; hv[3] = (_Float16)acc[i].w;
            ((h4*)feat0)[(size_t)n * 32 + c] = hv;
        }
        float pl = acc[i].x * al4.x + acc[i].y * al4.y + acc[i].z * al4.z + acc[i].w * al4.w;
        float pr = acc[i].x * ar4.x + acc[i].y * ar4.y + acc[i].z * ar4.z + acc[i].w * ar4.w;
#pragma unroll
        for (int o = 8; o > 0; o >>= 1) { pl += __shfl_down(pl, o, 16); pr += __shfl_down(pr, o, 16); }
        if ((tid & 15) == 0 && n < NN) { el0[n * 2 + head] = pl; er0[n * 2 + head] = pr; }
    }
}

// ---------------- CSR build ----------------
#define SCB 512
__global__ __launch_bounds__(SCB) void k_scan1(
    const int* __restrict__ deg, int* __restrict__ incl, int* __restrict__ bsum)
{
    __shared__ int s[SCB];
    int t = threadIdx.x;
    int i = blockIdx.x * SCB + t;
    int v = (i < NN) ? deg[i] : 0;
    s[t] = v;
    __syncthreads();
    for (int o = 1; o < SCB; o <<= 1) {
        int u = (t >= o) ? s[t - o] : 0;
        __syncthreads();
        s[t] += u;
        __syncthreads();
    }
    incl[i] = s[t];
    if (t == SCB - 1) bsum[blockIdx.x] = s[t];
}

__global__ __launch_bounds__(128) void k_scan2(int* __restrict__ bsum, int nb)
{
    __shared__ int s[128];
    int t = threadIdx.x;
    int v = (t < nb) ? bsum[t] : 0;
    s[t] = v;
    __syncthreads();
    for (int o = 1; o < 128; o <<= 1) {
        int u = (t >= o) ? s[t - o] : 0;
        __syncthreads();
        s[t] += u;
        __syncthreads();
    }
    if (t < nb) bsum[t] = s[t] - v;   // exclusive
}

__global__ void k_scan3(const int* __restrict__ incl, const int* __restrict__ bsum,
                        const int* __restrict__ deg, int* __restrict__ off,
                        int* __restrict__ cur)
{
    int i = blockIdx.x * blockDim.x + threadIdx.x;
    if (i >= NN) return;
    int v = incl[i] + bsum[i >> 9];
    off[i + 1] = v;
    cur[i] = v - deg[i];
    if (i == 0) off[0] = 0;
}

__global__ void k_scatter(const int* __restrict__ src, const int* __restrict__ dst,
                          int* __restrict__ cur, int* __restrict__ ssort)
{
    int e = blockIdx.x * blockDim.x + threadIdx.x;
    if (e < EE) {
        int p = atomicAdd(&cur[dst[e]], 1);
        ssort[p] = src[e];
    }
}

// ------- layer-0 agg + bias + relu + LN -> x. 1 node/128 thr, wave=head. ---
// lane: grp = lane>>3 (8 edge subgroups), c = lane&7 (h8 col, cols 8c..8c+7).
__global__ __launch_bounds__(128) void k_agg0(
    const int* __restrict__ off, const int* __restrict__ ssort,
    const float* __restrict__ el0, const float* __restrict__ er0,
    const _Float16* __restrict__ feat0, const float* __restrict__ b0,
    const float* __restrict__ g0, const float* __restrict__ be0,
    float* __restrict__ x)
{
    int n = blockIdx.x, tid = threadIdx.x;
    int hh = tid >> 6, lane = tid & 63;
    int grp = lane >> 3, c = lane & 7;
    int beg = off[n], end = off[n + 1];
    float ern = er0[n * 2 + hh];
    const h8* fb = (const h8*)feat0;         // row = 16 h8; head slice = 8 h8
    float acc[8] = {};
    float den = 0.f;
    for (int cb = beg; cb < end; cb += 64) {
        int m = end - cb; if (m > 64) m = 64;
        int s_reg = 0; float p_reg = 0.f;
        if (lane < m) {
            s_reg = ssort[cb + lane];
            float v = el0[s_reg * 2 + hh] + ern;
            v = v > 0.f ? v : 0.2f * v;
            p_reg = __expf(v);
        }
        den += p_reg;
        for (int i = 0; i < m; i += 8) {
            int j = i + grp;
            int   sj = __shfl(s_reg, j);
            float qj = __shfl(p_reg, j);
            if (j >= m) qj = 0.f;
            h8 f8 = fb[(size_t)sj * 16 + hh * 8 + c];
#pragma unroll
            for (int k = 0; k < 8; ++k) acc[k] += qj * (float)f8[k];
        }
    }
    // sum 8 edge subgroups: lanes {c, c+8, ..., c+56} -> lane c (c<8)
#pragma unroll
    for (int k = 0; k < 8; ++k) {
        acc[k] += __shfl_down(acc[k], 32);
        acc[k] += __shfl_down(acc[k], 16);
        acc[k] += __shfl_down(acc[k], 8);
    }
#pragma unroll
    for (int o = 32; o > 0; o >>= 1) den += __shfl_down(den, o);
    den = __shfl(den, 0);
    float inv = (end > beg) ? 1.f / den : 0.f;
    // lanes 0..7 hold cols 8c..8c+7 of this head's 64 dims
    float4 ba = ((const float4*)b0)[hh * 16 + c * 2];
    float4 bb = ((const float4*)b0)[hh * 16 + c * 2 + 1];
    float val[8];
    val[0] = fmaxf(acc[0] * inv + ba.x, 0.f);
    val[1] = fmaxf(acc[1] * inv + ba.y, 0.f);
    val[2] = fmaxf(acc[2] * inv + ba.z, 0.f);
    val[3] = fmaxf(acc[3] * inv + ba.w, 0.f);
    val[4] = fmaxf(acc[4] * inv + bb.x, 0.f);
    val[5] = fmaxf(acc[5] * inv + bb.y, 0.f);
    val[6] = fmaxf(acc[6] * inv + bb.z, 0.f);
    val[7] = fmaxf(acc[7] * inv + bb.w, 0.f);
    float s1 = 0.f, s2 = 0.f;
#pragma unroll
    for (int k = 0; k < 8; ++k) { s1 += val[k]; s2 += val[k] * val[k]; }
    // butterfly over lanes 0..7
#pragma unroll
    for (int o = 1; o < 8; o <<= 1) { s1 += __shfl_xor(s1, o, 8); s2 += __shfl_xor(s2, o, 8); }
    __shared__ float sh[4];
    if (lane == 0) { sh[hh] = s1; sh[2 + hh] = s2; }
    __syncthreads();
    float tot = sh[0] + sh[1], tot2 = sh[2] + sh[3];
    float mu = tot * (1.f / 128.f);
    float var = tot2 * (1.f / 128.f) - mu * mu;
    float rs = rsqrtf(var + 1e-5f);
    if (lane < 8) {
        float4 ga = ((const float4*)g0)[hh * 16 + c * 2];
        float4 gb = ((const float4*)g0)[hh * 16 + c * 2 + 1];
        float4 ea = ((const float4*)be0)[hh * 16 + c * 2];
        float4 eb = ((const float4*)be0)[hh * 16 + c * 2 + 1];
        float4 oa, ob;
        oa.x = (val[0] - mu) * rs * ga.x + ea.x;
        oa.y = (val[1] - mu) * rs * ga.y + ea.y;
        oa.z = (val[2] - mu) * rs * ga.z + ea.z;
        oa.w = (val[3] - mu) * rs * ga.w + ea.w;
        ob.x = (val[4] - mu) * rs * gb.x + eb.x;
        ob.y = (val[5] - mu) * rs * gb.y + eb.y;
        ob.z = (val[6] - mu) * rs * gb.z + eb.z;
        ob.w = (val[7] - mu) * rs * gb.w + eb.w;
        float4* xr = (float4*)(x + (size_t)n * 128);
        xr[hh * 16 + c * 2] = oa;
        xr[hh * 16 + c * 2 + 1] = ob;
    }
}

// ---- layer-1 GEMM: feat1 = x @ W1 (+ el1/er1). 64 nodes/block, 4/thread. --
__global__ __launch_bounds__(256) void k_gemm1(
    const float* __restrict__ x, const float* __restrict__ W1,
    const float* __restrict__ al1, const float* __restrict__ ar1,
    _Float16* __restrict__ feat1, float* __restrict__ el1, float* __restrict__ er1)
{
    int tid = threadIdx.x;
    int c = tid & 15, g = tid >> 4;
    int n0 = blockIdx.x * 64;
    __shared__ float xs[64][128];
#pragma unroll
    for (int r = 0; r < 8; ++r) {
        int f = tid + 256 * r;
        int node = f >> 5, kc = f & 31;
        int n = n0 + node;
        float4 v = {0.f, 0.f, 0.f, 0.f};
        if (n < NN) v = ((const float4*)x)[(size_t)n * 32 + kc];
        ((float4*)xs[node])[kc] = v;
    }
    __syncthreads();
    const float4* W4 = (const float4*)W1;   // [128][16] float4
    float4 acc[4] = {};
    for (int k = 0; k < 128; k += 4) {
        float4 w0 = W4[(k + 0) * 16 + c];
        float4 w1 = W4[(k + 1) * 16 + c];
        float4 w2 = W4[(k + 2) * 16 + c];
        float4 w3 = W4[(k + 3) * 16 + c];
#pragma unroll
        for (int i = 0; i < 4; ++i) {
            float4 hv = *(const float4*)&xs[g * 4 + i][k];
            acc[i].x += hv.x * w0.x + hv.y * w1.x + hv.z * w2.x + hv.w * w3.x;
            acc[i].y += hv.x * w0.y + hv.y * w1.y + hv.z * w2.y + hv.w * w3.y;
            acc[i].z += hv.x * w0.z + hv.y * w1.z + hv.z * w2.z + hv.w * w3.z;
            acc[i].w += hv.x * w0.w + hv.y * w1.w + hv.z * w2.w + hv.w * w3.w;
        }
    }
    float4 al4 = ((const float4*)al1)[c];
    float4 ar4 = ((const float4*)ar1)[c];
#pragma unroll
    for (int i = 0; i < 4; ++i) {
        int n = n0 + g * 4 + i;
        if (n < NN) {
            h4 hv;
            hv[0] = (_Float16)acc[i].x; hv[1] = (_Float16)acc[i].y;
            hv[2] = (_Float16)acc[i].z; hv[3] = (_Float16)acc[i].w;
            ((h4*)feat1)[(size_t)n * 16 + c] = hv;
        }
        float pl = acc[i].x * al4.x + acc[i].y * al4.y + acc[i].z * al4.z + acc[i].w * al4.w;
        float pr = acc[i].x * ar4.x + acc[i].y * ar4.y + acc[i].z * ar4.z + acc[i].w * ar4.w;
#pragma unroll
        for (int o = 8; o > 0; o >>= 1) { pl += __shfl_down(pl, o, 16); pr += __shfl_down(pr, o, 16); }
        if ((tid & 15) == 0 && n < NN) { el1[n] = pl; er1[n] = pr; }
    }
}

// ------- layer-1 agg + bias + LN -> out. 1 node per wave. ------------------
// grp = lane>>3 (8 edge subgroups), c = lane&7 (h8 col, cols 8c..8c+7).
__global__ __launch_bounds__(256) void k_agg1(
    const int* __restrict__ off, const int* __restrict__ ssort,
    const float* __restrict__ el1, const float* __restrict__ er1,
    const _Float16* __restrict__ feat1, const float* __restrict__ b1,
    const float* __restrict__ g1, const float* __restrict__ be1,
    float* __restrict__ out)
{
    int w = threadIdx.x >> 6, lane = threadIdx.x & 63;
    int grp = lane >> 3, c = lane & 7;
    int n = blockIdx.x * 4 + w;
    int beg = off[n], end = off[n + 1];
    float ern = er1[n];
    const h8* fb = (const h8*)feat1;         // row = 8 h8
    float acc[8] = {};
    float den = 0.f;
    for (int cb = beg; cb < end; cb += 64) {
        int m = end - cb; if (m > 64) m = 64;
        int s_reg = 0; float p_reg = 0.f;
        if (lane < m) {
            s_reg = ssort[cb + lane];
            float v = el1[s_reg] + ern;
            v = v > 0.f ? v : 0.2f * v;
            p_reg = __expf(v);
        }
        den += p_reg;
        for (int i = 0; i < m; i += 8) {
            int j = i + grp;
            int   sj = __shfl(s_reg, j);
            float qj = __shfl(p_reg, j);
            if (j >= m) qj = 0.f;
            h8 f8 = fb[(size_t)sj * 8 + c];
#pragma unroll
            for (int k = 0; k < 8; ++k) acc[k] += qj * (float)f8[k];
        }
    }
#pragma unroll
    for (int k = 0; k < 8; ++k) {
        acc[k] += __shfl_down(acc[k], 32);
        acc[k] += __shfl_down(acc[k], 16);
        acc[k] += __shfl_down(acc[k], 8);
    }
#pragma unroll
    for (int o = 32; o > 0; o >>= 1) den += __shfl_down(den, o);
    den = __shfl(den, 0);
    float inv = (end > beg) ? 1.f / den : 0.f;
    float4 ba = ((const float4*)b1)[c * 2];
    float4 bb = ((const float4*)b1)[c * 2 + 1];
    float val[8];
    val[0] = acc[0] * inv + ba.x; val[1] = acc[1] * inv + ba.y;
    val[2] = acc[2] * inv + ba.z; val[3] = acc[3] * inv + ba.w;
    val[4] = acc[4] * inv + bb.x; val[5] = acc[5] * inv + bb.y;
    val[6] = acc[6] * inv + bb.z; val[7] = acc[7] * inv + bb.w;
    float s1 = 0.f, s2 = 0.f;
#pragma unroll
    for (int k = 0; k < 8; ++k) { s1 += val[k]; s2 += val[k] * val[k]; }
#pragma unroll
    for (int o = 1; o < 8; o <<= 1) { s1 += __shfl_xor(s1, o, 8); s2 += __shfl_xor(s2, o, 8); }
    float mu = s1 * (1.f / 64.f);
    float var = s2 * (1.f / 64.f) - mu * mu;
    float rs = rsqrtf(var + 1e-5f);
    if (lane < 8) {
        float4 ga = ((const float4*)g1)[c * 2];
        float4 gb = ((const float4*)g1)[c * 2 + 1];
        float4 ea = ((const float4*)be1)[c * 2];
        float4 eb = ((const float4*)be1)[c * 2 + 1];
        float4 oa, ob;
        oa.x = (val[0] - mu) * rs * ga.x + ea.x;
        oa.y = (val[1] - mu) * rs * ga.y + ea.y;
        oa.z = (val[2] - mu) * rs * ga.z + ea.z;
        oa.w = (val[3] - mu) * rs * ga.w + ea.w;
        ob.x = (val[4] - mu) * rs * gb.x + eb.x;
        ob.y = (val[5] - mu) * rs * gb.y + eb.y;
        ob.z = (val[6] - mu) * rs * gb.z + eb.z;
        ob.w = (val[7] - mu) * rs * gb.w + eb.w;
        float4* orow = (float4*)(out + (size_t)n * 64);
        orow[c * 2] = oa;
        orow[c * 2 + 1] = ob;
    }
}

extern "C" void kernel_launch(void* const* d_in, const int* in_sizes, int n_in,
                              void* d_out, int out_size, void* d_ws, size_t ws_size,
                              hipStream_t stream)
{
    const float* h   = (const float*)d_in[0];
    const float* W0  = (const float*)d_in[1];
    const float* al0 = (const float*)d_in[2];
    const float* ar0 = (const float*)d_in[3];
    const float* b0  = (const float*)d_in[4];
    const float* W1  = (const float*)d_in[5];
    const float* al1 = (const float*)d_in[6];
    const float* ar1 = (const float*)d_in[7];
    const float* b1  = (const float*)d_in[8];
    const float* g0  = (const float*)d_in[9];
    const float* be0 = (const float*)d_in[10];
    const float* g1  = (const float*)d_in[11];
    const float* be1 = (const float*)d_in[12];
    const int*   src = (const int*)d_in[13];
    const int*   dst = (const int*)d_in[14];
    float* out = (float*)d_out;

    char* p = (char*)d_ws;
    auto alloc = [&](size_t bytes) -> char* {
        char* r = p;
        p += (bytes + 255) & ~(size_t)255;
        return r;
    };
    const int NB1 = (NN + SCB - 1) / SCB;  // 98 scan blocks
    _Float16* feat0 = (_Float16*)alloc((size_t)NN * 128 * sizeof(_Float16));
    float* el0   = (float*)alloc((size_t)NN * 2 * sizeof(float));
    float* er0   = (float*)alloc((size_t)NN * 2 * sizeof(float));
    float* x     = (float*)alloc((size_t)NN * 128 * sizeof(float));
    _Float16* feat1 = (_Float16*)alloc((size_t)NN * 64 * sizeof(_Float16));
    float* el1   = (float*)alloc((size_t)NN * sizeof(float));
    float* er1   = (float*)alloc((size_t)NN * sizeof(float));
    int*   deg   = (int*)alloc((size_t)NN * sizeof(int));
    int*   incl  = (int*)alloc((size_t)NB1 * SCB * sizeof(int));
    int*   bsum  = (int*)alloc((size_t)NB1 * sizeof(int));
    int*   off   = (int*)alloc((size_t)(NN + 1) * sizeof(int));
    int*   cur   = (int*)alloc((size_t)NN * sizeof(int));
    int*   ssort = (int*)alloc((size_t)EE * sizeof(int));

    hipMemsetAsync(deg, 0, (size_t)NN * sizeof(int), stream);

    k_gemm0<<<(NN + 63) / 64, 256, 0, stream>>>(h, W0, al0, ar0, dst, deg, feat0, el0, er0);
    k_scan1<<<NB1, SCB, 0, stream>>>(deg, incl, bsum);
    k_scan2<<<1, 128, 0, stream>>>(bsum, NB1);
    k_scan3<<<(NN + 255) / 256, 256, 0, stream>>>(incl, bsum, deg, off, cur);
    k_scatter<<<(EE + 255) / 256, 256, 0, stream>>>(src, dst, cur, ssort);
    k_agg0<<<NN, 128, 0, stream>>>(off, ssort, el0, er0, feat0, b0, g0, be0, x);
    k_gemm1<<<(NN + 63) / 64, 256, 0, stream>>>(x, W1, al1, ar1, feat1, el1, er1);
    k_agg1<<<NN / 4, 256, 0, stream>>>(off, ssort, el1, er1, feat1, b1, g1, be1, out);
}

// Round 6
// 301.389 us; speedup vs baseline: 1.7735x; 1.0752x over previous
//
#include <hip/hip_runtime.h>
#include <hip/hip_bf16.h>

// GAT 2-layer: N=50000, E=800000, DN=128, D=64, H=2 (layer0). All f32 I/O.
// R6: MFMA (f32_16x16x32_f16) for both GEMMs. W pre-packed into B-fragment
// order by k_prep (L1-resident); h/x staged in LDS as f16 (padded rows);
// D staged through padded LDS f32 for coalesced stores + el/er epilogue.
// feat0/feat1/x stored f16 (halves gather/stage bytes). Standalone k_deg
// (R5's fused-atomic version serialized the GEMM behind vmcnt drain).
// Agg: 8 col-lanes x 8 edge-groups, 1KB/gather-inst, no-max softmax.

#define NN 50000
#define EE 800000

typedef _Float16 h4 __attribute__((ext_vector_type(4)));
typedef _Float16 h8 __attribute__((ext_vector_type(8)));
typedef float f32x4 __attribute__((ext_vector_type(4)));

// ---- prep: pack W0 -> Wp0[t=8][kk=4][lane=64][j=8], W1 -> Wp1[4][4][64][8]
// Wp[t][kk][lane][j] = W[(kk*32 + (lane>>4)*8 + j)][t*16 + (lane&15)]  (f16)
__global__ __launch_bounds__(256) void k_prep(
    const float* __restrict__ W0, const float* __restrict__ W1,
    h8* __restrict__ Wp0, h8* __restrict__ Wp1)
{
    int idx = blockIdx.x * 256 + threadIdx.x;
    if (idx < 2048) {
        int lane = idx & 63, kk = (idx >> 6) & 3, t = idx >> 8;
        int q = lane >> 4, c = lane & 15;
        h8 v;
#pragma unroll
        for (int j = 0; j < 8; ++j)
            v[j] = (_Float16)W0[(kk * 32 + q * 8 + j) * 128 + t * 16 + c];
        Wp0[idx] = v;
    } else if (idx < 3072) {
        int i2 = idx - 2048;
        int lane = i2 & 63, kk = (i2 >> 6) & 3, t = i2 >> 8;
        int q = lane >> 4, c = lane & 15;
        h8 v;
#pragma unroll
        for (int j = 0; j < 8; ++j)
            v[j] = (_Float16)W1[(kk * 32 + q * 8 + j) * 64 + t * 16 + c];
        Wp1[i2] = v;
    }
}

// ---- layer-0 GEMM (MFMA): feat0 = h @ W0 (+ el0/er0). 64 nodes/block. ----
#define HS_STRIDE 136   // 128 + 8 f16 pad: A-frag ds_read_b128 conflict-free
#define D0_STRIDE 132   // 128 + 4 f32 pad
__global__ __launch_bounds__(256) void k_gemm0(
    const float* __restrict__ h, const h8* __restrict__ Wp0,
    const float* __restrict__ al0, const float* __restrict__ ar0,
    _Float16* __restrict__ feat0, float* __restrict__ el0, float* __restrict__ er0)
{
    int tid = threadIdx.x;
    int n0 = blockIdx.x * 64;
    __shared__ _Float16 hs[64 * HS_STRIDE];
    __shared__ float ds2[64 * D0_STRIDE];
    // stage h (f32 -> f16): 2048 float4, 8 per thread
#pragma unroll
    for (int r = 0; r < 8; ++r) {
        int f = tid + 256 * r;
        int node = f >> 5, kc = f & 31;
        int n = n0 + node;
        float4 v = {0.f, 0.f, 0.f, 0.f};
        if (n < NN) v = ((const float4*)h)[(size_t)n * 32 + kc];
        h4 hv; hv[0] = (_Float16)v.x; hv[1] = (_Float16)v.y;
        hv[2] = (_Float16)v.z; hv[3] = (_Float16)v.w;
        *(h4*)&hs[node * HS_STRIDE + kc * 4] = hv;
    }
    __syncthreads();
    int w = tid >> 6, lane = tid & 63;
    int m = lane & 15, q = lane >> 4;
    // A fragments: node row = w*16 + m, k = kk*32 + q*8 + j
    h8 aF[4];
#pragma unroll
    for (int kk = 0; kk < 4; ++kk)
        aF[kk] = *(const h8*)&hs[(w * 16 + m) * HS_STRIDE + kk * 32 + q * 8];
    // 8 col-tiles x 4 k-steps
#pragma unroll
    for (int t = 0; t < 8; ++t) {
        f32x4 acc = {0.f, 0.f, 0.f, 0.f};
#pragma unroll
        for (int kk = 0; kk < 4; ++kk) {
            h8 bF = Wp0[(t * 4 + kk) * 64 + lane];
            acc = __builtin_amdgcn_mfma_f32_16x16x32_f16(aF[kk], bF, acc, 0, 0, 0);
        }
        // D: row = q*4 + r (node), col = t*16 + m
#pragma unroll
        for (int r = 0; r < 4; ++r)
            ds2[(w * 16 + q * 4 + r) * D0_STRIDE + t * 16 + m] = acc[r];
    }
    __syncthreads();
    // feat0 stores (f16): 1024 h8-groups, 4 per thread
#pragma unroll
    for (int r = 0; r < 4; ++r) {
        int f = tid + 256 * r;
        int node = f >> 4, c8 = f & 15;
        int n = n0 + node;
        if (n < NN) {
            float4 a = *(const float4*)&ds2[node * D0_STRIDE + c8 * 8];
            float4 b = *(const float4*)&ds2[node * D0_STRIDE + c8 * 8 + 4];
            h8 v;
            v[0] = (_Float16)a.x; v[1] = (_Float16)a.y; v[2] = (_Float16)a.z; v[3] = (_Float16)a.w;
            v[4] = (_Float16)b.x; v[5] = (_Float16)b.y; v[6] = (_Float16)b.z; v[7] = (_Float16)b.w;
            ((h8*)feat0)[(size_t)n * 16 + c8] = v;
        }
    }
    // el/er: thread = (node, qq); qq covers cols qq*32..qq*32+31
    {
        int node = tid >> 2, qq = tid & 3;
        int n = n0 + node;
        float pl = 0.f, pr = 0.f;
#pragma unroll
        for (int i = 0; i < 8; ++i) {
            float4 v = *(const float4*)&ds2[node * D0_STRIDE + qq * 32 + i * 4];
            float4 a = ((const float4*)al0)[qq * 8 + i];
            float4 r = ((const float4*)ar0)[qq * 8 + i];
            pl += v.x * a.x + v.y * a.y + v.z * a.z + v.w * a.w;
            pr += v.x * r.x + v.y * r.y + v.z * r.z + v.w * r.w;
        }
        pl += __shfl_xor(pl, 1, 4); pr += __shfl_xor(pr, 1, 4);   // qq pairs (0,1),(2,3)
        if (n < NN) {
            if (qq == 0) { el0[n * 2] = pl;     er0[n * 2] = pr; }
            if (qq == 2) { el0[n * 2 + 1] = pl; er0[n * 2 + 1] = pr; }
        }
    }
}

// ---------------- CSR build ----------------
__global__ void k_deg(const int* __restrict__ dst, int* __restrict__ deg)
{
    int e = blockIdx.x * blockDim.x + threadIdx.x;
    if (e < EE) atomicAdd(&deg[dst[e]], 1);
}

#define SCB 512
__global__ __launch_bounds__(SCB) void k_scan1(
    const int* __restrict__ deg, int* __restrict__ incl, int* __restrict__ bsum)
{
    __shared__ int s[SCB];
    int t = threadIdx.x;
    int i = blockIdx.x * SCB + t;
    int v = (i < NN) ? deg[i] : 0;
    s[t] = v;
    __syncthreads();
    for (int o = 1; o < SCB; o <<= 1) {
        int u = (t >= o) ? s[t - o] : 0;
        __syncthreads();
        s[t] += u;
        __syncthreads();
    }
    incl[i] = s[t];
    if (t == SCB - 1) bsum[blockIdx.x] = s[t];
}

__global__ __launch_bounds__(128) void k_scan2(int* __restrict__ bsum, int nb)
{
    __shared__ int s[128];
    int t = threadIdx.x;
    int v = (t < nb) ? bsum[t] : 0;
    s[t] = v;
    __syncthreads();
    for (int o = 1; o < 128; o <<= 1) {
        int u = (t >= o) ? s[t - o] : 0;
        __syncthreads();
        s[t] += u;
        __syncthreads();
    }
    if (t < nb) bsum[t] = s[t] - v;   // exclusive
}

__global__ void k_scan3(const int* __restrict__ incl, const int* __restrict__ bsum,
                        const int* __restrict__ deg, int* __restrict__ off,
                        int* __restrict__ cur)
{
    int i = blockIdx.x * blockDim.x + threadIdx.x;
    if (i >= NN) return;
    int v = incl[i] + bsum[i >> 9];
    off[i + 1] = v;
    cur[i] = v - deg[i];
    if (i == 0) off[0] = 0;
}

__global__ void k_scatter(const int* __restrict__ src, const int* __restrict__ dst,
                          int* __restrict__ cur, int* __restrict__ ssort)
{
    int e = blockIdx.x * blockDim.x + threadIdx.x;
    if (e < EE) {
        int p = atomicAdd(&cur[dst[e]], 1);
        ssort[p] = src[e];
    }
}

// ------- layer-0 agg + bias + relu + LN -> x (f16). 1 node/128 thr. --------
__global__ __launch_bounds__(128) void k_agg0(
    const int* __restrict__ off, const int* __restrict__ ssort,
    const float* __restrict__ el0, const float* __restrict__ er0,
    const _Float16* __restrict__ feat0, const float* __restrict__ b0,
    const float* __restrict__ g0, const float* __restrict__ be0,
    _Float16* __restrict__ x)
{
    int n = blockIdx.x, tid = threadIdx.x;
    int hh = tid >> 6, lane = tid & 63;
    int grp = lane >> 3, c = lane & 7;
    int beg = off[n], end = off[n + 1];
    float ern = er0[n * 2 + hh];
    const h8* fb = (const h8*)feat0;         // row = 16 h8; head slice = 8 h8
    float acc[8] = {};
    float den = 0.f;
    for (int cb = beg; cb < end; cb += 64) {
        int m = end - cb; if (m > 64) m = 64;
        int s_reg = 0; float p_reg = 0.f;
        if (lane < m) {
            s_reg = ssort[cb + lane];
            float v = el0[s_reg * 2 + hh] + ern;
            v = v > 0.f ? v : 0.2f * v;
            p_reg = __expf(v);
        }
        den += p_reg;
        for (int i = 0; i < m; i += 8) {
            int j = i + grp;
            int   sj = __shfl(s_reg, j);
            float qj = __shfl(p_reg, j);
            if (j >= m) qj = 0.f;
            h8 f8 = fb[(size_t)sj * 16 + hh * 8 + c];
#pragma unroll
            for (int k = 0; k < 8; ++k) acc[k] += qj * (float)f8[k];
        }
    }
#pragma unroll
    for (int k = 0; k < 8; ++k) {
        acc[k] += __shfl_down(acc[k], 32);
        acc[k] += __shfl_down(acc[k], 16);
        acc[k] += __shfl_down(acc[k], 8);
    }
#pragma unroll
    for (int o = 32; o > 0; o >>= 1) den += __shfl_down(den, o);
    den = __shfl(den, 0);
    float inv = (end > beg) ? 1.f / den : 0.f;
    float4 ba = ((const float4*)b0)[hh * 16 + c * 2];
    float4 bb = ((const float4*)b0)[hh * 16 + c * 2 + 1];
    float val[8];
    val[0] = fmaxf(acc[0] * inv + ba.x, 0.f);
    val[1] = fmaxf(acc[1] * inv + ba.y, 0.f);
    val[2] = fmaxf(acc[2] * inv + ba.z, 0.f);
    val[3] = fmaxf(acc[3] * inv + ba.w, 0.f);
    val[4] = fmaxf(acc[4] * inv + bb.x, 0.f);
    val[5] = fmaxf(acc[5] * inv + bb.y, 0.f);
    val[6] = fmaxf(acc[6] * inv + bb.z, 0.f);
    val[7] = fmaxf(acc[7] * inv + bb.w, 0.f);
    float s1 = 0.f, s2 = 0.f;
#pragma unroll
    for (int k = 0; k < 8; ++k) { s1 += val[k]; s2 += val[k] * val[k]; }
#pragma unroll
    for (int o = 1; o < 8; o <<= 1) { s1 += __shfl_xor(s1, o, 8); s2 += __shfl_xor(s2, o, 8); }
    __shared__ float sh[4];
    if (lane == 0) { sh[hh] = s1; sh[2 + hh] = s2; }
    __syncthreads();
    float tot = sh[0] + sh[1], tot2 = sh[2] + sh[3];
    float mu = tot * (1.f / 128.f);
    float var = tot2 * (1.f / 128.f) - mu * mu;
    float rs = rsqrtf(var + 1e-5f);
    if (lane < 8) {
        float4 ga = ((const float4*)g0)[hh * 16 + c * 2];
        float4 gb = ((const float4*)g0)[hh * 16 + c * 2 + 1];
        float4 ea = ((const float4*)be0)[hh * 16 + c * 2];
        float4 eb = ((const float4*)be0)[hh * 16 + c * 2 + 1];
        h8 xv;
        xv[0] = (_Float16)((val[0] - mu) * rs * ga.x + ea.x);
        xv[1] = (_Float16)((val[1] - mu) * rs * ga.y + ea.y);
        xv[2] = (_Float16)((val[2] - mu) * rs * ga.z + ea.z);
        xv[3] = (_Float16)((val[3] - mu) * rs * ga.w + ea.w);
        xv[4] = (_Float16)((val[4] - mu) * rs * gb.x + eb.x);
        xv[5] = (_Float16)((val[5] - mu) * rs * gb.y + eb.y);
        xv[6] = (_Float16)((val[6] - mu) * rs * gb.z + eb.z);
        xv[7] = (_Float16)((val[7] - mu) * rs * gb.w + eb.w);
        ((h8*)x)[(size_t)n * 16 + hh * 8 + c] = xv;
    }
}

// ---- layer-1 GEMM (MFMA): feat1 = x @ W1 (+ el1/er1). 64 nodes/block. ----
#define D1_STRIDE 68    // 64 + 4 f32 pad
__global__ __launch_bounds__(256) void k_gemm1(
    const _Float16* __restrict__ x, const h8* __restrict__ Wp1,
    const float* __restrict__ al1, const float* __restrict__ ar1,
    _Float16* __restrict__ feat1, float* __restrict__ el1, float* __restrict__ er1)
{
    int tid = threadIdx.x;
    int n0 = blockIdx.x * 64;
    __shared__ _Float16 xs[64 * HS_STRIDE];
    __shared__ float ds2[64 * D1_STRIDE];
    // stage x (already f16): 1024 h8, 4 per thread
#pragma unroll
    for (int r = 0; r < 4; ++r) {
        int f = tid + 256 * r;
        int node = f >> 4, kc = f & 15;
        int n = n0 + node;
        h8 v = {};
        if (n < NN) v = ((const h8*)x)[(size_t)n * 16 + kc];
        *(h8*)&xs[node * HS_STRIDE + kc * 8] = v;
    }
    __syncthreads();
    int w = tid >> 6, lane = tid & 63;
    int m = lane & 15, q = lane >> 4;
    h8 aF[4];
#pragma unroll
    for (int kk = 0; kk < 4; ++kk)
        aF[kk] = *(const h8*)&xs[(w * 16 + m) * HS_STRIDE + kk * 32 + q * 8];
#pragma unroll
    for (int t = 0; t < 4; ++t) {
        f32x4 acc = {0.f, 0.f, 0.f, 0.f};
#pragma unroll
        for (int kk = 0; kk < 4; ++kk) {
            h8 bF = Wp1[(t * 4 + kk) * 64 + lane];
            acc = __builtin_amdgcn_mfma_f32_16x16x32_f16(aF[kk], bF, acc, 0, 0, 0);
        }
#pragma unroll
        for (int r = 0; r < 4; ++r)
            ds2[(w * 16 + q * 4 + r) * D1_STRIDE + t * 16 + m] = acc[r];
    }
    __syncthreads();
    // feat1 stores: 512 h8-groups, 2 per thread
#pragma unroll
    for (int r = 0; r < 2; ++r) {
        int f = tid + 256 * r;
        int node = f >> 3, c8 = f & 7;
        int n = n0 + node;
        if (n < NN) {
            float4 a = *(const float4*)&ds2[node * D1_STRIDE + c8 * 8];
            float4 b = *(const float4*)&ds2[node * D1_STRIDE + c8 * 8 + 4];
            h8 v;
            v[0] = (_Float16)a.x; v[1] = (_Float16)a.y; v[2] = (_Float16)a.z; v[3] = (_Float16)a.w;
            v[4] = (_Float16)b.x; v[5] = (_Float16)b.y; v[6] = (_Float16)b.z; v[7] = (_Float16)b.w;
            ((h8*)feat1)[(size_t)n * 8 + c8] = v;
        }
    }
    // el1/er1: thread = (node, qq); qq covers cols qq*16..+15; reduce all 4
    {
        int node = tid >> 2, qq = tid & 3;
        int n = n0 + node;
        float pl = 0.f, pr = 0.f;
#pragma unroll
        for (int i = 0; i < 4; ++i) {
            float4 v = *(const float4*)&ds2[node * D1_STRIDE + qq * 16 + i * 4];
            float4 a = ((const float4*)al1)[qq * 4 + i];
            float4 r = ((const float4*)ar1)[qq * 4 + i];
            pl += v.x * a.x + v.y * a.y + v.z * a.z + v.w * a.w;
            pr += v.x * r.x + v.y * r.y + v.z * r.z + v.w * r.w;
        }
        pl += __shfl_xor(pl, 1, 4); pr += __shfl_xor(pr, 1, 4);
        pl += __shfl_xor(pl, 2, 4); pr += __shfl_xor(pr, 2, 4);
        if (qq == 0 && n < NN) { el1[n] = pl; er1[n] = pr; }
    }
}

// ------- layer-1 agg + bias + LN -> out (f32). 1 node per wave. ------------
__global__ __launch_bounds__(256) void k_agg1(
    const int* __restrict__ off, const int* __restrict__ ssort,
    const float* __restrict__ el1, const float* __restrict__ er1,
    const _Float16* __restrict__ feat1, const float* __restrict__ b1,
    const float* __restrict__ g1, const float* __restrict__ be1,
    float* __restrict__ out)
{
    int w = threadIdx.x >> 6, lane = threadIdx.x & 63;
    int grp = lane >> 3, c = lane & 7;
    int n = blockIdx.x * 4 + w;
    int beg = off[n], end = off[n + 1];
    float ern = er1[n];
    const h8* fb = (const h8*)feat1;         // row = 8 h8
    float acc[8] = {};
    float den = 0.f;
    for (int cb = beg; cb < end; cb += 64) {
        int m = end - cb; if (m > 64) m = 64;
        int s_reg = 0; float p_reg = 0.f;
        if (lane < m) {
            s_reg = ssort[cb + lane];
            float v = el1[s_reg] + ern;
            v = v > 0.f ? v : 0.2f * v;
            p_reg = __expf(v);
        }
        den += p_reg;
        for (int i = 0; i < m; i += 8) {
            int j = i + grp;
            int   sj = __shfl(s_reg, j);
            float qj = __shfl(p_reg, j);
            if (j >= m) qj = 0.f;
            h8 f8 = fb[(size_t)sj * 8 + c];
#pragma unroll
            for (int k = 0; k < 8; ++k) acc[k] += qj * (float)f8[k];
        }
    }
#pragma unroll
    for (int k = 0; k < 8; ++k) {
        acc[k] += __shfl_down(acc[k], 32);
        acc[k] += __shfl_down(acc[k], 16);
        acc[k] += __shfl_down(acc[k], 8);
    }
#pragma unroll
    for (int o = 32; o > 0; o >>= 1) den += __shfl_down(den, o);
    den = __shfl(den, 0);
    float inv = (end > beg) ? 1.f / den : 0.f;
    float4 ba = ((const float4*)b1)[c * 2];
    float4 bb = ((const float4*)b1)[c * 2 + 1];
    float val[8];
    val[0] = acc[0] * inv + ba.x; val[1] = acc[1] * inv + ba.y;
    val[2] = acc[2] * inv + ba.z; val[3] = acc[3] * inv + ba.w;
    val[4] = acc[4] * inv + bb.x; val[5] = acc[5] * inv + bb.y;
    val[6] = acc[6] * inv + bb.z; val[7] = acc[7] * inv + bb.w;
    float s1 = 0.f, s2 = 0.f;
#pragma unroll
    for (int k = 0; k < 8; ++k) { s1 += val[k]; s2 += val[k] * val[k]; }
#pragma unroll
    for (int o = 1; o < 8; o <<= 1) { s1 += __shfl_xor(s1, o, 8); s2 += __shfl_xor(s2, o, 8); }
    float mu = s1 * (1.f / 64.f);
    float var = s2 * (1.f / 64.f) - mu * mu;
    float rs = rsqrtf(var + 1e-5f);
    if (lane < 8) {
        float4 ga = ((const float4*)g1)[c * 2];
        float4 gb = ((const float4*)g1)[c * 2 + 1];
        float4 ea = ((const float4*)be1)[c * 2];
        float4 eb = ((const float4*)be1)[c * 2 + 1];
        float4 oa, ob;
        oa.x = (val[0] - mu) * rs * ga.x + ea.x;
        oa.y = (val[1] - mu) * rs * ga.y + ea.y;
        oa.z = (val[2] - mu) * rs * ga.z + ea.z;
        oa.w = (val[3] - mu) * rs * ga.w + ea.w;
        ob.x = (val[4] - mu) * rs * gb.x + eb.x;
        ob.y = (val[5] - mu) * rs * gb.y + eb.y;
        ob.z = (val[6] - mu) * rs * gb.z + eb.z;
        ob.w = (val[7] - mu) * rs * gb.w + eb.w;
        float4* orow = (float4*)(out + (size_t)n * 64);
        orow[c * 2] = oa;
        orow[c * 2 + 1] = ob;
    }
}

extern "C" void kernel_launch(void* const* d_in, const int* in_sizes, int n_in,
                              void* d_out, int out_size, void* d_ws, size_t ws_size,
                              hipStream_t stream)
{
    const float* h   = (const float*)d_in[0];
    const float* W0  = (const float*)d_in[1];
    const float* al0 = (const float*)d_in[2];
    const float* ar0 = (const float*)d_in[3];
    const float* b0  = (const float*)d_in[4];
    const float* W1  = (const float*)d_in[5];
    const float* al1 = (const float*)d_in[6];
    const float* ar1 = (const float*)d_in[7];
    const float* b1  = (const float*)d_in[8];
    const float* g0  = (const float*)d_in[9];
    const float* be0 = (const float*)d_in[10];
    const float* g1  = (const float*)d_in[11];
    const float* be1 = (const float*)d_in[12];
    const int*   src = (const int*)d_in[13];
    const int*   dst = (const int*)d_in[14];
    float* out = (float*)d_out;

    char* p = (char*)d_ws;
    auto alloc = [&](size_t bytes) -> char* {
        char* r = p;
        p += (bytes + 255) & ~(size_t)255;
        return r;
    };
    const int NB1 = (NN + SCB - 1) / SCB;  // 98 scan blocks
    _Float16* feat0 = (_Float16*)alloc((size_t)NN * 128 * sizeof(_Float16));
    float* el0   = (float*)alloc((size_t)NN * 2 * sizeof(float));
    float* er0   = (float*)alloc((size_t)NN * 2 * sizeof(float));
    _Float16* x  = (_Float16*)alloc((size_t)NN * 128 * sizeof(_Float16));
    _Float16* feat1 = (_Float16*)alloc((size_t)NN * 64 * sizeof(_Float16));
    float* el1   = (float*)alloc((size_t)NN * sizeof(float));
    float* er1   = (float*)alloc((size_t)NN * sizeof(float));
    int*   deg   = (int*)alloc((size_t)NN * sizeof(int));
    int*   incl  = (int*)alloc((size_t)NB1 * SCB * sizeof(int));
    int*   bsum  = (int*)alloc((size_t)NB1 * sizeof(int));
    int*   off   = (int*)alloc((size_t)(NN + 1) * sizeof(int));
    int*   cur   = (int*)alloc((size_t)NN * sizeof(int));
    int*   ssort = (int*)alloc((size_t)EE * sizeof(int));
    h8*    Wp0   = (h8*)alloc(2048 * sizeof(h8));
    h8*    Wp1   = (h8*)alloc(1024 * sizeof(h8));

    hipMemsetAsync(deg, 0, (size_t)NN * sizeof(int), stream);

    k_prep<<<12, 256, 0, stream>>>(W0, W1, Wp0, Wp1);
    k_deg<<<(EE + 255) / 256, 256, 0, stream>>>(dst, deg);
    k_gemm0<<<(NN + 63) / 64, 256, 0, stream>>>(h, Wp0, al0, ar0, feat0, el0, er0);
    k_scan1<<<NB1, SCB, 0, stream>>>(deg, incl, bsum);
    k_scan2<<<1, 128, 0, stream>>>(bsum, NB1);
    k_scan3<<<(NN + 255) / 256, 256, 0, stream>>>(incl, bsum, deg, off, cur);
    k_scatter<<<(EE + 255) / 256, 256, 0, stream>>>(src, dst, cur, ssort);
    k_agg0<<<NN, 128, 0, stream>>>(off, ssort, el0, er0, feat0, b0, g0, be0, x);
    k_gemm1<<<(NN + 63) / 64, 256, 0, stream>>>(x, Wp1, al1, ar1, feat1, el1, er1);
    k_agg1<<<NN / 4, 256, 0, stream>>>(off, ssort, el1, er1, feat1, b1, g1, be1, out);
}

// Round 7
// 283.880 us; speedup vs baseline: 1.8829x; 1.0617x over previous
//
#include <hip/hip_runtime.h>
#include <hip/hip_bf16.h>

// GAT 2-layer: N=50000, E=800000, DN=128, D=64, H=2 (layer0). All f32 I/O.
// R7: agg0 restructured to ONE WAVE PER NODE (both heads in one pass: 16
// col-lanes x 4 edge-groups, float2 el0 gather) -- halves per-node fixed
// cost and edge-side duplicate work vs R6's 2-wave blocks. LDS unions in
// both MFMA GEMMs (hs/ds2 share memory -> better occupancy). k_prep fused
// into k_deg. feat0/feat1/x f16; no-max softmax; CSR-by-dst.

#define NN 50000
#define EE 800000

typedef _Float16 h4 __attribute__((ext_vector_type(4)));
typedef _Float16 h8 __attribute__((ext_vector_type(8)));
typedef float f32x4 __attribute__((ext_vector_type(4)));

// ---- deg histogram + W pack fused (independent work) ----------------------
// Wp[t][kk][lane][j] = W[(kk*32 + (lane>>4)*8 + j)][t*16 + (lane&15)]  (f16)
__global__ void k_degprep(
    const int* __restrict__ dst, int* __restrict__ deg,
    const float* __restrict__ W0, const float* __restrict__ W1,
    h8* __restrict__ Wp0, h8* __restrict__ Wp1)
{
    int idx = blockIdx.x * 256 + threadIdx.x;
    if (idx < EE) atomicAdd(&deg[dst[idx]], 1);
    if (idx < 2048) {
        int lane = idx & 63, kk = (idx >> 6) & 3, t = idx >> 8;
        int q = lane >> 4, c = lane & 15;
        h8 v;
#pragma unroll
        for (int j = 0; j < 8; ++j)
            v[j] = (_Float16)W0[(kk * 32 + q * 8 + j) * 128 + t * 16 + c];
        Wp0[idx] = v;
    } else if (idx < 3072) {
        int i2 = idx - 2048;
        int lane = i2 & 63, kk = (i2 >> 6) & 3, t = i2 >> 8;
        int q = lane >> 4, c = lane & 15;
        h8 v;
#pragma unroll
        for (int j = 0; j < 8; ++j)
            v[j] = (_Float16)W1[(kk * 32 + q * 8 + j) * 64 + t * 16 + c];
        Wp1[i2] = v;
    }
}

// ---- layer-0 GEMM (MFMA): feat0 = h @ W0 (+ el0/er0). 64 nodes/block. ----
#define HS_STRIDE 136   // 128 + 8 f16 pad
#define D0_STRIDE 132   // 128 + 4 f32 pad
__global__ __launch_bounds__(256) void k_gemm0(
    const float* __restrict__ h, const h8* __restrict__ Wp0,
    const float* __restrict__ al0, const float* __restrict__ ar0,
    _Float16* __restrict__ feat0, float* __restrict__ el0, float* __restrict__ er0)
{
    int tid = threadIdx.x;
    int n0 = blockIdx.x * 64;
    __shared__ char smem[64 * D0_STRIDE * 4];      // union: hs (f16) then ds2 (f32)
    _Float16* hs = (_Float16*)smem;
    float* ds2 = (float*)smem;
    // stage h (f32 -> f16): 2048 float4, 8 per thread
#pragma unroll
    for (int r = 0; r < 8; ++r) {
        int f = tid + 256 * r;
        int node = f >> 5, kc = f & 31;
        int n = n0 + node;
        float4 v = {0.f, 0.f, 0.f, 0.f};
        if (n < NN) v = ((const float4*)h)[(size_t)n * 32 + kc];
        h4 hv; hv[0] = (_Float16)v.x; hv[1] = (_Float16)v.y;
        hv[2] = (_Float16)v.z; hv[3] = (_Float16)v.w;
        *(h4*)&hs[node * HS_STRIDE + kc * 4] = hv;
    }
    __syncthreads();
    int w = tid >> 6, lane = tid & 63;
    int m = lane & 15, q = lane >> 4;
    h8 aF[4];
#pragma unroll
    for (int kk = 0; kk < 4; ++kk)
        aF[kk] = *(const h8*)&hs[(w * 16 + m) * HS_STRIDE + kk * 32 + q * 8];
    __syncthreads();                                // hs dead; reuse as ds2
#pragma unroll
    for (int t = 0; t < 8; ++t) {
        f32x4 acc = {0.f, 0.f, 0.f, 0.f};
#pragma unroll
        for (int kk = 0; kk < 4; ++kk) {
            h8 bF = Wp0[(t * 4 + kk) * 64 + lane];
            acc = __builtin_amdgcn_mfma_f32_16x16x32_f16(aF[kk], bF, acc, 0, 0, 0);
        }
#pragma unroll
        for (int r = 0; r < 4; ++r)
            ds2[(w * 16 + q * 4 + r) * D0_STRIDE + t * 16 + m] = acc[r];
    }
    __syncthreads();
    // feat0 stores (f16): 1024 h8-groups, 4 per thread
#pragma unroll
    for (int r = 0; r < 4; ++r) {
        int f = tid + 256 * r;
        int node = f >> 4, c8 = f & 15;
        int n = n0 + node;
        if (n < NN) {
            float4 a = *(const float4*)&ds2[node * D0_STRIDE + c8 * 8];
            float4 b = *(const float4*)&ds2[node * D0_STRIDE + c8 * 8 + 4];
            h8 v;
            v[0] = (_Float16)a.x; v[1] = (_Float16)a.y; v[2] = (_Float16)a.z; v[3] = (_Float16)a.w;
            v[4] = (_Float16)b.x; v[5] = (_Float16)b.y; v[6] = (_Float16)b.z; v[7] = (_Float16)b.w;
            ((h8*)feat0)[(size_t)n * 16 + c8] = v;
        }
    }
    // el/er: thread = (node, qq); qq covers cols qq*32..qq*32+31
    {
        int node = tid >> 2, qq = tid & 3;
        int n = n0 + node;
        float pl = 0.f, pr = 0.f;
#pragma unroll
        for (int i = 0; i < 8; ++i) {
            float4 v = *(const float4*)&ds2[node * D0_STRIDE + qq * 32 + i * 4];
            float4 a = ((const float4*)al0)[qq * 8 + i];
            float4 r = ((const float4*)ar0)[qq * 8 + i];
            pl += v.x * a.x + v.y * a.y + v.z * a.z + v.w * a.w;
            pr += v.x * r.x + v.y * r.y + v.z * r.z + v.w * r.w;
        }
        pl += __shfl_xor(pl, 1, 4); pr += __shfl_xor(pr, 1, 4);
        if (n < NN) {
            if (qq == 0) { el0[n * 2] = pl;     er0[n * 2] = pr; }
            if (qq == 2) { el0[n * 2 + 1] = pl; er0[n * 2 + 1] = pr; }
        }
    }
}

// ---------------- CSR build ----------------
#define SCB 512
__global__ __launch_bounds__(SCB) void k_scan1(
    const int* __restrict__ deg, int* __restrict__ incl, int* __restrict__ bsum)
{
    __shared__ int s[SCB];
    int t = threadIdx.x;
    int i = blockIdx.x * SCB + t;
    int v = (i < NN) ? deg[i] : 0;
    s[t] = v;
    __syncthreads();
    for (int o = 1; o < SCB; o <<= 1) {
        int u = (t >= o) ? s[t - o] : 0;
        __syncthreads();
        s[t] += u;
        __syncthreads();
    }
    incl[i] = s[t];
    if (t == SCB - 1) bsum[blockIdx.x] = s[t];
}

__global__ __launch_bounds__(128) void k_scan2(int* __restrict__ bsum, int nb)
{
    __shared__ int s[128];
    int t = threadIdx.x;
    int v = (t < nb) ? bsum[t] : 0;
    s[t] = v;
    __syncthreads();
    for (int o = 1; o < 128; o <<= 1) {
        int u = (t >= o) ? s[t - o] : 0;
        __syncthreads();
        s[t] += u;
        __syncthreads();
    }
    if (t < nb) bsum[t] = s[t] - v;   // exclusive
}

__global__ void k_scan3(const int* __restrict__ incl, const int* __restrict__ bsum,
                        const int* __restrict__ deg, int* __restrict__ off,
                        int* __restrict__ cur)
{
    int i = blockIdx.x * blockDim.x + threadIdx.x;
    if (i >= NN) return;
    int v = incl[i] + bsum[i >> 9];
    off[i + 1] = v;
    cur[i] = v - deg[i];
    if (i == 0) off[0] = 0;
}

__global__ void k_scatter(const int* __restrict__ src, const int* __restrict__ dst,
                          int* __restrict__ cur, int* __restrict__ ssort)
{
    int e = blockIdx.x * blockDim.x + threadIdx.x;
    if (e < EE) {
        int p = atomicAdd(&cur[dst[e]], 1);
        ssort[p] = src[e];
    }
}

// ------- layer-0 agg + bias + relu + LN -> x (f16). ONE WAVE PER NODE. -----
// lane: grp = lane>>4 (4 edge subgroups), c = lane&15 (h8 chunk = 8 cols;
// c<8 -> head0 cols, c>=8 -> head1 cols). Both heads in one pass.
__global__ __launch_bounds__(256) void k_agg0(
    const int* __restrict__ off, const int* __restrict__ ssort,
    const float* __restrict__ el0, const float* __restrict__ er0,
    const _Float16* __restrict__ feat0, const float* __restrict__ b0,
    const float* __restrict__ g0, const float* __restrict__ be0,
    _Float16* __restrict__ x)
{
    int w = threadIdx.x >> 6, lane = threadIdx.x & 63;
    int grp = lane >> 4, c = lane & 15;
    int n = blockIdx.x * 4 + w;                 // NN = 50000 = 12500*4 exact
    int beg = off[n], end = off[n + 1];
    float2 ern2 = ((const float2*)er0)[n];
    const h8* fb = (const h8*)feat0;            // row = 16 h8 chunks
    float acc[8] = {};
    float den0 = 0.f, den1 = 0.f;
    for (int cb = beg; cb < end; cb += 64) {
        int m = end - cb; if (m > 64) m = 64;
        int s_reg = 0; float p0 = 0.f, p1 = 0.f;
        if (lane < m) {
            s_reg = ssort[cb + lane];
            float2 el2 = ((const float2*)el0)[s_reg];
            float v0 = el2.x + ern2.x; v0 = v0 > 0.f ? v0 : 0.2f * v0;
            float v1 = el2.y + ern2.y; v1 = v1 > 0.f ? v1 : 0.2f * v1;
            p0 = __expf(v0); p1 = __expf(v1);
        }
        den0 += p0; den1 += p1;
        for (int i = 0; i < m; i += 4) {
            int j = i + grp;
            int   sj = __shfl(s_reg, j);
            float q0 = __shfl(p0, j);
            float q1 = __shfl(p1, j);
            float qj = (c < 8) ? q0 : q1;
            if (j >= m) qj = 0.f;
            h8 f8 = fb[(size_t)sj * 16 + c];
#pragma unroll
            for (int k = 0; k < 8; ++k) acc[k] = fmaf(qj, (float)f8[k], acc[k]);
        }
    }
    // reduce 4 edge subgroups: lanes {c, c+16, c+32, c+48} -> lane c
#pragma unroll
    for (int k = 0; k < 8; ++k) {
        acc[k] += __shfl_down(acc[k], 32);
        acc[k] += __shfl_down(acc[k], 16);
    }
#pragma unroll
    for (int o = 32; o > 0; o >>= 1) { den0 += __shfl_down(den0, o); den1 += __shfl_down(den1, o); }
    den0 = __shfl(den0, 0); den1 = __shfl(den1, 0);
    float den = (c < 8) ? den0 : den1;
    float inv = (end > beg) ? 1.f / den : 0.f;
    // lanes c=0..15 (grp 0) hold cols c*8..c*8+7 of the 128-dim row
    float4 ba = ((const float4*)b0)[c * 2];
    float4 bb = ((const float4*)b0)[c * 2 + 1];
    float val[8];
    val[0] = fmaxf(acc[0] * inv + ba.x, 0.f);
    val[1] = fmaxf(acc[1] * inv + ba.y, 0.f);
    val[2] = fmaxf(acc[2] * inv + ba.z, 0.f);
    val[3] = fmaxf(acc[3] * inv + ba.w, 0.f);
    val[4] = fmaxf(acc[4] * inv + bb.x, 0.f);
    val[5] = fmaxf(acc[5] * inv + bb.y, 0.f);
    val[6] = fmaxf(acc[6] * inv + bb.z, 0.f);
    val[7] = fmaxf(acc[7] * inv + bb.w, 0.f);
    float s1 = 0.f, s2 = 0.f;
#pragma unroll
    for (int k = 0; k < 8; ++k) { s1 += val[k]; s2 += val[k] * val[k]; }
    // butterfly over the 16 col-lanes (only grp 0 result used)
#pragma unroll
    for (int o = 1; o < 16; o <<= 1) { s1 += __shfl_xor(s1, o, 16); s2 += __shfl_xor(s2, o, 16); }
    float mu = s1 * (1.f / 128.f);
    float var = s2 * (1.f / 128.f) - mu * mu;
    float rs = rsqrtf(var + 1e-5f);
    if (grp == 0) {
        float4 ga = ((const float4*)g0)[c * 2];
        float4 gb = ((const float4*)g0)[c * 2 + 1];
        float4 ea = ((const float4*)be0)[c * 2];
        float4 eb = ((const float4*)be0)[c * 2 + 1];
        h8 xv;
        xv[0] = (_Float16)((val[0] - mu) * rs * ga.x + ea.x);
        xv[1] = (_Float16)((val[1] - mu) * rs * ga.y + ea.y);
        xv[2] = (_Float16)((val[2] - mu) * rs * ga.z + ea.z);
        xv[3] = (_Float16)((val[3] - mu) * rs * ga.w + ea.w);
        xv[4] = (_Float16)((val[4] - mu) * rs * gb.x + eb.x);
        xv[5] = (_Float16)((val[5] - mu) * rs * gb.y + eb.y);
        xv[6] = (_Float16)((val[6] - mu) * rs * gb.z + eb.z);
        xv[7] = (_Float16)((val[7] - mu) * rs * gb.w + eb.w);
        ((h8*)x)[(size_t)n * 16 + c] = xv;
    }
}

// ---- layer-1 GEMM (MFMA): feat1 = x @ W1 (+ el1/er1). 64 nodes/block. ----
#define D1_STRIDE 68    // 64 + 4 f32 pad
__global__ __launch_bounds__(256) void k_gemm1(
    const _Float16* __restrict__ x, const h8* __restrict__ Wp1,
    const float* __restrict__ al1, const float* __restrict__ ar1,
    _Float16* __restrict__ feat1, float* __restrict__ el1, float* __restrict__ er1)
{
    int tid = threadIdx.x;
    int n0 = blockIdx.x * 64;
    __shared__ char smem[64 * HS_STRIDE * 2 > 64 * D1_STRIDE * 4
                         ? 64 * HS_STRIDE * 2 : 64 * D1_STRIDE * 4];
    _Float16* xs = (_Float16*)smem;
    float* ds2 = (float*)smem;
    // stage x (already f16): 1024 h8, 4 per thread
#pragma unroll
    for (int r = 0; r < 4; ++r) {
        int f = tid + 256 * r;
        int node = f >> 4, kc = f & 15;
        int n = n0 + node;
        h8 v = {};
        if (n < NN) v = ((const h8*)x)[(size_t)n * 16 + kc];
        *(h8*)&xs[node * HS_STRIDE + kc * 8] = v;
    }
    __syncthreads();
    int w = tid >> 6, lane = tid & 63;
    int m = lane & 15, q = lane >> 4;
    h8 aF[4];
#pragma unroll
    for (int kk = 0; kk < 4; ++kk)
        aF[kk] = *(const h8*)&xs[(w * 16 + m) * HS_STRIDE + kk * 32 + q * 8];
    __syncthreads();                                // xs dead; reuse as ds2
#pragma unroll
    for (int t = 0; t < 4; ++t) {
        f32x4 acc = {0.f, 0.f, 0.f, 0.f};
#pragma unroll
        for (int kk = 0; kk < 4; ++kk) {
            h8 bF = Wp1[(t * 4 + kk) * 64 + lane];
            acc = __builtin_amdgcn_mfma_f32_16x16x32_f16(aF[kk], bF, acc, 0, 0, 0);
        }
#pragma unroll
        for (int r = 0; r < 4; ++r)
            ds2[(w * 16 + q * 4 + r) * D1_STRIDE + t * 16 + m] = acc[r];
    }
    __syncthreads();
    // feat1 stores: 512 h8-groups, 2 per thread
#pragma unroll
    for (int r = 0; r < 2; ++r) {
        int f = tid + 256 * r;
        int node = f >> 3, c8 = f & 7;
        int n = n0 + node;
        if (n < NN) {
            float4 a = *(const float4*)&ds2[node * D1_STRIDE + c8 * 8];
            float4 b = *(const float4*)&ds2[node * D1_STRIDE + c8 * 8 + 4];
            h8 v;
            v[0] = (_Float16)a.x; v[1] = (_Float16)a.y; v[2] = (_Float16)a.z; v[3] = (_Float16)a.w;
            v[4] = (_Float16)b.x; v[5] = (_Float16)b.y; v[6] = (_Float16)b.z; v[7] = (_Float16)b.w;
            ((h8*)feat1)[(size_t)n * 8 + c8] = v;
        }
    }
    // el1/er1: thread = (node, qq); qq covers cols qq*16..+15; reduce all 4
    {
        int node = tid >> 2, qq = tid & 3;
        int n = n0 + node;
        float pl = 0.f, pr = 0.f;
#pragma unroll
        for (int i = 0; i < 4; ++i) {
            float4 v = *(const float4*)&ds2[node * D1_STRIDE + qq * 16 + i * 4];
            float4 a = ((const float4*)al1)[qq * 4 + i];
            float4 r = ((const float4*)ar1)[qq * 4 + i];
            pl += v.x * a.x + v.y * a.y + v.z * a.z + v.w * a.w;
            pr += v.x * r.x + v.y * r.y + v.z * r.z + v.w * r.w;
        }
        pl += __shfl_xor(pl, 1, 4); pr += __shfl_xor(pr, 1, 4);
        pl += __shfl_xor(pl, 2, 4); pr += __shfl_xor(pr, 2, 4);
        if (qq == 0 && n < NN) { el1[n] = pl; er1[n] = pr; }
    }
}

// ------- layer-1 agg + bias + LN -> out (f32). 1 node per wave. ------------
__global__ __launch_bounds__(256) void k_agg1(
    const int* __restrict__ off, const int* __restrict__ ssort,
    const float* __restrict__ el1, const float* __restrict__ er1,
    const _Float16* __restrict__ feat1, const float* __restrict__ b1,
    const float* __restrict__ g1, const float* __restrict__ be1,
    float* __restrict__ out)
{
    int w = threadIdx.x >> 6, lane = threadIdx.x & 63;
    int grp = lane >> 3, c = lane & 7;
    int n = blockIdx.x * 4 + w;
    int beg = off[n], end = off[n + 1];
    float ern = er1[n];
    const h8* fb = (const h8*)feat1;         // row = 8 h8
    float acc[8] = {};
    float den = 0.f;
    for (int cb = beg; cb < end; cb += 64) {
        int m = end - cb; if (m > 64) m = 64;
        int s_reg = 0; float p_reg = 0.f;
        if (lane < m) {
            s_reg = ssort[cb + lane];
            float v = el1[s_reg] + ern;
            v = v > 0.f ? v : 0.2f * v;
            p_reg = __expf(v);
        }
        den += p_reg;
        for (int i = 0; i < m; i += 8) {
            int j = i + grp;
            int   sj = __shfl(s_reg, j);
            float qj = __shfl(p_reg, j);
            if (j >= m) qj = 0.f;
            h8 f8 = fb[(size_t)sj * 8 + c];
#pragma unroll
            for (int k = 0; k < 8; ++k) acc[k] = fmaf(qj, (float)f8[k], acc[k]);
        }
    }
#pragma unroll
    for (int k = 0; k < 8; ++k) {
        acc[k] += __shfl_down(acc[k], 32);
        acc[k] += __shfl_down(acc[k], 16);
        acc[k] += __shfl_down(acc[k], 8);
    }
#pragma unroll
    for (int o = 32; o > 0; o >>= 1) den += __shfl_down(den, o);
    den = __shfl(den, 0);
    float inv = (end > beg) ? 1.f / den : 0.f;
    float4 ba = ((const float4*)b1)[c * 2];
    float4 bb = ((const float4*)b1)[c * 2 + 1];
    float val[8];
    val[0] = acc[0] * inv + ba.x; val[1] = acc[1] * inv + ba.y;
    val[2] = acc[2] * inv + ba.z; val[3] = acc[3] * inv + ba.w;
    val[4] = acc[4] * inv + bb.x; val[5] = acc[5] * inv + bb.y;
    val[6] = acc[6] * inv + bb.z; val[7] = acc[7] * inv + bb.w;
    float s1 = 0.f, s2 = 0.f;
#pragma unroll
    for (int k = 0; k < 8; ++k) { s1 += val[k]; s2 += val[k] * val[k]; }
#pragma unroll
    for (int o = 1; o < 8; o <<= 1) { s1 += __shfl_xor(s1, o, 8); s2 += __shfl_xor(s2, o, 8); }
    float mu = s1 * (1.f / 64.f);
    float var = s2 * (1.f / 64.f) - mu * mu;
    float rs = rsqrtf(var + 1e-5f);
    if (lane < 8) {
        float4 ga = ((const float4*)g1)[c * 2];
        float4 gb = ((const float4*)g1)[c * 2 + 1];
        float4 ea = ((const float4*)be1)[c * 2];
        float4 eb = ((const float4*)be1)[c * 2 + 1];
        float4 oa, ob;
        oa.x = (val[0] - mu) * rs * ga.x + ea.x;
        oa.y = (val[1] - mu) * rs * ga.y + ea.y;
        oa.z = (val[2] - mu) * rs * ga.z + ea.z;
        oa.w = (val[3] - mu) * rs * ga.w + ea.w;
        ob.x = (val[4] - mu) * rs * gb.x + eb.x;
        ob.y = (val[5] - mu) * rs * gb.y + eb.y;
        ob.z = (val[6] - mu) * rs * gb.z + eb.z;
        ob.w = (val[7] - mu) * rs * gb.w + eb.w;
        float4* orow = (float4*)(out + (size_t)n * 64);
        orow[c * 2] = oa;
        orow[c * 2 + 1] = ob;
    }
}

extern "C" void kernel_launch(void* const* d_in, const int* in_sizes, int n_in,
                              void* d_out, int out_size, void* d_ws, size_t ws_size,
                              hipStream_t stream)
{
    const float* h   = (const float*)d_in[0];
    const float* W0  = (const float*)d_in[1];
    const float* al0 = (const float*)d_in[2];
    const float* ar0 = (const float*)d_in[3];
    const float* b0  = (const float*)d_in[4];
    const float* W1  = (const float*)d_in[5];
    const float* al1 = (const float*)d_in[6];
    const float* ar1 = (const float*)d_in[7];
    const float* b1  = (const float*)d_in[8];
    const float* g0  = (const float*)d_in[9];
    const float* be0 = (const float*)d_in[10];
    const float* g1  = (const float*)d_in[11];
    const float* be1 = (const float*)d_in[12];
    const int*   src = (const int*)d_in[13];
    const int*   dst = (const int*)d_in[14];
    float* out = (float*)d_out;

    char* p = (char*)d_ws;
    auto alloc = [&](size_t bytes) -> char* {
        char* r = p;
        p += (bytes + 255) & ~(size_t)255;
        return r;
    };
    const int NB1 = (NN + SCB - 1) / SCB;  // 98 scan blocks
    _Float16* feat0 = (_Float16*)alloc((size_t)NN * 128 * sizeof(_Float16));
    float* el0   = (float*)alloc((size_t)NN * 2 * sizeof(float));
    float* er0   = (float*)alloc((size_t)NN * 2 * sizeof(float));
    _Float16* x  = (_Float16*)alloc((size_t)NN * 128 * sizeof(_Float16));
    _Float16* feat1 = (_Float16*)alloc((size_t)NN * 64 * sizeof(_Float16));
    float* el1   = (float*)alloc((size_t)NN * sizeof(float));
    float* er1   = (float*)alloc((size_t)NN * sizeof(float));
    int*   deg   = (int*)alloc((size_t)NN * sizeof(int));
    int*   incl  = (int*)alloc((size_t)NB1 * SCB * sizeof(int));
    int*   bsum  = (int*)alloc((size_t)NB1 * sizeof(int));
    int*   off   = (int*)alloc((size_t)(NN + 1) * sizeof(int));
    int*   cur   = (int*)alloc((size_t)NN * sizeof(int));
    int*   ssort = (int*)alloc((size_t)EE * sizeof(int));
    h8*    Wp0   = (h8*)alloc(2048 * sizeof(h8));
    h8*    Wp1   = (h8*)alloc(1024 * sizeof(h8));

    hipMemsetAsync(deg, 0, (size_t)NN * sizeof(int), stream);

    k_degprep<<<(EE + 255) / 256, 256, 0, stream>>>(dst, deg, W0, W1, Wp0, Wp1);
    k_gemm0<<<(NN + 63) / 64, 256, 0, stream>>>(h, Wp0, al0, ar0, feat0, el0, er0);
    k_scan1<<<NB1, SCB, 0, stream>>>(deg, incl, bsum);
    k_scan2<<<1, 128, 0, stream>>>(bsum, NB1);
    k_scan3<<<(NN + 255) / 256, 256, 0, stream>>>(incl, bsum, deg, off, cur);
    k_scatter<<<(EE + 255) / 256, 256, 0, stream>>>(src, dst, cur, ssort);
    k_agg0<<<NN / 4, 256, 0, stream>>>(off, ssort, el0, er0, feat0, b0, g0, be0, x);
    k_gemm1<<<(NN + 63) / 64, 256, 0, stream>>>(x, Wp1, al1, ar1, feat1, el1, er1);
    k_agg1<<<NN / 4, 256, 0, stream>>>(off, ssort, el1, er1, feat1, b1, g1, be1, out);
}

// Round 8
// 271.525 us; speedup vs baseline: 1.9685x; 1.0455x over previous
//
#include <hip/hip_runtime.h>
#include <hip/hip_bf16.h>

// GAT 2-layer: N=50000, E=800000, DN=128, D=64, H=2 (layer0). All f32 I/O.
// R8: two-level XCD-local CSR scatter. Old k_scatter wrote 4B to random
// lines touched by all XCDs -> 52MB writeback (16x amplification, R7 PMC).
// Now: k_bin claims per-(block,bucket) runs in the bucket's CSR range and
// writes packed (dst16|src16) records there (runs block-private -> lines
// stay in one XCD L2); k_final (one block per 256-node bucket) scatters
// src16 into the final u16 ssort within an ~8KB single-XCD window.
// Rest as R7: MFMA f16 GEMMs (LDS union), one-wave-per-node agg0,
// f16 feat0/feat1/x, no-max softmax.

#define NN 50000
#define EE 800000
#define NBUCK 196            // ceil(NN/256)
#define CHUNK 8192           // edges per k_bin block

typedef _Float16 h4 __attribute__((ext_vector_type(4)));
typedef _Float16 h8 __attribute__((ext_vector_type(8)));
typedef float f32x4 __attribute__((ext_vector_type(4)));

// ---- deg histogram + W pack fused (independent work) ----------------------
// Wp[t][kk][lane][j] = W[(kk*32 + (lane>>4)*8 + j)][t*16 + (lane&15)]  (f16)
__global__ void k_degprep(
    const int* __restrict__ dst, int* __restrict__ deg,
    const float* __restrict__ W0, const float* __restrict__ W1,
    h8* __restrict__ Wp0, h8* __restrict__ Wp1)
{
    int idx = blockIdx.x * 256 + threadIdx.x;
    if (idx < EE) atomicAdd(&deg[dst[idx]], 1);
    if (idx < 2048) {
        int lane = idx & 63, kk = (idx >> 6) & 3, t = idx >> 8;
        int q = lane >> 4, c = lane & 15;
        h8 v;
#pragma unroll
        for (int j = 0; j < 8; ++j)
            v[j] = (_Float16)W0[(kk * 32 + q * 8 + j) * 128 + t * 16 + c];
        Wp0[idx] = v;
    } else if (idx < 3072) {
        int i2 = idx - 2048;
        int lane = i2 & 63, kk = (i2 >> 6) & 3, t = i2 >> 8;
        int q = lane >> 4, c = lane & 15;
        h8 v;
#pragma unroll
        for (int j = 0; j < 8; ++j)
            v[j] = (_Float16)W1[(kk * 32 + q * 8 + j) * 64 + t * 16 + c];
        Wp1[i2] = v;
    }
}

// ---- layer-0 GEMM (MFMA): feat0 = h @ W0 (+ el0/er0). 64 nodes/block. ----
#define HS_STRIDE 136   // 128 + 8 f16 pad
#define D0_STRIDE 132   // 128 + 4 f32 pad
__global__ __launch_bounds__(256) void k_gemm0(
    const float* __restrict__ h, const h8* __restrict__ Wp0,
    const float* __restrict__ al0, const float* __restrict__ ar0,
    _Float16* __restrict__ feat0, float* __restrict__ el0, float* __restrict__ er0)
{
    int tid = threadIdx.x;
    int n0 = blockIdx.x * 64;
    __shared__ char smem[64 * D0_STRIDE * 4];      // union: hs (f16) then ds2 (f32)
    _Float16* hs = (_Float16*)smem;
    float* ds2 = (float*)smem;
#pragma unroll
    for (int r = 0; r < 8; ++r) {
        int f = tid + 256 * r;
        int node = f >> 5, kc = f & 31;
        int n = n0 + node;
        float4 v = {0.f, 0.f, 0.f, 0.f};
        if (n < NN) v = ((const float4*)h)[(size_t)n * 32 + kc];
        h4 hv; hv[0] = (_Float16)v.x; hv[1] = (_Float16)v.y;
        hv[2] = (_Float16)v.z; hv[3] = (_Float16)v.w;
        *(h4*)&hs[node * HS_STRIDE + kc * 4] = hv;
    }
    __syncthreads();
    int w = tid >> 6, lane = tid & 63;
    int m = lane & 15, q = lane >> 4;
    h8 aF[4];
#pragma unroll
    for (int kk = 0; kk < 4; ++kk)
        aF[kk] = *(const h8*)&hs[(w * 16 + m) * HS_STRIDE + kk * 32 + q * 8];
    __syncthreads();                                // hs dead; reuse as ds2
#pragma unroll
    for (int t = 0; t < 8; ++t) {
        f32x4 acc = {0.f, 0.f, 0.f, 0.f};
#pragma unroll
        for (int kk = 0; kk < 4; ++kk) {
            h8 bF = Wp0[(t * 4 + kk) * 64 + lane];
            acc = __builtin_amdgcn_mfma_f32_16x16x32_f16(aF[kk], bF, acc, 0, 0, 0);
        }
#pragma unroll
        for (int r = 0; r < 4; ++r)
            ds2[(w * 16 + q * 4 + r) * D0_STRIDE + t * 16 + m] = acc[r];
    }
    __syncthreads();
#pragma unroll
    for (int r = 0; r < 4; ++r) {
        int f = tid + 256 * r;
        int node = f >> 4, c8 = f & 15;
        int n = n0 + node;
        if (n < NN) {
            float4 a = *(const float4*)&ds2[node * D0_STRIDE + c8 * 8];
            float4 b = *(const float4*)&ds2[node * D0_STRIDE + c8 * 8 + 4];
            h8 v;
            v[0] = (_Float16)a.x; v[1] = (_Float16)a.y; v[2] = (_Float16)a.z; v[3] = (_Float16)a.w;
            v[4] = (_Float16)b.x; v[5] = (_Float16)b.y; v[6] = (_Float16)b.z; v[7] = (_Float16)b.w;
            ((h8*)feat0)[(size_t)n * 16 + c8] = v;
        }
    }
    {
        int node = tid >> 2, qq = tid & 3;
        int n = n0 + node;
        float pl = 0.f, pr = 0.f;
#pragma unroll
        for (int i = 0; i < 8; ++i) {
            float4 v = *(const float4*)&ds2[node * D0_STRIDE + qq * 32 + i * 4];
            float4 a = ((const float4*)al0)[qq * 8 + i];
            float4 r = ((const float4*)ar0)[qq * 8 + i];
            pl += v.x * a.x + v.y * a.y + v.z * a.z + v.w * a.w;
            pr += v.x * r.x + v.y * r.y + v.z * r.z + v.w * r.w;
        }
        pl += __shfl_xor(pl, 1, 4); pr += __shfl_xor(pr, 1, 4);
        if (n < NN) {
            if (qq == 0) { el0[n * 2] = pl;     er0[n * 2] = pr; }
            if (qq == 2) { el0[n * 2 + 1] = pl; er0[n * 2 + 1] = pr; }
        }
    }
}

// ---------------- CSR build ----------------
#define SCB 512
__global__ __launch_bounds__(SCB) void k_scan1(
    const int* __restrict__ deg, int* __restrict__ incl, int* __restrict__ bsum)
{
    __shared__ int s[SCB];
    int t = threadIdx.x;
    int i = blockIdx.x * SCB + t;
    int v = (i < NN) ? deg[i] : 0;
    s[t] = v;
    __syncthreads();
    for (int o = 1; o < SCB; o <<= 1) {
        int u = (t >= o) ? s[t - o] : 0;
        __syncthreads();
        s[t] += u;
        __syncthreads();
    }
    incl[i] = s[t];
    if (t == SCB - 1) bsum[blockIdx.x] = s[t];
}

__global__ __launch_bounds__(128) void k_scan2(int* __restrict__ bsum, int nb)
{
    __shared__ int s[128];
    int t = threadIdx.x;
    int v = (t < nb) ? bsum[t] : 0;
    s[t] = v;
    __syncthreads();
    for (int o = 1; o < 128; o <<= 1) {
        int u = (t >= o) ? s[t - o] : 0;
        __syncthreads();
        s[t] += u;
        __syncthreads();
    }
    if (t < nb) bsum[t] = s[t] - v;   // exclusive
}

// finalize offsets + cursors + per-bucket staging cursors
__global__ void k_scan3(const int* __restrict__ incl, const int* __restrict__ bsum,
                        const int* __restrict__ deg, int* __restrict__ off,
                        int* __restrict__ cur, int* __restrict__ bcur)
{
    int i = blockIdx.x * blockDim.x + threadIdx.x;
    if (i >= NN) return;
    int v = incl[i] + bsum[i >> 9];
    off[i + 1] = v;
    int st = v - deg[i];          // = off[i]
    cur[i] = st;
    if ((i & 255) == 0) bcur[i >> 8] = st;
    if (i == 0) off[0] = 0;
}

// ---- pass 1: bin edges into bucket CSR ranges (block-private runs) --------
__global__ __launch_bounds__(256) void k_bin(
    const int* __restrict__ src, const int* __restrict__ dst,
    int* __restrict__ bcur, unsigned int* __restrict__ staging)
{
    __shared__ int hist[NBUCK];
    __shared__ int rnk[NBUCK];
    __shared__ int gbase[NBUCK];
    int tid = threadIdx.x;
    int base = blockIdx.x * CHUNK;
    int m = EE - base; if (m > CHUNK) m = CHUNK;
    for (int t = tid; t < NBUCK; t += 256) { hist[t] = 0; rnk[t] = 0; }
    __syncthreads();
    for (int i = tid; i < m; i += 256)
        atomicAdd(&hist[dst[base + i] >> 8], 1);
    __syncthreads();
    for (int t = tid; t < NBUCK; t += 256)
        if (hist[t]) gbase[t] = atomicAdd(&bcur[t], hist[t]);
    __syncthreads();
    for (int i = tid; i < m; i += 256) {
        int d = dst[base + i], s = src[base + i];
        int b = d >> 8;
        int r = atomicAdd(&rnk[b], 1);
        staging[gbase[b] + r] = ((unsigned)d << 16) | (unsigned)s;
    }
}

// ---- pass 2: one block per bucket; scatter src16 within 8KB window --------
__global__ __launch_bounds__(256) void k_final(
    const unsigned int* __restrict__ staging, const int* __restrict__ off,
    int* __restrict__ cur, unsigned short* __restrict__ ssort)
{
    int b = blockIdx.x;
    int nlo = b << 8;
    int nhi = nlo + 256; if (nhi > NN) nhi = NN;
    int lo = off[nlo], hi = off[nhi];
    for (int p = lo + threadIdx.x; p < hi; p += 256) {
        unsigned rec = staging[p];
        int n = rec >> 16;
        int pos = atomicAdd(&cur[n], 1);
        ssort[pos] = (unsigned short)(rec & 0xFFFFu);
    }
}

// ------- layer-0 agg + bias + relu + LN -> x (f16). ONE WAVE PER NODE. -----
__global__ __launch_bounds__(256) void k_agg0(
    const int* __restrict__ off, const unsigned short* __restrict__ ssort,
    const float* __restrict__ el0, const float* __restrict__ er0,
    const _Float16* __restrict__ feat0, const float* __restrict__ b0,
    const float* __restrict__ g0, const float* __restrict__ be0,
    _Float16* __restrict__ x)
{
    int w = threadIdx.x >> 6, lane = threadIdx.x & 63;
    int grp = lane >> 4, c = lane & 15;
    int n = blockIdx.x * 4 + w;                 // NN = 12500*4 exact
    int beg = off[n], end = off[n + 1];
    float2 ern2 = ((const float2*)er0)[n];
    const h8* fb = (const h8*)feat0;            // row = 16 h8 chunks
    float acc[8] = {};
    float den0 = 0.f, den1 = 0.f;
    for (int cb = beg; cb < end; cb += 64) {
        int m = end - cb; if (m > 64) m = 64;
        int s_reg = 0; float p0 = 0.f, p1 = 0.f;
        if (lane < m) {
            s_reg = ssort[cb + lane];
            float2 el2 = ((const float2*)el0)[s_reg];
            float v0 = el2.x + ern2.x; v0 = v0 > 0.f ? v0 : 0.2f * v0;
            float v1 = el2.y + ern2.y; v1 = v1 > 0.f ? v1 : 0.2f * v1;
            p0 = __expf(v0); p1 = __expf(v1);
        }
        den0 += p0; den1 += p1;
        for (int i = 0; i < m; i += 4) {
            int j = i + grp;
            int   sj = __shfl(s_reg, j);
            float q0 = __shfl(p0, j);
            float q1 = __shfl(p1, j);
            float qj = (c < 8) ? q0 : q1;
            if (j >= m) qj = 0.f;
            h8 f8 = fb[(size_t)sj * 16 + c];
#pragma unroll
            for (int k = 0; k < 8; ++k) acc[k] = fmaf(qj, (float)f8[k], acc[k]);
        }
    }
#pragma unroll
    for (int k = 0; k < 8; ++k) {
        acc[k] += __shfl_down(acc[k], 32);
        acc[k] += __shfl_down(acc[k], 16);
    }
#pragma unroll
    for (int o = 32; o > 0; o >>= 1) { den0 += __shfl_down(den0, o); den1 += __shfl_down(den1, o); }
    den0 = __shfl(den0, 0); den1 = __shfl(den1, 0);
    float den = (c < 8) ? den0 : den1;
    float inv = (end > beg) ? 1.f / den : 0.f;
    float4 ba = ((const float4*)b0)[c * 2];
    float4 bb = ((const float4*)b0)[c * 2 + 1];
    float val[8];
    val[0] = fmaxf(acc[0] * inv + ba.x, 0.f);
    val[1] = fmaxf(acc[1] * inv + ba.y, 0.f);
    val[2] = fmaxf(acc[2] * inv + ba.z, 0.f);
    val[3] = fmaxf(acc[3] * inv + ba.w, 0.f);
    val[4] = fmaxf(acc[4] * inv + bb.x, 0.f);
    val[5] = fmaxf(acc[5] * inv + bb.y, 0.f);
    val[6] = fmaxf(acc[6] * inv + bb.z, 0.f);
    val[7] = fmaxf(acc[7] * inv + bb.w, 0.f);
    float s1 = 0.f, s2 = 0.f;
#pragma unroll
    for (int k = 0; k < 8; ++k) { s1 += val[k]; s2 += val[k] * val[k]; }
#pragma unroll
    for (int o = 1; o < 16; o <<= 1) { s1 += __shfl_xor(s1, o, 16); s2 += __shfl_xor(s2, o, 16); }
    float mu = s1 * (1.f / 128.f);
    float var = s2 * (1.f / 128.f) - mu * mu;
    float rs = rsqrtf(var + 1e-5f);
    if (grp == 0) {
        float4 ga = ((const float4*)g0)[c * 2];
        float4 gb = ((const float4*)g0)[c * 2 + 1];
        float4 ea = ((const float4*)be0)[c * 2];
        float4 eb = ((const float4*)be0)[c * 2 + 1];
        h8 xv;
        xv[0] = (_Float16)((val[0] - mu) * rs * ga.x + ea.x);
        xv[1] = (_Float16)((val[1] - mu) * rs * ga.y + ea.y);
        xv[2] = (_Float16)((val[2] - mu) * rs * ga.z + ea.z);
        xv[3] = (_Float16)((val[3] - mu) * rs * ga.w + ea.w);
        xv[4] = (_Float16)((val[4] - mu) * rs * gb.x + eb.x);
        xv[5] = (_Float16)((val[5] - mu) * rs * gb.y + eb.y);
        xv[6] = (_Float16)((val[6] - mu) * rs * gb.z + eb.z);
        xv[7] = (_Float16)((val[7] - mu) * rs * gb.w + eb.w);
        ((h8*)x)[(size_t)n * 16 + c] = xv;
    }
}

// ---- layer-1 GEMM (MFMA): feat1 = x @ W1 (+ el1/er1). 64 nodes/block. ----
#define D1_STRIDE 68    // 64 + 4 f32 pad
__global__ __launch_bounds__(256) void k_gemm1(
    const _Float16* __restrict__ x, const h8* __restrict__ Wp1,
    const float* __restrict__ al1, const float* __restrict__ ar1,
    _Float16* __restrict__ feat1, float* __restrict__ el1, float* __restrict__ er1)
{
    int tid = threadIdx.x;
    int n0 = blockIdx.x * 64;
    __shared__ char smem[64 * HS_STRIDE * 2 > 64 * D1_STRIDE * 4
                         ? 64 * HS_STRIDE * 2 : 64 * D1_STRIDE * 4];
    _Float16* xs = (_Float16*)smem;
    float* ds2 = (float*)smem;
#pragma unroll
    for (int r = 0; r < 4; ++r) {
        int f = tid + 256 * r;
        int node = f >> 4, kc = f & 15;
        int n = n0 + node;
        h8 v = {};
        if (n < NN) v = ((const h8*)x)[(size_t)n * 16 + kc];
        *(h8*)&xs[node * HS_STRIDE + kc * 8] = v;
    }
    __syncthreads();
    int w = tid >> 6, lane = tid & 63;
    int m = lane & 15, q = lane >> 4;
    h8 aF[4];
#pragma unroll
    for (int kk = 0; kk < 4; ++kk)
        aF[kk] = *(const h8*)&xs[(w * 16 + m) * HS_STRIDE + kk * 32 + q * 8];
    __syncthreads();                                // xs dead; reuse as ds2
#pragma unroll
    for (int t = 0; t < 4; ++t) {
        f32x4 acc = {0.f, 0.f, 0.f, 0.f};
#pragma unroll
        for (int kk = 0; kk < 4; ++kk) {
            h8 bF = Wp1[(t * 4 + kk) * 64 + lane];
            acc = __builtin_amdgcn_mfma_f32_16x16x32_f16(aF[kk], bF, acc, 0, 0, 0);
        }
#pragma unroll
        for (int r = 0; r < 4; ++r)
            ds2[(w * 16 + q * 4 + r) * D1_STRIDE + t * 16 + m] = acc[r];
    }
    __syncthreads();
#pragma unroll
    for (int r = 0; r < 2; ++r) {
        int f = tid + 256 * r;
        int node = f >> 3, c8 = f & 7;
        int n = n0 + node;
        if (n < NN) {
            float4 a = *(const float4*)&ds2[node * D1_STRIDE + c8 * 8];
            float4 b = *(const float4*)&ds2[node * D1_STRIDE + c8 * 8 + 4];
            h8 v;
            v[0] = (_Float16)a.x; v[1] = (_Float16)a.y; v[2] = (_Float16)a.z; v[3] = (_Float16)a.w;
            v[4] = (_Float16)b.x; v[5] = (_Float16)b.y; v[6] = (_Float16)b.z; v[7] = (_Float16)b.w;
            ((h8*)feat1)[(size_t)n * 8 + c8] = v;
        }
    }
    {
        int node = tid >> 2, qq = tid & 3;
        int n = n0 + node;
        float pl = 0.f, pr = 0.f;
#pragma unroll
        for (int i = 0; i < 4; ++i) {
            float4 v = *(const float4*)&ds2[node * D1_STRIDE + qq * 16 + i * 4];
            float4 a = ((const float4*)al1)[qq * 4 + i];
            float4 r = ((const float4*)ar1)[qq * 4 + i];
            pl += v.x * a.x + v.y * a.y + v.z * a.z + v.w * a.w;
            pr += v.x * r.x + v.y * r.y + v.z * r.z + v.w * r.w;
        }
        pl += __shfl_xor(pl, 1, 4); pr += __shfl_xor(pr, 1, 4);
        pl += __shfl_xor(pl, 2, 4); pr += __shfl_xor(pr, 2, 4);
        if (qq == 0 && n < NN) { el1[n] = pl; er1[n] = pr; }
    }
}

// ------- layer-1 agg + bias + LN -> out (f32). 1 node per wave. ------------
__global__ __launch_bounds__(256) void k_agg1(
    const int* __restrict__ off, const unsigned short* __restrict__ ssort,
    const float* __restrict__ el1, const float* __restrict__ er1,
    const _Float16* __restrict__ feat1, const float* __restrict__ b1,
    const float* __restrict__ g1, const float* __restrict__ be1,
    float* __restrict__ out)
{
    int w = threadIdx.x >> 6, lane = threadIdx.x & 63;
    int grp = lane >> 3, c = lane & 7;
    int n = blockIdx.x * 4 + w;
    int beg = off[n], end = off[n + 1];
    float ern = er1[n];
    const h8* fb = (const h8*)feat1;         // row = 8 h8
    float acc[8] = {};
    float den = 0.f;
    for (int cb = beg; cb < end; cb += 64) {
        int m = end - cb; if (m > 64) m = 64;
        int s_reg = 0; float p_reg = 0.f;
        if (lane < m) {
            s_reg = ssort[cb + lane];
            float v = el1[s_reg] + ern;
            v = v > 0.f ? v : 0.2f * v;
            p_reg = __expf(v);
        }
        den += p_reg;
        for (int i = 0; i < m; i += 8) {
            int j = i + grp;
            int   sj = __shfl(s_reg, j);
            float qj = __shfl(p_reg, j);
            if (j >= m) qj = 0.f;
            h8 f8 = fb[(size_t)sj * 8 + c];
#pragma unroll
            for (int k = 0; k < 8; ++k) acc[k] = fmaf(qj, (float)f8[k], acc[k]);
        }
    }
#pragma unroll
    for (int k = 0; k < 8; ++k) {
        acc[k] += __shfl_down(acc[k], 32);
        acc[k] += __shfl_down(acc[k], 16);
        acc[k] += __shfl_down(acc[k], 8);
    }
#pragma unroll
    for (int o = 32; o > 0; o >>= 1) den += __shfl_down(den, o);
    den = __shfl(den, 0);
    float inv = (end > beg) ? 1.f / den : 0.f;
    float4 ba = ((const float4*)b1)[c * 2];
    float4 bb = ((const float4*)b1)[c * 2 + 1];
    float val[8];
    val[0] = acc[0] * inv + ba.x; val[1] = acc[1] * inv + ba.y;
    val[2] = acc[2] * inv + ba.z; val[3] = acc[3] * inv + ba.w;
    val[4] = acc[4] * inv + bb.x; val[5] = acc[5] * inv + bb.y;
    val[6] = acc[6] * inv + bb.z; val[7] = acc[7] * inv + bb.w;
    float s1 = 0.f, s2 = 0.f;
#pragma unroll
    for (int k = 0; k < 8; ++k) { s1 += val[k]; s2 += val[k] * val[k]; }
#pragma unroll
    for (int o = 1; o < 8; o <<= 1) { s1 += __shfl_xor(s1, o, 8); s2 += __shfl_xor(s2, o, 8); }
    float mu = s1 * (1.f / 64.f);
    float var = s2 * (1.f / 64.f) - mu * mu;
    float rs = rsqrtf(var + 1e-5f);
    if (lane < 8) {
        float4 ga = ((const float4*)g1)[c * 2];
        float4 gb = ((const float4*)g1)[c * 2 + 1];
        float4 ea = ((const float4*)be1)[c * 2];
        float4 eb = ((const float4*)be1)[c * 2 + 1];
        float4 oa, ob;
        oa.x = (val[0] - mu) * rs * ga.x + ea.x;
        oa.y = (val[1] - mu) * rs * ga.y + ea.y;
        oa.z = (val[2] - mu) * rs * ga.z + ea.z;
        oa.w = (val[3] - mu) * rs * ga.w + ea.w;
        ob.x = (val[4] - mu) * rs * gb.x + eb.x;
        ob.y = (val[5] - mu) * rs * gb.y + eb.y;
        ob.z = (val[6] - mu) * rs * gb.z + eb.z;
        ob.w = (val[7] - mu) * rs * gb.w + eb.w;
        float4* orow = (float4*)(out + (size_t)n * 64);
        orow[c * 2] = oa;
        orow[c * 2 + 1] = ob;
    }
}

extern "C" void kernel_launch(void* const* d_in, const int* in_sizes, int n_in,
                              void* d_out, int out_size, void* d_ws, size_t ws_size,
                              hipStream_t stream)
{
    const float* h   = (const float*)d_in[0];
    const float* W0  = (const float*)d_in[1];
    const float* al0 = (const float*)d_in[2];
    const float* ar0 = (const float*)d_in[3];
    const float* b0  = (const float*)d_in[4];
    const float* W1  = (const float*)d_in[5];
    const float* al1 = (const float*)d_in[6];
    const float* ar1 = (const float*)d_in[7];
    const float* b1  = (const float*)d_in[8];
    const float* g0  = (const float*)d_in[9];
    const float* be0 = (const float*)d_in[10];
    const float* g1  = (const float*)d_in[11];
    const float* be1 = (const float*)d_in[12];
    const int*   src = (const int*)d_in[13];
    const int*   dst = (const int*)d_in[14];
    float* out = (float*)d_out;

    char* p = (char*)d_ws;
    auto alloc = [&](size_t bytes) -> char* {
        char* r = p;
        p += (bytes + 255) & ~(size_t)255;
        return r;
    };
    const int NB1 = (NN + SCB - 1) / SCB;  // 98 scan blocks
    _Float16* feat0 = (_Float16*)alloc((size_t)NN * 128 * sizeof(_Float16));
    float* el0   = (float*)alloc((size_t)NN * 2 * sizeof(float));
    float* er0   = (float*)alloc((size_t)NN * 2 * sizeof(float));
    _Float16* x  = (_Float16*)alloc((size_t)NN * 128 * sizeof(_Float16));
    _Float16* feat1 = (_Float16*)alloc((size_t)NN * 64 * sizeof(_Float16));
    float* el1   = (float*)alloc((size_t)NN * sizeof(float));
    float* er1   = (float*)alloc((size_t)NN * sizeof(float));
    int*   deg   = (int*)alloc((size_t)NN * sizeof(int));
    int*   incl  = (int*)alloc((size_t)NB1 * SCB * sizeof(int));
    int*   bsum  = (int*)alloc((size_t)NB1 * sizeof(int));
    int*   off   = (int*)alloc((size_t)(NN + 1) * sizeof(int));
    int*   cur   = (int*)alloc((size_t)NN * sizeof(int));
    int*   bcur  = (int*)alloc((size_t)NBUCK * sizeof(int));
    unsigned int*   staging = (unsigned int*)alloc((size_t)EE * sizeof(unsigned int));
    unsigned short* ssort   = (unsigned short*)alloc((size_t)EE * sizeof(unsigned short));
    h8*    Wp0   = (h8*)alloc(2048 * sizeof(h8));
    h8*    Wp1   = (h8*)alloc(1024 * sizeof(h8));

    hipMemsetAsync(deg, 0, (size_t)NN * sizeof(int), stream);

    k_degprep<<<(EE + 255) / 256, 256, 0, stream>>>(dst, deg, W0, W1, Wp0, Wp1);
    k_gemm0<<<(NN + 63) / 64, 256, 0, stream>>>(h, Wp0, al0, ar0, feat0, el0, er0);
    k_scan1<<<NB1, SCB, 0, stream>>>(deg, incl, bsum);
    k_scan2<<<1, 128, 0, stream>>>(bsum, NB1);
    k_scan3<<<(NN + 255) / 256, 256, 0, stream>>>(incl, bsum, deg, off, cur, bcur);
    k_bin<<<(EE + CHUNK - 1) / CHUNK, 256, 0, stream>>>(src, dst, bcur, staging);
    k_final<<<NBUCK, 256, 0, stream>>>(staging, off, cur, ssort);
    k_agg0<<<NN / 4, 256, 0, stream>>>(off, ssort, el0, er0, feat0, b0, g0, be0, x);
    k_gemm1<<<(NN + 63) / 64, 256, 0, stream>>>(x, Wp1, al1, ar1, feat1, el1, er1);
    k_agg1<<<NN / 4, 256, 0, stream>>>(off, ssort, el1, er1, feat1, b1, g1, be1, out);
}

// Round 9
// 255.230 us; speedup vs baseline: 2.0942x; 1.0638x over previous
//
#include <hip/hip_runtime.h>
#include <hip/hip_bf16.h>

// GAT 2-layer: N=50000, E=800000, DN=128, D=64, H=2 (layer0). All f32 I/O.
// R9: CSR chain slimmed. k_bin now owns deg (atomicAdd during its write
// pass) and stages records at FIXED per-bucket bases (no off dependency)
// -> k_degprep deleted (one fewer 3.2MB dst pass). k_final is an LDS
// counting sort per 256-node bucket: hist+scan+place in LDS, then fully
// coalesced u16 streaming stores (no global cur atomics); atomic fallback
// if a bucket ever exceeds LDS capacity. W-pack rides in k_scan1.
// Rest as R8: MFMA f16 GEMMs (LDS union), one-wave-per-node agg0/agg1,
// f16 feat0/feat1/x, no-max softmax, XCD-local two-level scatter.

#define NN 50000
#define EE 800000
#define NBUCK 196            // ceil(NN/256)
#define CHUNK 8192           // edges per k_bin block
#define CAP 8192             // staging slots per bucket (mean 4082, std ~64)

typedef _Float16 h4 __attribute__((ext_vector_type(4)));
typedef _Float16 h8 __attribute__((ext_vector_type(8)));
typedef float f32x4 __attribute__((ext_vector_type(4)));

// ---- pass 1: bin edges into fixed-capacity bucket staging + deg ----------
__global__ __launch_bounds__(256) void k_bin(
    const int* __restrict__ src, const int* __restrict__ dst,
    int* __restrict__ deg, int* __restrict__ bcnt,
    unsigned int* __restrict__ staging)
{
    __shared__ int hist[NBUCK];
    __shared__ int rnk[NBUCK];
    __shared__ int gbase[NBUCK];
    int tid = threadIdx.x;
    int base = blockIdx.x * CHUNK;
    int m = EE - base; if (m > CHUNK) m = CHUNK;
    for (int t = tid; t < NBUCK; t += 256) { hist[t] = 0; rnk[t] = 0; }
    __syncthreads();
    for (int i = tid; i < m; i += 256)
        atomicAdd(&hist[dst[base + i] >> 8], 1);
    __syncthreads();
    for (int t = tid; t < NBUCK; t += 256)
        if (hist[t]) gbase[t] = atomicAdd(&bcnt[t], hist[t]);
    __syncthreads();
    for (int i = tid; i < m; i += 256) {
        int d = dst[base + i], s = src[base + i];
        atomicAdd(&deg[d], 1);
        int b = d >> 8;
        int r = atomicAdd(&rnk[b], 1);
        staging[(size_t)b * CAP + gbase[b] + r] = ((unsigned)d << 16) | (unsigned)s;
    }
}

// ---------------- CSR scan (+ W pack riding along) ----------------
// Wp[t][kk][lane][j] = W[(kk*32 + (lane>>4)*8 + j)][t*16 + (lane&15)]  (f16)
#define SCB 512
__global__ __launch_bounds__(SCB) void k_scan1(
    const int* __restrict__ deg, int* __restrict__ incl, int* __restrict__ bsum,
    const float* __restrict__ W0, const float* __restrict__ W1,
    h8* __restrict__ Wp0, h8* __restrict__ Wp1)
{
    int t = threadIdx.x;
    int idx = blockIdx.x * SCB + t;
    if (idx < 2048) {
        int lane = idx & 63, kk = (idx >> 6) & 3, tt = idx >> 8;
        int q = lane >> 4, c = lane & 15;
        h8 v;
#pragma unroll
        for (int j = 0; j < 8; ++j)
            v[j] = (_Float16)W0[(kk * 32 + q * 8 + j) * 128 + tt * 16 + c];
        Wp0[idx] = v;
    } else if (idx < 3072) {
        int i2 = idx - 2048;
        int lane = i2 & 63, kk = (i2 >> 6) & 3, tt = i2 >> 8;
        int q = lane >> 4, c = lane & 15;
        h8 v;
#pragma unroll
        for (int j = 0; j < 8; ++j)
            v[j] = (_Float16)W1[(kk * 32 + q * 8 + j) * 64 + tt * 16 + c];
        Wp1[i2] = v;
    }
    __shared__ int s[SCB];
    int v = (idx < NN) ? deg[idx] : 0;
    s[t] = v;
    __syncthreads();
    for (int o = 1; o < SCB; o <<= 1) {
        int u = (t >= o) ? s[t - o] : 0;
        __syncthreads();
        s[t] += u;
        __syncthreads();
    }
    incl[idx] = s[t];
    if (t == SCB - 1) bsum[blockIdx.x] = s[t];
}

__global__ __launch_bounds__(128) void k_scan2(int* __restrict__ bsum, int nb)
{
    __shared__ int s[128];
    int t = threadIdx.x;
    int v = (t < nb) ? bsum[t] : 0;
    s[t] = v;
    __syncthreads();
    for (int o = 1; o < 128; o <<= 1) {
        int u = (t >= o) ? s[t - o] : 0;
        __syncthreads();
        s[t] += u;
        __syncthreads();
    }
    if (t < nb) bsum[t] = s[t] - v;   // exclusive
}

__global__ void k_scan3(const int* __restrict__ incl, const int* __restrict__ bsum,
                        const int* __restrict__ deg, int* __restrict__ off,
                        int* __restrict__ cur)
{
    int i = blockIdx.x * blockDim.x + threadIdx.x;
    if (i >= NN) return;
    int v = incl[i] + bsum[i >> 9];
    off[i + 1] = v;
    cur[i] = v - deg[i];
    if (i == 0) off[0] = 0;
}

// ---- pass 2: LDS counting sort per bucket; coalesced u16 stores ----------
__global__ __launch_bounds__(256) void k_final(
    const unsigned int* __restrict__ staging, const int* __restrict__ bcnt,
    const int* __restrict__ off, int* __restrict__ cur,
    unsigned short* __restrict__ ssort)
{
    int b = blockIdx.x;
    int tid = threadIdx.x;
    int cnt = bcnt[b];
    size_t base = (size_t)b * CAP;
    int lo = off[b << 8];
    __shared__ unsigned short buf[CAP];
    __shared__ int hist[256];
    __shared__ int sc[256];
    if (cnt <= CAP) {
        hist[tid] = 0;
        __syncthreads();
        for (int i = tid; i < cnt; i += 256)
            atomicAdd(&hist[(staging[base + i] >> 16) & 255], 1);
        __syncthreads();
        int hv = hist[tid];
        sc[tid] = hv;
        __syncthreads();
        for (int o = 1; o < 256; o <<= 1) {
            int u = (tid >= o) ? sc[tid - o] : 0;
            __syncthreads();
            sc[tid] += u;
            __syncthreads();
        }
        hist[tid] = sc[tid] - hv;          // exclusive offset, reused as cursor
        __syncthreads();
        for (int i = tid; i < cnt; i += 256) {
            unsigned rec = staging[base + i];
            int loc = (rec >> 16) & 255;
            int r = atomicAdd(&hist[loc], 1);
            buf[r] = (unsigned short)(rec & 0xFFFFu);
        }
        __syncthreads();
        for (int i = tid; i < cnt; i += 256)
            ssort[lo + i] = buf[i];
    } else {
        // statistical impossibility path; correctness fallback
        for (int i = tid; i < cnt; i += 256) {
            unsigned rec = staging[base + i];
            int n = rec >> 16;
            int pos = atomicAdd(&cur[n], 1);
            ssort[pos] = (unsigned short)(rec & 0xFFFFu);
        }
    }
}

// ---- layer-0 GEMM (MFMA): feat0 = h @ W0 (+ el0/er0). 64 nodes/block. ----
#define HS_STRIDE 136   // 128 + 8 f16 pad
#define D0_STRIDE 132   // 128 + 4 f32 pad
__global__ __launch_bounds__(256) void k_gemm0(
    const float* __restrict__ h, const h8* __restrict__ Wp0,
    const float* __restrict__ al0, const float* __restrict__ ar0,
    _Float16* __restrict__ feat0, float* __restrict__ el0, float* __restrict__ er0)
{
    int tid = threadIdx.x;
    int n0 = blockIdx.x * 64;
    __shared__ char smem[64 * D0_STRIDE * 4];      // union: hs (f16) then ds2 (f32)
    _Float16* hs = (_Float16*)smem;
    float* ds2 = (float*)smem;
#pragma unroll
    for (int r = 0; r < 8; ++r) {
        int f = tid + 256 * r;
        int node = f >> 5, kc = f & 31;
        int n = n0 + node;
        float4 v = {0.f, 0.f, 0.f, 0.f};
        if (n < NN) v = ((const float4*)h)[(size_t)n * 32 + kc];
        h4 hv; hv[0] = (_Float16)v.x; hv[1] = (_Float16)v.y;
        hv[2] = (_Float16)v.z; hv[3] = (_Float16)v.w;
        *(h4*)&hs[node * HS_STRIDE + kc * 4] = hv;
    }
    __syncthreads();
    int w = tid >> 6, lane = tid & 63;
    int m = lane & 15, q = lane >> 4;
    h8 aF[4];
#pragma unroll
    for (int kk = 0; kk < 4; ++kk)
        aF[kk] = *(const h8*)&hs[(w * 16 + m) * HS_STRIDE + kk * 32 + q * 8];
    __syncthreads();                                // hs dead; reuse as ds2
#pragma unroll
    for (int t = 0; t < 8; ++t) {
        f32x4 acc = {0.f, 0.f, 0.f, 0.f};
#pragma unroll
        for (int kk = 0; kk < 4; ++kk) {
            h8 bF = Wp0[(t * 4 + kk) * 64 + lane];
            acc = __builtin_amdgcn_mfma_f32_16x16x32_f16(aF[kk], bF, acc, 0, 0, 0);
        }
#pragma unroll
        for (int r = 0; r < 4; ++r)
            ds2[(w * 16 + q * 4 + r) * D0_STRIDE + t * 16 + m] = acc[r];
    }
    __syncthreads();
#pragma unroll
    for (int r = 0; r < 4; ++r) {
        int f = tid + 256 * r;
        int node = f >> 4, c8 = f & 15;
        int n = n0 + node;
        if (n < NN) {
            float4 a = *(const float4*)&ds2[node * D0_STRIDE + c8 * 8];
            float4 b = *(const float4*)&ds2[node * D0_STRIDE + c8 * 8 + 4];
            h8 v;
            v[0] = (_Float16)a.x; v[1] = (_Float16)a.y; v[2] = (_Float16)a.z; v[3] = (_Float16)a.w;
            v[4] = (_Float16)b.x; v[5] = (_Float16)b.y; v[6] = (_Float16)b.z; v[7] = (_Float16)b.w;
            ((h8*)feat0)[(size_t)n * 16 + c8] = v;
        }
    }
    {
        int node = tid >> 2, qq = tid & 3;
        int n = n0 + node;
        float pl = 0.f, pr = 0.f;
#pragma unroll
        for (int i = 0; i < 8; ++i) {
            float4 v = *(const float4*)&ds2[node * D0_STRIDE + qq * 32 + i * 4];
            float4 a = ((const float4*)al0)[qq * 8 + i];
            float4 r = ((const float4*)ar0)[qq * 8 + i];
            pl += v.x * a.x + v.y * a.y + v.z * a.z + v.w * a.w;
            pr += v.x * r.x + v.y * r.y + v.z * r.z + v.w * r.w;
        }
        pl += __shfl_xor(pl, 1, 4); pr += __shfl_xor(pr, 1, 4);
        if (n < NN) {
            if (qq == 0) { el0[n * 2] = pl;     er0[n * 2] = pr; }
            if (qq == 2) { el0[n * 2 + 1] = pl; er0[n * 2 + 1] = pr; }
        }
    }
}

// ------- layer-0 agg + bias + relu + LN -> x (f16). ONE WAVE PER NODE. -----
__global__ __launch_bounds__(256) void k_agg0(
    const int* __restrict__ off, const unsigned short* __restrict__ ssort,
    const float* __restrict__ el0, const float* __restrict__ er0,
    const _Float16* __restrict__ feat0, const float* __restrict__ b0,
    const float* __restrict__ g0, const float* __restrict__ be0,
    _Float16* __restrict__ x)
{
    int w = threadIdx.x >> 6, lane = threadIdx.x & 63;
    int grp = lane >> 4, c = lane & 15;
    int n = blockIdx.x * 4 + w;                 // NN = 12500*4 exact
    int beg = off[n], end = off[n + 1];
    float2 ern2 = ((const float2*)er0)[n];
    const h8* fb = (const h8*)feat0;            // row = 16 h8 chunks
    float acc[8] = {};
    float den0 = 0.f, den1 = 0.f;
    for (int cb = beg; cb < end; cb += 64) {
        int m = end - cb; if (m > 64) m = 64;
        int s_reg = 0; float p0 = 0.f, p1 = 0.f;
        if (lane < m) {
            s_reg = ssort[cb + lane];
            float2 el2 = ((const float2*)el0)[s_reg];
            float v0 = el2.x + ern2.x; v0 = v0 > 0.f ? v0 : 0.2f * v0;
            float v1 = el2.y + ern2.y; v1 = v1 > 0.f ? v1 : 0.2f * v1;
            p0 = __expf(v0); p1 = __expf(v1);
        }
        den0 += p0; den1 += p1;
        for (int i = 0; i < m; i += 4) {
            int j = i + grp;
            int   sj = __shfl(s_reg, j);
            float q0 = __shfl(p0, j);
            float q1 = __shfl(p1, j);
            float qj = (c < 8) ? q0 : q1;
            if (j >= m) qj = 0.f;
            h8 f8 = fb[(size_t)sj * 16 + c];
#pragma unroll
            for (int k = 0; k < 8; ++k) acc[k] = fmaf(qj, (float)f8[k], acc[k]);
        }
    }
#pragma unroll
    for (int k = 0; k < 8; ++k) {
        acc[k] += __shfl_down(acc[k], 32);
        acc[k] += __shfl_down(acc[k], 16);
    }
#pragma unroll
    for (int o = 32; o > 0; o >>= 1) { den0 += __shfl_down(den0, o); den1 += __shfl_down(den1, o); }
    den0 = __shfl(den0, 0); den1 = __shfl(den1, 0);
    float den = (c < 8) ? den0 : den1;
    float inv = (end > beg) ? 1.f / den : 0.f;
    float4 ba = ((const float4*)b0)[c * 2];
    float4 bb = ((const float4*)b0)[c * 2 + 1];
    float val[8];
    val[0] = fmaxf(acc[0] * inv + ba.x, 0.f);
    val[1] = fmaxf(acc[1] * inv + ba.y, 0.f);
    val[2] = fmaxf(acc[2] * inv + ba.z, 0.f);
    val[3] = fmaxf(acc[3] * inv + ba.w, 0.f);
    val[4] = fmaxf(acc[4] * inv + bb.x, 0.f);
    val[5] = fmaxf(acc[5] * inv + bb.y, 0.f);
    val[6] = fmaxf(acc[6] * inv + bb.z, 0.f);
    val[7] = fmaxf(acc[7] * inv + bb.w, 0.f);
    float s1 = 0.f, s2 = 0.f;
#pragma unroll
    for (int k = 0; k < 8; ++k) { s1 += val[k]; s2 += val[k] * val[k]; }
#pragma unroll
    for (int o = 1; o < 16; o <<= 1) { s1 += __shfl_xor(s1, o, 16); s2 += __shfl_xor(s2, o, 16); }
    float mu = s1 * (1.f / 128.f);
    float var = s2 * (1.f / 128.f) - mu * mu;
    float rs = rsqrtf(var + 1e-5f);
    if (grp == 0) {
        float4 ga = ((const float4*)g0)[c * 2];
        float4 gb = ((const float4*)g0)[c * 2 + 1];
        float4 ea = ((const float4*)be0)[c * 2];
        float4 eb = ((const float4*)be0)[c * 2 + 1];
        h8 xv;
        xv[0] = (_Float16)((val[0] - mu) * rs * ga.x + ea.x);
        xv[1] = (_Float16)((val[1] - mu) * rs * ga.y + ea.y);
        xv[2] = (_Float16)((val[2] - mu) * rs * ga.z + ea.z);
        xv[3] = (_Float16)((val[3] - mu) * rs * ga.w + ea.w);
        xv[4] = (_Float16)((val[4] - mu) * rs * gb.x + eb.x);
        xv[5] = (_Float16)((val[5] - mu) * rs * gb.y + eb.y);
        xv[6] = (_Float16)((val[6] - mu) * rs * gb.z + eb.z);
        xv[7] = (_Float16)((val[7] - mu) * rs * gb.w + eb.w);
        ((h8*)x)[(size_t)n * 16 + c] = xv;
    }
}

// ---- layer-1 GEMM (MFMA): feat1 = x @ W1 (+ el1/er1). 64 nodes/block. ----
#define D1_STRIDE 68    // 64 + 4 f32 pad
__global__ __launch_bounds__(256) void k_gemm1(
    const _Float16* __restrict__ x, const h8* __restrict__ Wp1,
    const float* __restrict__ al1, const float* __restrict__ ar1,
    _Float16* __restrict__ feat1, float* __restrict__ el1, float* __restrict__ er1)
{
    int tid = threadIdx.x;
    int n0 = blockIdx.x * 64;
    __shared__ char smem[64 * HS_STRIDE * 2 > 64 * D1_STRIDE * 4
                         ? 64 * HS_STRIDE * 2 : 64 * D1_STRIDE * 4];
    _Float16* xs = (_Float16*)smem;
    float* ds2 = (float*)smem;
#pragma unroll
    for (int r = 0; r < 4; ++r) {
        int f = tid + 256 * r;
        int node = f >> 4, kc = f & 15;
        int n = n0 + node;
        h8 v = {};
        if (n < NN) v = ((const h8*)x)[(size_t)n * 16 + kc];
        *(h8*)&xs[node * HS_STRIDE + kc * 8] = v;
    }
    __syncthreads();
    int w = tid >> 6, lane = tid & 63;
    int m = lane & 15, q = lane >> 4;
    h8 aF[4];
#pragma unroll
    for (int kk = 0; kk < 4; ++kk)
        aF[kk] = *(const h8*)&xs[(w * 16 + m) * HS_STRIDE + kk * 32 + q * 8];
    __syncthreads();                                // xs dead; reuse as ds2
#pragma unroll
    for (int t = 0; t < 4; ++t) {
        f32x4 acc = {0.f, 0.f, 0.f, 0.f};
#pragma unroll
        for (int kk = 0; kk < 4; ++kk) {
            h8 bF = Wp1[(t * 4 + kk) * 64 + lane];
            acc = __builtin_amdgcn_mfma_f32_16x16x32_f16(aF[kk], bF, acc, 0, 0, 0);
        }
#pragma unroll
        for (int r = 0; r < 4; ++r)
            ds2[(w * 16 + q * 4 + r) * D1_STRIDE + t * 16 + m] = acc[r];
    }
    __syncthreads();
#pragma unroll
    for (int r = 0; r < 2; ++r) {
        int f = tid + 256 * r;
        int node = f >> 3, c8 = f & 7;
        int n = n0 + node;
        if (n < NN) {
            float4 a = *(const float4*)&ds2[node * D1_STRIDE + c8 * 8];
            float4 b = *(const float4*)&ds2[node * D1_STRIDE + c8 * 8 + 4];
            h8 v;
            v[0] = (_Float16)a.x; v[1] = (_Float16)a.y; v[2] = (_Float16)a.z; v[3] = (_Float16)a.w;
            v[4] = (_Float16)b.x; v[5] = (_Float16)b.y; v[6] = (_Float16)b.z; v[7] = (_Float16)b.w;
            ((h8*)feat1)[(size_t)n * 8 + c8] = v;
        }
    }
    {
        int node = tid >> 2, qq = tid & 3;
        int n = n0 + node;
        float pl = 0.f, pr = 0.f;
#pragma unroll
        for (int i = 0; i < 4; ++i) {
            float4 v = *(const float4*)&ds2[node * D1_STRIDE + qq * 16 + i * 4];
            float4 a = ((const float4*)al1)[qq * 4 + i];
            float4 r = ((const float4*)ar1)[qq * 4 + i];
            pl += v.x * a.x + v.y * a.y + v.z * a.z + v.w * a.w;
            pr += v.x * r.x + v.y * r.y + v.z * r.z + v.w * r.w;
        }
        pl += __shfl_xor(pl, 1, 4); pr += __shfl_xor(pr, 1, 4);
        pl += __shfl_xor(pl, 2, 4); pr += __shfl_xor(pr, 2, 4);
        if (qq == 0 && n < NN) { el1[n] = pl; er1[n] = pr; }
    }
}

// ------- layer-1 agg + bias + LN -> out (f32). 1 node per wave. ------------
__global__ __launch_bounds__(256) void k_agg1(
    const int* __restrict__ off, const unsigned short* __restrict__ ssort,
    const float* __restrict__ el1, const float* __restrict__ er1,
    const _Float16* __restrict__ feat1, const float* __restrict__ b1,
    const float* __restrict__ g1, const float* __restrict__ be1,
    float* __restrict__ out)
{
    int w = threadIdx.x >> 6, lane = threadIdx.x & 63;
    int grp = lane >> 3, c = lane & 7;
    int n = blockIdx.x * 4 + w;
    int beg = off[n], end = off[n + 1];
    float ern = er1[n];
    const h8* fb = (const h8*)feat1;         // row = 8 h8
    float acc[8] = {};
    float den = 0.f;
    for (int cb = beg; cb < end; cb += 64) {
        int m = end - cb; if (m > 64) m = 64;
        int s_reg = 0; float p_reg = 0.f;
        if (lane < m) {
            s_reg = ssort[cb + lane];
            float v = el1[s_reg] + ern;
            v = v > 0.f ? v : 0.2f * v;
            p_reg = __expf(v);
        }
        den += p_reg;
        for (int i = 0; i < m; i += 8) {
            int j = i + grp;
            int   sj = __shfl(s_reg, j);
            float qj = __shfl(p_reg, j);
            if (j >= m) qj = 0.f;
            h8 f8 = fb[(size_t)sj * 8 + c];
#pragma unroll
            for (int k = 0; k < 8; ++k) acc[k] = fmaf(qj, (float)f8[k], acc[k]);
        }
    }
#pragma unroll
    for (int k = 0; k < 8; ++k) {
        acc[k] += __shfl_down(acc[k], 32);
        acc[k] += __shfl_down(acc[k], 16);
        acc[k] += __shfl_down(acc[k], 8);
    }
#pragma unroll
    for (int o = 32; o > 0; o >>= 1) den += __shfl_down(den, o);
    den = __shfl(den, 0);
    float inv = (end > beg) ? 1.f / den : 0.f;
    float4 ba = ((const float4*)b1)[c * 2];
    float4 bb = ((const float4*)b1)[c * 2 + 1];
    float val[8];
    val[0] = acc[0] * inv + ba.x; val[1] = acc[1] * inv + ba.y;
    val[2] = acc[2] * inv + ba.z; val[3] = acc[3] * inv + ba.w;
    val[4] = acc[4] * inv + bb.x; val[5] = acc[5] * inv + bb.y;
    val[6] = acc[6] * inv + bb.z; val[7] = acc[7] * inv + bb.w;
    float s1 = 0.f, s2 = 0.f;
#pragma unroll
    for (int k = 0; k < 8; ++k) { s1 += val[k]; s2 += val[k] * val[k]; }
#pragma unroll
    for (int o = 1; o < 8; o <<= 1) { s1 += __shfl_xor(s1, o, 8); s2 += __shfl_xor(s2, o, 8); }
    float mu = s1 * (1.f / 64.f);
    float var = s2 * (1.f / 64.f) - mu * mu;
    float rs = rsqrtf(var + 1e-5f);
    if (lane < 8) {
        float4 ga = ((const float4*)g1)[c * 2];
        float4 gb = ((const float4*)g1)[c * 2 + 1];
        float4 ea = ((const float4*)be1)[c * 2];
        float4 eb = ((const float4*)be1)[c * 2 + 1];
        float4 oa, ob;
        oa.x = (val[0] - mu) * rs * ga.x + ea.x;
        oa.y = (val[1] - mu) * rs * ga.y + ea.y;
        oa.z = (val[2] - mu) * rs * ga.z + ea.z;
        oa.w = (val[3] - mu) * rs * ga.w + ea.w;
        ob.x = (val[4] - mu) * rs * gb.x + eb.x;
        ob.y = (val[5] - mu) * rs * gb.y + eb.y;
        ob.z = (val[6] - mu) * rs * gb.z + eb.z;
        ob.w = (val[7] - mu) * rs * gb.w + eb.w;
        float4* orow = (float4*)(out + (size_t)n * 64);
        orow[c * 2] = oa;
        orow[c * 2 + 1] = ob;
    }
}

extern "C" void kernel_launch(void* const* d_in, const int* in_sizes, int n_in,
                              void* d_out, int out_size, void* d_ws, size_t ws_size,
                              hipStream_t stream)
{
    const float* h   = (const float*)d_in[0];
    const float* W0  = (const float*)d_in[1];
    const float* al0 = (const float*)d_in[2];
    const float* ar0 = (const float*)d_in[3];
    const float* b0  = (const float*)d_in[4];
    const float* W1  = (const float*)d_in[5];
    const float* al1 = (const float*)d_in[6];
    const float* ar1 = (const float*)d_in[7];
    const float* b1  = (const float*)d_in[8];
    const float* g0  = (const float*)d_in[9];
    const float* be0 = (const float*)d_in[10];
    const float* g1  = (const float*)d_in[11];
    const float* be1 = (const float*)d_in[12];
    const int*   src = (const int*)d_in[13];
    const int*   dst = (const int*)d_in[14];
    float* out = (float*)d_out;

    char* p = (char*)d_ws;
    auto alloc = [&](size_t bytes) -> char* {
        char* r = p;
        p += (bytes + 255) & ~(size_t)255;
        return r;
    };
    const int NB1 = (NN + SCB - 1) / SCB;  // 98 scan blocks
    _Float16* feat0 = (_Float16*)alloc((size_t)NN * 128 * sizeof(_Float16));
    float* el0   = (float*)alloc((size_t)NN * 2 * sizeof(float));
    float* er0   = (float*)alloc((size_t)NN * 2 * sizeof(float));
    _Float16* x  = (_Float16*)alloc((size_t)NN * 128 * sizeof(_Float16));
    _Float16* feat1 = (_Float16*)alloc((size_t)NN * 64 * sizeof(_Float16));
    float* el1   = (float*)alloc((size_t)NN * sizeof(float));
    float* er1   = (float*)alloc((size_t)NN * sizeof(float));
    int*   deg   = (int*)alloc((size_t)NN * sizeof(int));       // contiguous
    int*   bcnt  = (int*)alloc((size_t)NBUCK * sizeof(int));    // with deg
    int*   incl  = (int*)alloc((size_t)NB1 * SCB * sizeof(int));
    int*   bsum  = (int*)alloc((size_t)NB1 * sizeof(int));
    int*   off   = (int*)alloc((size_t)(NN + 1) * sizeof(int));
    int*   cur   = (int*)alloc((size_t)NN * sizeof(int));
    unsigned int*   staging = (unsigned int*)alloc((size_t)NBUCK * CAP * sizeof(unsigned int));
    unsigned short* ssort   = (unsigned short*)alloc((size_t)EE * sizeof(unsigned short));
    h8*    Wp0   = (h8*)alloc(2048 * sizeof(h8));
    h8*    Wp1   = (h8*)alloc(1024 * sizeof(h8));

    // zero deg + bcnt in one memset (deg padded to 256B, bcnt adjacent)
    size_t zbytes = (((size_t)NN * sizeof(int) + 255) & ~(size_t)255)
                  + (size_t)NBUCK * sizeof(int);
    hipMemsetAsync(deg, 0, zbytes, stream);

    k_bin<<<(EE + CHUNK - 1) / CHUNK, 256, 0, stream>>>(src, dst, deg, bcnt, staging);
    k_scan1<<<NB1, SCB, 0, stream>>>(deg, incl, bsum, W0, W1, Wp0, Wp1);
    k_scan2<<<1, 128, 0, stream>>>(bsum, NB1);
    k_scan3<<<(NN + 255) / 256, 256, 0, stream>>>(incl, bsum, deg, off, cur);
    k_final<<<NBUCK, 256, 0, stream>>>(staging, bcnt, off, cur, ssort);
    k_gemm0<<<(NN + 63) / 64, 256, 0, stream>>>(h, Wp0, al0, ar0, feat0, el0, er0);
    k_agg0<<<NN / 4, 256, 0, stream>>>(off, ssort, el0, er0, feat0, b0, g0, be0, x);
    k_gemm1<<<(NN + 63) / 64, 256, 0, stream>>>(x, Wp1, al1, ar1, feat1, el1, er1);
    k_agg1<<<NN / 4, 256, 0, stream>>>(off, ssort, el1, er1, feat1, b1, g1, be1, out);
}

// Round 10
// 216.733 us; speedup vs baseline: 2.4662x; 1.1776x over previous
//
#include <hip/hip_runtime.h>
#include <hip/hip_bf16.h>

// GAT 2-layer: N=50000, E=800000, DN=128, D=64, H=2 (layer0). All f32 I/O.
// R10: CSR build re-parallelized. k_bin v2: 196 blocks x 1024 thr (int4
// edge loads, 4 edges/thr), NO deg atomics (degrees come free from
// k_final's LDS histogram); bcnt padded 1 counter/cache-line so block
// claims don't ping-pong lines across XCDs. k_scanB (1 block) scans the
// 196 bucket totals + packs W; k_final counting-sorts each bucket in LDS
// AND writes off[n+1] coalesced. deg/cur/incl/bsum + 2 dispatches deleted.
// Rest as R9: MFMA f16 GEMMs (LDS union), one-wave-per-node agg0/agg1,
// f16 feat0/feat1/x, no-max softmax, u16 ssort.

#define NN 50000
#define EE 800000
#define NBUCK 196            // ceil(NN/256)
#define CHUNK 4096           // edges per k_bin block
#define CAP 8192             // staging slots per bucket (mean 4096, std ~64)

typedef _Float16 h4 __attribute__((ext_vector_type(4)));
typedef _Float16 h8 __attribute__((ext_vector_type(8)));
typedef float f32x4 __attribute__((ext_vector_type(4)));

// ---- pass 1: bin edges into fixed-base bucket staging ---------------------
// bcntp is padded: counter b lives at bcntp[b*16] (own cache line).
__global__ __launch_bounds__(1024) void k_bin(
    const int* __restrict__ src, const int* __restrict__ dst,
    int* __restrict__ bcntp, unsigned int* __restrict__ staging)
{
    __shared__ int hist[NBUCK];
    __shared__ int rnk[NBUCK];
    __shared__ int gbase[NBUCK];
    int tid = threadIdx.x;
    int base = blockIdx.x * CHUNK;
    int m = EE - base; if (m > CHUNK) m = CHUNK;   // always multiple of 4
    if (tid < NBUCK) { hist[tid] = 0; rnk[tid] = 0; }
    __syncthreads();
    int e0 = tid * 4;
    bool act = e0 < m;
    int4 d4 = {0, 0, 0, 0}, s4 = {0, 0, 0, 0};
    if (act) {
        d4 = ((const int4*)(dst + base))[tid];
        s4 = ((const int4*)(src + base))[tid];
        atomicAdd(&hist[d4.x >> 8], 1);
        atomicAdd(&hist[d4.y >> 8], 1);
        atomicAdd(&hist[d4.z >> 8], 1);
        atomicAdd(&hist[d4.w >> 8], 1);
    }
    __syncthreads();
    if (tid < NBUCK && hist[tid])
        gbase[tid] = atomicAdd(&bcntp[tid * 16], hist[tid]);
    __syncthreads();
    if (act) {
        int d[4] = {d4.x, d4.y, d4.z, d4.w};
        int s[4] = {s4.x, s4.y, s4.z, s4.w};
#pragma unroll
        for (int k = 0; k < 4; ++k) {
            int b = d[k] >> 8;
            int r = atomicAdd(&rnk[b], 1);
            int slot = gbase[b] + r;
            if (slot < CAP)    // statistically never exceeded; memory-safety clamp
                staging[(size_t)b * CAP + slot] =
                    ((unsigned)(d[k] & 255) << 16) | (unsigned)s[k];
        }
    }
}

// ---- scan of bucket totals (196) + W pack (fused; independent) ------------
// Wp[t][kk][lane][j] = W[(kk*32 + (lane>>4)*8 + j)][t*16 + (lane&15)]  (f16)
__global__ __launch_bounds__(1024) void k_scanB(
    const int* __restrict__ bcntp, int* __restrict__ bexc, int* __restrict__ off,
    const float* __restrict__ W0, const float* __restrict__ W1,
    h8* __restrict__ Wp0, h8* __restrict__ Wp1)
{
    int t = threadIdx.x;
    for (int idx = t; idx < 3072; idx += 1024) {
        if (idx < 2048) {
            int lane = idx & 63, kk = (idx >> 6) & 3, tt = idx >> 8;
            int q = lane >> 4, c = lane & 15;
            h8 v;
#pragma unroll
            for (int j = 0; j < 8; ++j)
                v[j] = (_Float16)W0[(kk * 32 + q * 8 + j) * 128 + tt * 16 + c];
            Wp0[idx] = v;
        } else {
            int i2 = idx - 2048;
            int lane = i2 & 63, kk = (i2 >> 6) & 3, tt = i2 >> 8;
            int q = lane >> 4, c = lane & 15;
            h8 v;
#pragma unroll
            for (int j = 0; j < 8; ++j)
                v[j] = (_Float16)W1[(kk * 32 + q * 8 + j) * 64 + tt * 16 + c];
            Wp1[i2] = v;
        }
    }
    __shared__ int s[256];
    int v = 0;
    if (t < 256) { v = (t < NBUCK) ? bcntp[t * 16] : 0; s[t] = v; }
    __syncthreads();
    for (int o = 1; o < 256; o <<= 1) {
        int u = 0;
        if (t < 256 && t >= o) u = s[t - o];
        __syncthreads();
        if (t < 256) s[t] += u;
        __syncthreads();
    }
    if (t < NBUCK) bexc[t] = s[t] - v;   // exclusive scan
    if (t == 0) off[0] = 0;
}

// ---- pass 2: LDS counting sort per bucket; writes off[n+1] + u16 ssort ----
__global__ __launch_bounds__(256) void k_final(
    const unsigned int* __restrict__ staging, const int* __restrict__ bcntp,
    const int* __restrict__ bexc, int* __restrict__ off,
    unsigned short* __restrict__ ssort)
{
    int b = blockIdx.x;
    int tid = threadIdx.x;
    int cnt = bcntp[b * 16]; if (cnt > CAP) cnt = CAP;
    size_t base = (size_t)b * CAP;
    int lo = bexc[b];
    __shared__ unsigned short buf[CAP];
    __shared__ int hist[256];
    __shared__ int sc[256];
    hist[tid] = 0;
    __syncthreads();
    for (int i = tid; i < cnt; i += 256)
        atomicAdd(&hist[staging[base + i] >> 16], 1);
    __syncthreads();
    int hv = hist[tid];
    sc[tid] = hv;
    __syncthreads();
    for (int o = 1; o < 256; o <<= 1) {
        int u = (tid >= o) ? sc[tid - o] : 0;
        __syncthreads();
        sc[tid] += u;
        __syncthreads();
    }
    // CSR offsets for this bucket's nodes (coalesced)
    int nlo = b << 8;
    int nrem = NN - nlo; if (nrem > 256) nrem = 256;
    if (tid < nrem) off[nlo + tid + 1] = lo + sc[tid];
    hist[tid] = sc[tid] - hv;          // exclusive offset -> LDS cursor
    __syncthreads();
    for (int i = tid; i < cnt; i += 256) {
        unsigned rec = staging[base + i];
        int r = atomicAdd(&hist[rec >> 16], 1);
        buf[r] = (unsigned short)(rec & 0xFFFFu);
    }
    __syncthreads();
    for (int i = tid; i < cnt; i += 256)
        ssort[lo + i] = buf[i];
}

// ---- layer-0 GEMM (MFMA): feat0 = h @ W0 (+ el0/er0). 64 nodes/block. ----
#define HS_STRIDE 136   // 128 + 8 f16 pad
#define D0_STRIDE 132   // 128 + 4 f32 pad
__global__ __launch_bounds__(256) void k_gemm0(
    const float* __restrict__ h, const h8* __restrict__ Wp0,
    const float* __restrict__ al0, const float* __restrict__ ar0,
    _Float16* __restrict__ feat0, float* __restrict__ el0, float* __restrict__ er0)
{
    int tid = threadIdx.x;
    int n0 = blockIdx.x * 64;
    __shared__ char smem[64 * D0_STRIDE * 4];      // union: hs (f16) then ds2 (f32)
    _Float16* hs = (_Float16*)smem;
    float* ds2 = (float*)smem;
#pragma unroll
    for (int r = 0; r < 8; ++r) {
        int f = tid + 256 * r;
        int node = f >> 5, kc = f & 31;
        int n = n0 + node;
        float4 v = {0.f, 0.f, 0.f, 0.f};
        if (n < NN) v = ((const float4*)h)[(size_t)n * 32 + kc];
        h4 hv; hv[0] = (_Float16)v.x; hv[1] = (_Float16)v.y;
        hv[2] = (_Float16)v.z; hv[3] = (_Float16)v.w;
        *(h4*)&hs[node * HS_STRIDE + kc * 4] = hv;
    }
    __syncthreads();
    int w = tid >> 6, lane = tid & 63;
    int m = lane & 15, q = lane >> 4;
    h8 aF[4];
#pragma unroll
    for (int kk = 0; kk < 4; ++kk)
        aF[kk] = *(const h8*)&hs[(w * 16 + m) * HS_STRIDE + kk * 32 + q * 8];
    __syncthreads();                                // hs dead; reuse as ds2
#pragma unroll
    for (int t = 0; t < 8; ++t) {
        f32x4 acc = {0.f, 0.f, 0.f, 0.f};
#pragma unroll
        for (int kk = 0; kk < 4; ++kk) {
            h8 bF = Wp0[(t * 4 + kk) * 64 + lane];
            acc = __builtin_amdgcn_mfma_f32_16x16x32_f16(aF[kk], bF, acc, 0, 0, 0);
        }
#pragma unroll
        for (int r = 0; r < 4; ++r)
            ds2[(w * 16 + q * 4 + r) * D0_STRIDE + t * 16 + m] = acc[r];
    }
    __syncthreads();
#pragma unroll
    for (int r = 0; r < 4; ++r) {
        int f = tid + 256 * r;
        int node = f >> 4, c8 = f & 15;
        int n = n0 + node;
        if (n < NN) {
            float4 a = *(const float4*)&ds2[node * D0_STRIDE + c8 * 8];
            float4 b = *(const float4*)&ds2[node * D0_STRIDE + c8 * 8 + 4];
            h8 v;
            v[0] = (_Float16)a.x; v[1] = (_Float16)a.y; v[2] = (_Float16)a.z; v[3] = (_Float16)a.w;
            v[4] = (_Float16)b.x; v[5] = (_Float16)b.y; v[6] = (_Float16)b.z; v[7] = (_Float16)b.w;
            ((h8*)feat0)[(size_t)n * 16 + c8] = v;
        }
    }
    {
        int node = tid >> 2, qq = tid & 3;
        int n = n0 + node;
        float pl = 0.f, pr = 0.f;
#pragma unroll
        for (int i = 0; i < 8; ++i) {
            float4 v = *(const float4*)&ds2[node * D0_STRIDE + qq * 32 + i * 4];
            float4 a = ((const float4*)al0)[qq * 8 + i];
            float4 r = ((const float4*)ar0)[qq * 8 + i];
            pl += v.x * a.x + v.y * a.y + v.z * a.z + v.w * a.w;
            pr += v.x * r.x + v.y * r.y + v.z * r.z + v.w * r.w;
        }
        pl += __shfl_xor(pl, 1, 4); pr += __shfl_xor(pr, 1, 4);
        if (n < NN) {
            if (qq == 0) { el0[n * 2] = pl;     er0[n * 2] = pr; }
            if (qq == 2) { el0[n * 2 + 1] = pl; er0[n * 2 + 1] = pr; }
        }
    }
}

// ------- layer-0 agg + bias + relu + LN -> x (f16). ONE WAVE PER NODE. -----
__global__ __launch_bounds__(256) void k_agg0(
    const int* __restrict__ off, const unsigned short* __restrict__ ssort,
    const float* __restrict__ el0, const float* __restrict__ er0,
    const _Float16* __restrict__ feat0, const float* __restrict__ b0,
    const float* __restrict__ g0, const float* __restrict__ be0,
    _Float16* __restrict__ x)
{
    int w = threadIdx.x >> 6, lane = threadIdx.x & 63;
    int grp = lane >> 4, c = lane & 15;
    int n = blockIdx.x * 4 + w;                 // NN = 12500*4 exact
    int beg = off[n], end = off[n + 1];
    float2 ern2 = ((const float2*)er0)[n];
    const h8* fb = (const h8*)feat0;            // row = 16 h8 chunks
    float acc[8] = {};
    float den0 = 0.f, den1 = 0.f;
    for (int cb = beg; cb < end; cb += 64) {
        int m = end - cb; if (m > 64) m = 64;
        int s_reg = 0; float p0 = 0.f, p1 = 0.f;
        if (lane < m) {
            s_reg = ssort[cb + lane];
            float2 el2 = ((const float2*)el0)[s_reg];
            float v0 = el2.x + ern2.x; v0 = v0 > 0.f ? v0 : 0.2f * v0;
            float v1 = el2.y + ern2.y; v1 = v1 > 0.f ? v1 : 0.2f * v1;
            p0 = __expf(v0); p1 = __expf(v1);
        }
        den0 += p0; den1 += p1;
        for (int i = 0; i < m; i += 4) {
            int j = i + grp;
            int   sj = __shfl(s_reg, j);
            float q0 = __shfl(p0, j);
            float q1 = __shfl(p1, j);
            float qj = (c < 8) ? q0 : q1;
            if (j >= m) qj = 0.f;
            h8 f8 = fb[(size_t)sj * 16 + c];
#pragma unroll
            for (int k = 0; k < 8; ++k) acc[k] = fmaf(qj, (float)f8[k], acc[k]);
        }
    }
#pragma unroll
    for (int k = 0; k < 8; ++k) {
        acc[k] += __shfl_down(acc[k], 32);
        acc[k] += __shfl_down(acc[k], 16);
    }
#pragma unroll
    for (int o = 32; o > 0; o >>= 1) { den0 += __shfl_down(den0, o); den1 += __shfl_down(den1, o); }
    den0 = __shfl(den0, 0); den1 = __shfl(den1, 0);
    float den = (c < 8) ? den0 : den1;
    float inv = (end > beg) ? 1.f / den : 0.f;
    float4 ba = ((const float4*)b0)[c * 2];
    float4 bb = ((const float4*)b0)[c * 2 + 1];
    float val[8];
    val[0] = fmaxf(acc[0] * inv + ba.x, 0.f);
    val[1] = fmaxf(acc[1] * inv + ba.y, 0.f);
    val[2] = fmaxf(acc[2] * inv + ba.z, 0.f);
    val[3] = fmaxf(acc[3] * inv + ba.w, 0.f);
    val[4] = fmaxf(acc[4] * inv + bb.x, 0.f);
    val[5] = fmaxf(acc[5] * inv + bb.y, 0.f);
    val[6] = fmaxf(acc[6] * inv + bb.z, 0.f);
    val[7] = fmaxf(acc[7] * inv + bb.w, 0.f);
    float s1 = 0.f, s2 = 0.f;
#pragma unroll
    for (int k = 0; k < 8; ++k) { s1 += val[k]; s2 += val[k] * val[k]; }
#pragma unroll
    for (int o = 1; o < 16; o <<= 1) { s1 += __shfl_xor(s1, o, 16); s2 += __shfl_xor(s2, o, 16); }
    float mu = s1 * (1.f / 128.f);
    float var = s2 * (1.f / 128.f) - mu * mu;
    float rs = rsqrtf(var + 1e-5f);
    if (grp == 0) {
        float4 ga = ((const float4*)g0)[c * 2];
        float4 gb = ((const float4*)g0)[c * 2 + 1];
        float4 ea = ((const float4*)be0)[c * 2];
        float4 eb = ((const float4*)be0)[c * 2 + 1];
        h8 xv;
        xv[0] = (_Float16)((val[0] - mu) * rs * ga.x + ea.x);
        xv[1] = (_Float16)((val[1] - mu) * rs * ga.y + ea.y);
        xv[2] = (_Float16)((val[2] - mu) * rs * ga.z + ea.z);
        xv[3] = (_Float16)((val[3] - mu) * rs * ga.w + ea.w);
        xv[4] = (_Float16)((val[4] - mu) * rs * gb.x + eb.x);
        xv[5] = (_Float16)((val[5] - mu) * rs * gb.y + eb.y);
        xv[6] = (_Float16)((val[6] - mu) * rs * gb.z + eb.z);
        xv[7] = (_Float16)((val[7] - mu) * rs * gb.w + eb.w);
        ((h8*)x)[(size_t)n * 16 + c] = xv;
    }
}

// ---- layer-1 GEMM (MFMA): feat1 = x @ W1 (+ el1/er1). 64 nodes/block. ----
#define D1_STRIDE 68    // 64 + 4 f32 pad
__global__ __launch_bounds__(256) void k_gemm1(
    const _Float16* __restrict__ x, const h8* __restrict__ Wp1,
    const float* __restrict__ al1, const float* __restrict__ ar1,
    _Float16* __restrict__ feat1, float* __restrict__ el1, float* __restrict__ er1)
{
    int tid = threadIdx.x;
    int n0 = blockIdx.x * 64;
    __shared__ char smem[64 * HS_STRIDE * 2 > 64 * D1_STRIDE * 4
                         ? 64 * HS_STRIDE * 2 : 64 * D1_STRIDE * 4];
    _Float16* xs = (_Float16*)smem;
    float* ds2 = (float*)smem;
#pragma unroll
    for (int r = 0; r < 4; ++r) {
        int f = tid + 256 * r;
        int node = f >> 4, kc = f & 15;
        int n = n0 + node;
        h8 v = {};
        if (n < NN) v = ((const h8*)x)[(size_t)n * 16 + kc];
        *(h8*)&xs[node * HS_STRIDE + kc * 8] = v;
    }
    __syncthreads();
    int w = tid >> 6, lane = tid & 63;
    int m = lane & 15, q = lane >> 4;
    h8 aF[4];
#pragma unroll
    for (int kk = 0; kk < 4; ++kk)
        aF[kk] = *(const h8*)&xs[(w * 16 + m) * HS_STRIDE + kk * 32 + q * 8];
    __syncthreads();                                // xs dead; reuse as ds2
#pragma unroll
    for (int t = 0; t < 4; ++t) {
        f32x4 acc = {0.f, 0.f, 0.f, 0.f};
#pragma unroll
        for (int kk = 0; kk < 4; ++kk) {
            h8 bF = Wp1[(t * 4 + kk) * 64 + lane];
            acc = __builtin_amdgcn_mfma_f32_16x16x32_f16(aF[kk], bF, acc, 0, 0, 0);
        }
#pragma unroll
        for (int r = 0; r < 4; ++r)
            ds2[(w * 16 + q * 4 + r) * D1_STRIDE + t * 16 + m] = acc[r];
    }
    __syncthreads();
#pragma unroll
    for (int r = 0; r < 2; ++r) {
        int f = tid + 256 * r;
        int node = f >> 3, c8 = f & 7;
        int n = n0 + node;
        if (n < NN) {
            float4 a = *(const float4*)&ds2[node * D1_STRIDE + c8 * 8];
            float4 b = *(const float4*)&ds2[node * D1_STRIDE + c8 * 8 + 4];
            h8 v;
            v[0] = (_Float16)a.x; v[1] = (_Float16)a.y; v[2] = (_Float16)a.z; v[3] = (_Float16)a.w;
            v[4] = (_Float16)b.x; v[5] = (_Float16)b.y; v[6] = (_Float16)b.z; v[7] = (_Float16)b.w;
            ((h8*)feat1)[(size_t)n * 8 + c8] = v;
        }
    }
    {
        int node = tid >> 2, qq = tid & 3;
        int n = n0 + node;
        float pl = 0.f, pr = 0.f;
#pragma unroll
        for (int i = 0; i < 4; ++i) {
            float4 v = *(const float4*)&ds2[node * D1_STRIDE + qq * 16 + i * 4];
            float4 a = ((const float4*)al1)[qq * 4 + i];
            float4 r = ((const float4*)ar1)[qq * 4 + i];
            pl += v.x * a.x + v.y * a.y + v.z * a.z + v.w * a.w;
            pr += v.x * r.x + v.y * r.y + v.z * r.z + v.w * r.w;
        }
        pl += __shfl_xor(pl, 1, 4); pr += __shfl_xor(pr, 1, 4);
        pl += __shfl_xor(pl, 2, 4); pr += __shfl_xor(pr, 2, 4);
        if (qq == 0 && n < NN) { el1[n] = pl; er1[n] = pr; }
    }
}

// ------- layer-1 agg + bias + LN -> out (f32). 1 node per wave. ------------
__global__ __launch_bounds__(256) void k_agg1(
    const int* __restrict__ off, const unsigned short* __restrict__ ssort,
    const float* __restrict__ el1, const float* __restrict__ er1,
    const _Float16* __restrict__ feat1, const float* __restrict__ b1,
    const float* __restrict__ g1, const float* __restrict__ be1,
    float* __restrict__ out)
{
    int w = threadIdx.x >> 6, lane = threadIdx.x & 63;
    int grp = lane >> 3, c = lane & 7;
    int n = blockIdx.x * 4 + w;
    int beg = off[n], end = off[n + 1];
    float ern = er1[n];
    const h8* fb = (const h8*)feat1;         // row = 8 h8
    float acc[8] = {};
    float den = 0.f;
    for (int cb = beg; cb < end; cb += 64) {
        int m = end - cb; if (m > 64) m = 64;
        int s_reg = 0; float p_reg = 0.f;
        if (lane < m) {
            s_reg = ssort[cb + lane];
            float v = el1[s_reg] + ern;
            v = v > 0.f ? v : 0.2f * v;
            p_reg = __expf(v);
        }
        den += p_reg;
        for (int i = 0; i < m; i += 8) {
            int j = i + grp;
            int   sj = __shfl(s_reg, j);
            float qj = __shfl(p_reg, j);
            if (j >= m) qj = 0.f;
            h8 f8 = fb[(size_t)sj * 8 + c];
#pragma unroll
            for (int k = 0; k < 8; ++k) acc[k] = fmaf(qj, (float)f8[k], acc[k]);
        }
    }
#pragma unroll
    for (int k = 0; k < 8; ++k) {
        acc[k] += __shfl_down(acc[k], 32);
        acc[k] += __shfl_down(acc[k], 16);
        acc[k] += __shfl_down(acc[k], 8);
    }
#pragma unroll
    for (int o = 32; o > 0; o >>= 1) den += __shfl_down(den, o);
    den = __shfl(den, 0);
    float inv = (end > beg) ? 1.f / den : 0.f;
    float4 ba = ((const float4*)b1)[c * 2];
    float4 bb = ((const float4*)b1)[c * 2 + 1];
    float val[8];
    val[0] = acc[0] * inv + ba.x; val[1] = acc[1] * inv + ba.y;
    val[2] = acc[2] * inv + ba.z; val[3] = acc[3] * inv + ba.w;
    val[4] = acc[4] * inv + bb.x; val[5] = acc[5] * inv + bb.y;
    val[6] = acc[6] * inv + bb.z; val[7] = acc[7] * inv + bb.w;
    float s1 = 0.f, s2 = 0.f;
#pragma unroll
    for (int k = 0; k < 8; ++k) { s1 += val[k]; s2 += val[k] * val[k]; }
#pragma unroll
    for (int o = 1; o < 8; o <<= 1) { s1 += __shfl_xor(s1, o, 8); s2 += __shfl_xor(s2, o, 8); }
    float mu = s1 * (1.f / 64.f);
    float var = s2 * (1.f / 64.f) - mu * mu;
    float rs = rsqrtf(var + 1e-5f);
    if (lane < 8) {
        float4 ga = ((const float4*)g1)[c * 2];
        float4 gb = ((const float4*)g1)[c * 2 + 1];
        float4 ea = ((const float4*)be1)[c * 2];
        float4 eb = ((const float4*)be1)[c * 2 + 1];
        float4 oa, ob;
        oa.x = (val[0] - mu) * rs * ga.x + ea.x;
        oa.y = (val[1] - mu) * rs * ga.y + ea.y;
        oa.z = (val[2] - mu) * rs * ga.z + ea.z;
        oa.w = (val[3] - mu) * rs * ga.w + ea.w;
        ob.x = (val[4] - mu) * rs * gb.x + eb.x;
        ob.y = (val[5] - mu) * rs * gb.y + eb.y;
        ob.z = (val[6] - mu) * rs * gb.z + eb.z;
        ob.w = (val[7] - mu) * rs * gb.w + eb.w;
        float4* orow = (float4*)(out + (size_t)n * 64);
        orow[c * 2] = oa;
        orow[c * 2 + 1] = ob;
    }
}

extern "C" void kernel_launch(void* const* d_in, const int* in_sizes, int n_in,
                              void* d_out, int out_size, void* d_ws, size_t ws_size,
                              hipStream_t stream)
{
    const float* h   = (const float*)d_in[0];
    const float* W0  = (const float*)d_in[1];
    const float* al0 = (const float*)d_in[2];
    const float* ar0 = (const float*)d_in[3];
    const float* b0  = (const float*)d_in[4];
    const float* W1  = (const float*)d_in[5];
    const float* al1 = (const float*)d_in[6];
    const float* ar1 = (const float*)d_in[7];
    const float* b1  = (const float*)d_in[8];
    const float* g0  = (const float*)d_in[9];
    const float* be0 = (const float*)d_in[10];
    const float* g1  = (const float*)d_in[11];
    const float* be1 = (const float*)d_in[12];
    const int*   src = (const int*)d_in[13];
    const int*   dst = (const int*)d_in[14];
    float* out = (float*)d_out;

    char* p = (char*)d_ws;
    auto alloc = [&](size_t bytes) -> char* {
        char* r = p;
        p += (bytes + 255) & ~(size_t)255;
        return r;
    };
    _Float16* feat0 = (_Float16*)alloc((size_t)NN * 128 * sizeof(_Float16));
    float* el0   = (float*)alloc((size_t)NN * 2 * sizeof(float));
    float* er0   = (float*)alloc((size_t)NN * 2 * sizeof(float));
    _Float16* x  = (_Float16*)alloc((size_t)NN * 128 * sizeof(_Float16));
    _Float16* feat1 = (_Float16*)alloc((size_t)NN * 64 * sizeof(_Float16));
    float* el1   = (float*)alloc((size_t)NN * sizeof(float));
    float* er1   = (float*)alloc((size_t)NN * sizeof(float));
    int*   bcntp = (int*)alloc((size_t)NBUCK * 16 * sizeof(int));   // padded: 1/line
    int*   bexc  = (int*)alloc((size_t)NBUCK * sizeof(int));
    int*   off   = (int*)alloc((size_t)(NN + 1) * sizeof(int));
    unsigned int*   staging = (unsigned int*)alloc((size_t)NBUCK * CAP * sizeof(unsigned int));
    unsigned short* ssort   = (unsigned short*)alloc((size_t)EE * sizeof(unsigned short));
    h8*    Wp0   = (h8*)alloc(2048 * sizeof(h8));
    h8*    Wp1   = (h8*)alloc(1024 * sizeof(h8));

    hipMemsetAsync(bcntp, 0, (size_t)NBUCK * 16 * sizeof(int), stream);

    k_bin<<<(EE + CHUNK - 1) / CHUNK, 1024, 0, stream>>>(src, dst, bcntp, staging);
    k_scanB<<<1, 1024, 0, stream>>>(bcntp, bexc, off, W0, W1, Wp0, Wp1);
    k_final<<<NBUCK, 256, 0, stream>>>(staging, bcntp, bexc, off, ssort);
    k_gemm0<<<(NN + 63) / 64, 256, 0, stream>>>(h, Wp0, al0, ar0, feat0, el0, er0);
    k_agg0<<<NN / 4, 256, 0, stream>>>(off, ssort, el0, er0, feat0, b0, g0, be0, x);
    k_gemm1<<<(NN + 63) / 64, 256, 0, stream>>>(x, Wp1, al1, ar1, feat1, el1, er1);
    k_agg1<<<NN / 4, 256, 0, stream>>>(off, ssort, el1, er1, feat1, b1, g1, be1, out);
}

// Round 11
// 216.623 us; speedup vs baseline: 2.4675x; 1.0005x over previous
//
#include <hip/hip_runtime.h>
#include <hip/hip_bf16.h>

// GAT 2-layer: N=50000, E=800000, DN=128, D=64, H=2 (layer0). All f32 I/O.
// R11: pipeline fusion. (1) agg0+gemm1 fused: 64-node tile per 1024-thr
// block; 16 waves aggregate 4 nodes each (one-wave-per-node), x written
// as f16 directly into MFMA staging LDS (global x deleted), then the same
// block runs the W1 MFMA + feat1/el1/er1 epilogue. (2) k_scanB deleted:
// W-pack rides on k_bin (+3 blocks), bucket scan rides on gemm0 (+1 block).
// 8 -> 6 dispatches. Rest as R10: 1024-thr k_bin (int4, padded bcnt),
// LDS counting-sort k_final (writes off), MFMA f16 GEMMs, u16 ssort,
// f16 feat0/feat1, no-max softmax.

#define NN 50000
#define EE 800000
#define NBUCK 196            // ceil(NN/256)
#define CHUNK 4096           // edges per k_bin block
#define CAP 8192             // staging slots per bucket (mean 4096, std ~64)
#define GB0 ((NN + 63) / 64) // 782 gemm0 blocks; block GB0 = bucket scan

typedef _Float16 h4 __attribute__((ext_vector_type(4)));
typedef _Float16 h8 __attribute__((ext_vector_type(8)));
typedef float f32x4 __attribute__((ext_vector_type(4)));

// ---- pass 1: bin edges into fixed-base bucket staging (+ W pack blocks) ---
// bcntp padded: counter b at bcntp[b*16] (own cache line).
// Wp[t][kk][lane][j] = W[(kk*32 + (lane>>4)*8 + j)][t*16 + (lane&15)]  (f16)
__global__ __launch_bounds__(1024) void k_bin(
    const int* __restrict__ src, const int* __restrict__ dst,
    int* __restrict__ bcntp, unsigned int* __restrict__ staging,
    const float* __restrict__ W0, const float* __restrict__ W1,
    h8* __restrict__ Wp0, h8* __restrict__ Wp1)
{
    int tid = threadIdx.x;
    if (blockIdx.x >= (EE + CHUNK - 1) / CHUNK) {
        // W-pack blocks
        int idx = (blockIdx.x - (EE + CHUNK - 1) / CHUNK) * 1024 + tid;
        if (idx < 2048) {
            int lane = idx & 63, kk = (idx >> 6) & 3, tt = idx >> 8;
            int q = lane >> 4, c = lane & 15;
            h8 v;
#pragma unroll
            for (int j = 0; j < 8; ++j)
                v[j] = (_Float16)W0[(kk * 32 + q * 8 + j) * 128 + tt * 16 + c];
            Wp0[idx] = v;
        } else if (idx < 3072) {
            int i2 = idx - 2048;
            int lane = i2 & 63, kk = (i2 >> 6) & 3, tt = i2 >> 8;
            int q = lane >> 4, c = lane & 15;
            h8 v;
#pragma unroll
            for (int j = 0; j < 8; ++j)
                v[j] = (_Float16)W1[(kk * 32 + q * 8 + j) * 64 + tt * 16 + c];
            Wp1[i2] = v;
        }
        return;
    }
    __shared__ int hist[NBUCK];
    __shared__ int rnk[NBUCK];
    __shared__ int gbase[NBUCK];
    int base = blockIdx.x * CHUNK;
    int m = EE - base; if (m > CHUNK) m = CHUNK;   // multiple of 4
    if (tid < NBUCK) { hist[tid] = 0; rnk[tid] = 0; }
    __syncthreads();
    int e0 = tid * 4;
    bool act = e0 < m;
    int4 d4 = {0, 0, 0, 0}, s4 = {0, 0, 0, 0};
    if (act) {
        d4 = ((const int4*)(dst + base))[tid];
        s4 = ((const int4*)(src + base))[tid];
        atomicAdd(&hist[d4.x >> 8], 1);
        atomicAdd(&hist[d4.y >> 8], 1);
        atomicAdd(&hist[d4.z >> 8], 1);
        atomicAdd(&hist[d4.w >> 8], 1);
    }
    __syncthreads();
    if (tid < NBUCK && hist[tid])
        gbase[tid] = atomicAdd(&bcntp[tid * 16], hist[tid]);
    __syncthreads();
    if (act) {
        int d[4] = {d4.x, d4.y, d4.z, d4.w};
        int s[4] = {s4.x, s4.y, s4.z, s4.w};
#pragma unroll
        for (int k = 0; k < 4; ++k) {
            int b = d[k] >> 8;
            int r = atomicAdd(&rnk[b], 1);
            int slot = gbase[b] + r;
            if (slot < CAP)    // statistically never; memory-safety clamp
                staging[(size_t)b * CAP + slot] =
                    ((unsigned)(d[k] & 255) << 16) | (unsigned)s[k];
        }
    }
}

// ---- layer-0 GEMM (MFMA) + bucket-scan block. 64 nodes/block. -------------
#define HS_STRIDE 136   // 128 + 8 f16 pad
#define D0_STRIDE 132   // 128 + 4 f32 pad
__global__ __launch_bounds__(256) void k_gemm0(
    const float* __restrict__ h, const h8* __restrict__ Wp0,
    const float* __restrict__ al0, const float* __restrict__ ar0,
    _Float16* __restrict__ feat0, float* __restrict__ el0, float* __restrict__ er0,
    const int* __restrict__ bcntp, int* __restrict__ bexc, int* __restrict__ off)
{
    int tid = threadIdx.x;
    __shared__ char smem[64 * D0_STRIDE * 4];      // union: hs (f16) / ds2 (f32) / scan
    if (blockIdx.x == GB0) {
        // bucket exclusive scan (196 values)
        int* s = (int*)smem;
        int v = (tid < NBUCK) ? bcntp[tid * 16] : 0;
        s[tid] = v;
        __syncthreads();
        for (int o = 1; o < 256; o <<= 1) {
            int u = (tid >= o) ? s[tid - o] : 0;
            __syncthreads();
            s[tid] += u;
            __syncthreads();
        }
        if (tid < NBUCK) bexc[tid] = s[tid] - v;
        if (tid == 0) off[0] = 0;
        return;
    }
    _Float16* hs = (_Float16*)smem;
    float* ds2 = (float*)smem;
    int n0 = blockIdx.x * 64;
#pragma unroll
    for (int r = 0; r < 8; ++r) {
        int f = tid + 256 * r;
        int node = f >> 5, kc = f & 31;
        int n = n0 + node;
        float4 v = {0.f, 0.f, 0.f, 0.f};
        if (n < NN) v = ((const float4*)h)[(size_t)n * 32 + kc];
        h4 hv; hv[0] = (_Float16)v.x; hv[1] = (_Float16)v.y;
        hv[2] = (_Float16)v.z; hv[3] = (_Float16)v.w;
        *(h4*)&hs[node * HS_STRIDE + kc * 4] = hv;
    }
    __syncthreads();
    int w = tid >> 6, lane = tid & 63;
    int m = lane & 15, q = lane >> 4;
    h8 aF[4];
#pragma unroll
    for (int kk = 0; kk < 4; ++kk)
        aF[kk] = *(const h8*)&hs[(w * 16 + m) * HS_STRIDE + kk * 32 + q * 8];
    __syncthreads();                                // hs dead; reuse as ds2
#pragma unroll
    for (int t = 0; t < 8; ++t) {
        f32x4 acc = {0.f, 0.f, 0.f, 0.f};
#pragma unroll
        for (int kk = 0; kk < 4; ++kk) {
            h8 bF = Wp0[(t * 4 + kk) * 64 + lane];
            acc = __builtin_amdgcn_mfma_f32_16x16x32_f16(aF[kk], bF, acc, 0, 0, 0);
        }
#pragma unroll
        for (int r = 0; r < 4; ++r)
            ds2[(w * 16 + q * 4 + r) * D0_STRIDE + t * 16 + m] = acc[r];
    }
    __syncthreads();
#pragma unroll
    for (int r = 0; r < 4; ++r) {
        int f = tid + 256 * r;
        int node = f >> 4, c8 = f & 15;
        int n = n0 + node;
        if (n < NN) {
            float4 a = *(const float4*)&ds2[node * D0_STRIDE + c8 * 8];
            float4 b = *(const float4*)&ds2[node * D0_STRIDE + c8 * 8 + 4];
            h8 v;
            v[0] = (_Float16)a.x; v[1] = (_Float16)a.y; v[2] = (_Float16)a.z; v[3] = (_Float16)a.w;
            v[4] = (_Float16)b.x; v[5] = (_Float16)b.y; v[6] = (_Float16)b.z; v[7] = (_Float16)b.w;
            ((h8*)feat0)[(size_t)n * 16 + c8] = v;
        }
    }
    {
        int node = tid >> 2, qq = tid & 3;
        int n = n0 + node;
        float pl = 0.f, pr = 0.f;
#pragma unroll
        for (int i = 0; i < 8; ++i) {
            float4 v = *(const float4*)&ds2[node * D0_STRIDE + qq * 32 + i * 4];
            float4 a = ((const float4*)al0)[qq * 8 + i];
            float4 r = ((const float4*)ar0)[qq * 8 + i];
            pl += v.x * a.x + v.y * a.y + v.z * a.z + v.w * a.w;
            pr += v.x * r.x + v.y * r.y + v.z * r.z + v.w * r.w;
        }
        pl += __shfl_xor(pl, 1, 4); pr += __shfl_xor(pr, 1, 4);
        if (n < NN) {
            if (qq == 0) { el0[n * 2] = pl;     er0[n * 2] = pr; }
            if (qq == 2) { el0[n * 2 + 1] = pl; er0[n * 2 + 1] = pr; }
        }
    }
}

// ---- pass 2: LDS counting sort per bucket; writes off[n+1] + u16 ssort ----
__global__ __launch_bounds__(256) void k_final(
    const unsigned int* __restrict__ staging, const int* __restrict__ bcntp,
    const int* __restrict__ bexc, int* __restrict__ off,
    unsigned short* __restrict__ ssort)
{
    int b = blockIdx.x;
    int tid = threadIdx.x;
    int cnt = bcntp[b * 16]; if (cnt > CAP) cnt = CAP;
    size_t base = (size_t)b * CAP;
    int lo = bexc[b];
    __shared__ unsigned short buf[CAP];
    __shared__ int hist[256];
    __shared__ int sc[256];
    hist[tid] = 0;
    __syncthreads();
    for (int i = tid; i < cnt; i += 256)
        atomicAdd(&hist[staging[base + i] >> 16], 1);
    __syncthreads();
    int hv = hist[tid];
    sc[tid] = hv;
    __syncthreads();
    for (int o = 1; o < 256; o <<= 1) {
        int u = (tid >= o) ? sc[tid - o] : 0;
        __syncthreads();
        sc[tid] += u;
        __syncthreads();
    }
    int nlo = b << 8;
    int nrem = NN - nlo; if (nrem > 256) nrem = 256;
    if (tid < nrem) off[nlo + tid + 1] = lo + sc[tid];
    hist[tid] = sc[tid] - hv;          // exclusive offset -> LDS cursor
    __syncthreads();
    for (int i = tid; i < cnt; i += 256) {
        unsigned rec = staging[base + i];
        int r = atomicAdd(&hist[rec >> 16], 1);
        buf[r] = (unsigned short)(rec & 0xFFFFu);
    }
    __syncthreads();
    for (int i = tid; i < cnt; i += 256)
        ssort[lo + i] = buf[i];
}

// ---- FUSED layer-0 agg (+bias+relu+LN) -> LDS x -> layer-1 GEMM (MFMA) ----
// 1024 thr, 64 nodes/block. Agg: wave w16 handles nodes n0+w16*4+i (one
// wave per node, both heads). GEMM: wave w16 = (rowgroup rg = w16&3,
// col-tile t = w16>>2).
#define D1_STRIDE 68    // 64 + 4 f32 pad
__global__ __launch_bounds__(1024) void k_aggemm(
    const int* __restrict__ off, const unsigned short* __restrict__ ssort,
    const float* __restrict__ el0, const float* __restrict__ er0,
    const _Float16* __restrict__ feat0, const float* __restrict__ b0,
    const float* __restrict__ g0, const float* __restrict__ be0,
    const h8* __restrict__ Wp1, const float* __restrict__ al1,
    const float* __restrict__ ar1,
    _Float16* __restrict__ feat1, float* __restrict__ el1, float* __restrict__ er1)
{
    int tid = threadIdx.x;
    int w16 = tid >> 6, lane = tid & 63;
    int grp = lane >> 4, c = lane & 15;
    int n0 = blockIdx.x * 64;
    __shared__ char smem[64 * HS_STRIDE * 2 > 64 * D1_STRIDE * 4
                         ? 64 * HS_STRIDE * 2 : 64 * D1_STRIDE * 4];
    _Float16* xs = (_Float16*)smem;
    float* ds2 = (float*)smem;
    const h8* fb = (const h8*)feat0;            // row = 16 h8 chunks
    // ---- phase 1: aggregate 4 nodes per wave into xs (f16) ----
    for (int i = 0; i < 4; ++i) {
        int nl = w16 * 4 + i;
        int n = n0 + nl;
        if (n < NN) {
            int beg = off[n], end = off[n + 1];
            float2 ern2 = ((const float2*)er0)[n];
            float acc[8] = {};
            float den0 = 0.f, den1 = 0.f;
            for (int cb = beg; cb < end; cb += 64) {
                int m = end - cb; if (m > 64) m = 64;
                int s_reg = 0; float p0 = 0.f, p1 = 0.f;
                if (lane < m) {
                    s_reg = ssort[cb + lane];
                    float2 el2 = ((const float2*)el0)[s_reg];
                    float v0 = el2.x + ern2.x; v0 = v0 > 0.f ? v0 : 0.2f * v0;
                    float v1 = el2.y + ern2.y; v1 = v1 > 0.f ? v1 : 0.2f * v1;
                    p0 = __expf(v0); p1 = __expf(v1);
                }
                den0 += p0; den1 += p1;
                for (int ii = 0; ii < m; ii += 4) {
                    int j = ii + grp;
                    int   sj = __shfl(s_reg, j);
                    float q0 = __shfl(p0, j);
                    float q1 = __shfl(p1, j);
                    float qj = (c < 8) ? q0 : q1;
                    if (j >= m) qj = 0.f;
                    h8 f8 = fb[(size_t)sj * 16 + c];
#pragma unroll
                    for (int k = 0; k < 8; ++k) acc[k] = fmaf(qj, (float)f8[k], acc[k]);
                }
            }
#pragma unroll
            for (int k = 0; k < 8; ++k) {
                acc[k] += __shfl_down(acc[k], 32);
                acc[k] += __shfl_down(acc[k], 16);
            }
#pragma unroll
            for (int o = 32; o > 0; o >>= 1) { den0 += __shfl_down(den0, o); den1 += __shfl_down(den1, o); }
            den0 = __shfl(den0, 0); den1 = __shfl(den1, 0);
            float den = (c < 8) ? den0 : den1;
            float inv = (end > beg) ? 1.f / den : 0.f;
            float4 ba = ((const float4*)b0)[c * 2];
            float4 bb = ((const float4*)b0)[c * 2 + 1];
            float val[8];
            val[0] = fmaxf(acc[0] * inv + ba.x, 0.f);
            val[1] = fmaxf(acc[1] * inv + ba.y, 0.f);
            val[2] = fmaxf(acc[2] * inv + ba.z, 0.f);
            val[3] = fmaxf(acc[3] * inv + ba.w, 0.f);
            val[4] = fmaxf(acc[4] * inv + bb.x, 0.f);
            val[5] = fmaxf(acc[5] * inv + bb.y, 0.f);
            val[6] = fmaxf(acc[6] * inv + bb.z, 0.f);
            val[7] = fmaxf(acc[7] * inv + bb.w, 0.f);
            float s1 = 0.f, s2 = 0.f;
#pragma unroll
            for (int k = 0; k < 8; ++k) { s1 += val[k]; s2 += val[k] * val[k]; }
#pragma unroll
            for (int o = 1; o < 16; o <<= 1) { s1 += __shfl_xor(s1, o, 16); s2 += __shfl_xor(s2, o, 16); }
            float mu = s1 * (1.f / 128.f);
            float var = s2 * (1.f / 128.f) - mu * mu;
            float rs = rsqrtf(var + 1e-5f);
            if (grp == 0) {
                float4 ga = ((const float4*)g0)[c * 2];
                float4 gb = ((const float4*)g0)[c * 2 + 1];
                float4 ea = ((const float4*)be0)[c * 2];
                float4 eb = ((const float4*)be0)[c * 2 + 1];
                h8 xv;
                xv[0] = (_Float16)((val[0] - mu) * rs * ga.x + ea.x);
                xv[1] = (_Float16)((val[1] - mu) * rs * ga.y + ea.y);
                xv[2] = (_Float16)((val[2] - mu) * rs * ga.z + ea.z);
                xv[3] = (_Float16)((val[3] - mu) * rs * ga.w + ea.w);
                xv[4] = (_Float16)((val[4] - mu) * rs * gb.x + eb.x);
                xv[5] = (_Float16)((val[5] - mu) * rs * gb.y + eb.y);
                xv[6] = (_Float16)((val[6] - mu) * rs * gb.z + eb.z);
                xv[7] = (_Float16)((val[7] - mu) * rs * gb.w + eb.w);
                *(h8*)&xs[nl * HS_STRIDE + c * 8] = xv;
            }
        } else if (grp == 0) {
            h8 z = {};
            *(h8*)&xs[nl * HS_STRIDE + c * 8] = z;
        }
    }
    __syncthreads();
    // ---- phase 2: gemm1 (MFMA). wave = (rg, t). ----
    int rg = w16 & 3, t = w16 >> 2;
    int m = lane & 15, q = lane >> 4;
    h8 aF[4];
#pragma unroll
    for (int kk = 0; kk < 4; ++kk)
        aF[kk] = *(const h8*)&xs[(rg * 16 + m) * HS_STRIDE + kk * 32 + q * 8];
    __syncthreads();                                // xs dead; reuse as ds2
    f32x4 acc1 = {0.f, 0.f, 0.f, 0.f};
#pragma unroll
    for (int kk = 0; kk < 4; ++kk) {
        h8 bF = Wp1[(t * 4 + kk) * 64 + lane];
        acc1 = __builtin_amdgcn_mfma_f32_16x16x32_f16(aF[kk], bF, acc1, 0, 0, 0);
    }
#pragma unroll
    for (int r = 0; r < 4; ++r)
        ds2[(rg * 16 + q * 4 + r) * D1_STRIDE + t * 16 + m] = acc1[r];
    __syncthreads();
    if (tid < 512) {
        int node = tid >> 3, c8 = tid & 7;
        int n = n0 + node;
        if (n < NN) {
            float4 a = *(const float4*)&ds2[node * D1_STRIDE + c8 * 8];
            float4 b = *(const float4*)&ds2[node * D1_STRIDE + c8 * 8 + 4];
            h8 v;
            v[0] = (_Float16)a.x; v[1] = (_Float16)a.y; v[2] = (_Float16)a.z; v[3] = (_Float16)a.w;
            v[4] = (_Float16)b.x; v[5] = (_Float16)b.y; v[6] = (_Float16)b.z; v[7] = (_Float16)b.w;
            ((h8*)feat1)[(size_t)n * 8 + c8] = v;
        }
    } else if (tid < 768) {
        int t2 = tid - 512;
        int node = t2 >> 2, qq = t2 & 3;
        int n = n0 + node;
        float pl = 0.f, pr = 0.f;
#pragma unroll
        for (int i = 0; i < 4; ++i) {
            float4 v = *(const float4*)&ds2[node * D1_STRIDE + qq * 16 + i * 4];
            float4 a = ((const float4*)al1)[qq * 4 + i];
            float4 r = ((const float4*)ar1)[qq * 4 + i];
            pl += v.x * a.x + v.y * a.y + v.z * a.z + v.w * a.w;
            pr += v.x * r.x + v.y * r.y + v.z * r.z + v.w * r.w;
        }
        pl += __shfl_xor(pl, 1, 4); pr += __shfl_xor(pr, 1, 4);
        pl += __shfl_xor(pl, 2, 4); pr += __shfl_xor(pr, 2, 4);
        if (qq == 0 && n < NN) { el1[n] = pl; er1[n] = pr; }
    }
}

// ------- layer-1 agg + bias + LN -> out (f32). 1 node per wave. ------------
__global__ __launch_bounds__(256) void k_agg1(
    const int* __restrict__ off, const unsigned short* __restrict__ ssort,
    const float* __restrict__ el1, const float* __restrict__ er1,
    const _Float16* __restrict__ feat1, const float* __restrict__ b1,
    const float* __restrict__ g1, const float* __restrict__ be1,
    float* __restrict__ out)
{
    int w = threadIdx.x >> 6, lane = threadIdx.x & 63;
    int grp = lane >> 3, c = lane & 7;
    int n = blockIdx.x * 4 + w;
    int beg = off[n], end = off[n + 1];
    float ern = er1[n];
    const h8* fb = (const h8*)feat1;         // row = 8 h8
    float acc[8] = {};
    float den = 0.f;
    for (int cb = beg; cb < end; cb += 64) {
        int m = end - cb; if (m > 64) m = 64;
        int s_reg = 0; float p_reg = 0.f;
        if (lane < m) {
            s_reg = ssort[cb + lane];
            float v = el1[s_reg] + ern;
            v = v > 0.f ? v : 0.2f * v;
            p_reg = __expf(v);
        }
        den += p_reg;
        for (int i = 0; i < m; i += 8) {
            int j = i + grp;
            int   sj = __shfl(s_reg, j);
            float qj = __shfl(p_reg, j);
            if (j >= m) qj = 0.f;
            h8 f8 = fb[(size_t)sj * 8 + c];
#pragma unroll
            for (int k = 0; k < 8; ++k) acc[k] = fmaf(qj, (float)f8[k], acc[k]);
        }
    }
#pragma unroll
    for (int k = 0; k < 8; ++k) {
        acc[k] += __shfl_down(acc[k], 32);
        acc[k] += __shfl_down(acc[k], 16);
        acc[k] += __shfl_down(acc[k], 8);
    }
#pragma unroll
    for (int o = 32; o > 0; o >>= 1) den += __shfl_down(den, o);
    den = __shfl(den, 0);
    float inv = (end > beg) ? 1.f / den : 0.f;
    float4 ba = ((const float4*)b1)[c * 2];
    float4 bb = ((const float4*)b1)[c * 2 + 1];
    float val[8];
    val[0] = acc[0] * inv + ba.x; val[1] = acc[1] * inv + ba.y;
    val[2] = acc[2] * inv + ba.z; val[3] = acc[3] * inv + ba.w;
    val[4] = acc[4] * inv + bb.x; val[5] = acc[5] * inv + bb.y;
    val[6] = acc[6] * inv + bb.z; val[7] = acc[7] * inv + bb.w;
    float s1 = 0.f, s2 = 0.f;
#pragma unroll
    for (int k = 0; k < 8; ++k) { s1 += val[k]; s2 += val[k] * val[k]; }
#pragma unroll
    for (int o = 1; o < 8; o <<= 1) { s1 += __shfl_xor(s1, o, 8); s2 += __shfl_xor(s2, o, 8); }
    float mu = s1 * (1.f / 64.f);
    float var = s2 * (1.f / 64.f) - mu * mu;
    float rs = rsqrtf(var + 1e-5f);
    if (lane < 8) {
        float4 ga = ((const float4*)g1)[c * 2];
        float4 gb = ((const float4*)g1)[c * 2 + 1];
        float4 ea = ((const float4*)be1)[c * 2];
        float4 eb = ((const float4*)be1)[c * 2 + 1];
        float4 oa, ob;
        oa.x = (val[0] - mu) * rs * ga.x + ea.x;
        oa.y = (val[1] - mu) * rs * ga.y + ea.y;
        oa.z = (val[2] - mu) * rs * ga.z + ea.z;
        oa.w = (val[3] - mu) * rs * ga.w + ea.w;
        ob.x = (val[4] - mu) * rs * gb.x + eb.x;
        ob.y = (val[5] - mu) * rs * gb.y + eb.y;
        ob.z = (val[6] - mu) * rs * gb.z + eb.z;
        ob.w = (val[7] - mu) * rs * gb.w + eb.w;
        float4* orow = (float4*)(out + (size_t)n * 64);
        orow[c * 2] = oa;
        orow[c * 2 + 1] = ob;
    }
}

extern "C" void kernel_launch(void* const* d_in, const int* in_sizes, int n_in,
                              void* d_out, int out_size, void* d_ws, size_t ws_size,
                              hipStream_t stream)
{
    const float* h   = (const float*)d_in[0];
    const float* W0  = (const float*)d_in[1];
    const float* al0 = (const float*)d_in[2];
    const float* ar0 = (const float*)d_in[3];
    const float* b0  = (const float*)d_in[4];
    const float* W1  = (const float*)d_in[5];
    const float* al1 = (const float*)d_in[6];
    const float* ar1 = (const float*)d_in[7];
    const float* b1  = (const float*)d_in[8];
    const float* g0  = (const float*)d_in[9];
    const float* be0 = (const float*)d_in[10];
    const float* g1  = (const float*)d_in[11];
    const float* be1 = (const float*)d_in[12];
    const int*   src = (const int*)d_in[13];
    const int*   dst = (const int*)d_in[14];
    float* out = (float*)d_out;

    char* p = (char*)d_ws;
    auto alloc = [&](size_t bytes) -> char* {
        char* r = p;
        p += (bytes + 255) & ~(size_t)255;
        return r;
    };
    _Float16* feat0 = (_Float16*)alloc((size_t)NN * 128 * sizeof(_Float16));
    float* el0   = (float*)alloc((size_t)NN * 2 * sizeof(float));
    float* er0   = (float*)alloc((size_t)NN * 2 * sizeof(float));
    _Float16* feat1 = (_Float16*)alloc((size_t)NN * 64 * sizeof(_Float16));
    float* el1   = (float*)alloc((size_t)NN * sizeof(float));
    float* er1   = (float*)alloc((size_t)NN * sizeof(float));
    int*   bcntp = (int*)alloc((size_t)NBUCK * 16 * sizeof(int));   // padded: 1/line
    int*   bexc  = (int*)alloc((size_t)NBUCK * sizeof(int));
    int*   off   = (int*)alloc((size_t)(NN + 1) * sizeof(int));
    unsigned int*   staging = (unsigned int*)alloc((size_t)NBUCK * CAP * sizeof(unsigned int));
    unsigned short* ssort   = (unsigned short*)alloc((size_t)EE * sizeof(unsigned short));
    h8*    Wp0   = (h8*)alloc(2048 * sizeof(h8));
    h8*    Wp1   = (h8*)alloc(1024 * sizeof(h8));

    hipMemsetAsync(bcntp, 0, (size_t)NBUCK * 16 * sizeof(int), stream);

    const int NBBIN = (EE + CHUNK - 1) / CHUNK;    // 196
    k_bin<<<NBBIN + 3, 1024, 0, stream>>>(src, dst, bcntp, staging, W0, W1, Wp0, Wp1);
    k_gemm0<<<GB0 + 1, 256, 0, stream>>>(h, Wp0, al0, ar0, feat0, el0, er0,
                                         bcntp, bexc, off);
    k_final<<<NBUCK, 256, 0, stream>>>(staging, bcntp, bexc, off, ssort);
    k_aggemm<<<(NN + 63) / 64, 1024, 0, stream>>>(off, ssort, el0, er0, feat0,
                                                  b0, g0, be0, Wp1, al1, ar1,
                                                  feat1, el1, er1);
    k_agg1<<<NN / 4, 256, 0, stream>>>(off, ssort, el1, er1, feat1, b1, g1, be1, out);
}

// Round 12
// 214.087 us; speedup vs baseline: 2.4967x; 1.0118x over previous
//
#include <hip/hip_runtime.h>
#include <hip/hip_bf16.h>

// GAT 2-layer: N=50000, E=800000, DN=128, D=64, H=2 (layer0). All f32 I/O.
// R12: agg inner loops rebuilt around LDS record broadcast. R11's loop did
// 3 dynamic __shfl (= ds_bpermute) + compare/select per 4-edge iteration;
// now each lane writes its (s,p0,p1) record once to a per-wave LDS array
// (no barrier: wave-coherent) and the loop does ONE ds_read_b128 broadcast.
// Inactive lanes write zero records -> padding edges add 0, so the j>=m
// select is gone. Same for agg1 (int2 records, ds_read_b64).
// Rest as R11: fused agg0+gemm1 (x lives in LDS), W-pack/bucket-scan ride
// on k_bin/gemm0, LDS counting-sort k_final, MFMA f16 GEMMs, u16 ssort.

#define NN 50000
#define EE 800000
#define NBUCK 196            // ceil(NN/256)
#define CHUNK 4096           // edges per k_bin block
#define CAP 8192             // staging slots per bucket (mean 4096, std ~64)
#define GB0 ((NN + 63) / 64) // 782 gemm0 blocks; block GB0 = bucket scan

typedef _Float16 h4 __attribute__((ext_vector_type(4)));
typedef _Float16 h8 __attribute__((ext_vector_type(8)));
typedef float f32x4 __attribute__((ext_vector_type(4)));

// ---- pass 1: bin edges into fixed-base bucket staging (+ W pack blocks) ---
__global__ __launch_bounds__(1024) void k_bin(
    const int* __restrict__ src, const int* __restrict__ dst,
    int* __restrict__ bcntp, unsigned int* __restrict__ staging,
    const float* __restrict__ W0, const float* __restrict__ W1,
    h8* __restrict__ Wp0, h8* __restrict__ Wp1)
{
    int tid = threadIdx.x;
    if (blockIdx.x >= (EE + CHUNK - 1) / CHUNK) {
        int idx = (blockIdx.x - (EE + CHUNK - 1) / CHUNK) * 1024 + tid;
        if (idx < 2048) {
            int lane = idx & 63, kk = (idx >> 6) & 3, tt = idx >> 8;
            int q = lane >> 4, c = lane & 15;
            h8 v;
#pragma unroll
            for (int j = 0; j < 8; ++j)
                v[j] = (_Float16)W0[(kk * 32 + q * 8 + j) * 128 + tt * 16 + c];
            Wp0[idx] = v;
        } else if (idx < 3072) {
            int i2 = idx - 2048;
            int lane = i2 & 63, kk = (i2 >> 6) & 3, tt = i2 >> 8;
            int q = lane >> 4, c = lane & 15;
            h8 v;
#pragma unroll
            for (int j = 0; j < 8; ++j)
                v[j] = (_Float16)W1[(kk * 32 + q * 8 + j) * 64 + tt * 16 + c];
            Wp1[i2] = v;
        }
        return;
    }
    __shared__ int hist[NBUCK];
    __shared__ int rnk[NBUCK];
    __shared__ int gbase[NBUCK];
    int base = blockIdx.x * CHUNK;
    int m = EE - base; if (m > CHUNK) m = CHUNK;   // multiple of 4
    if (tid < NBUCK) { hist[tid] = 0; rnk[tid] = 0; }
    __syncthreads();
    int e0 = tid * 4;
    bool act = e0 < m;
    int4 d4 = {0, 0, 0, 0}, s4 = {0, 0, 0, 0};
    if (act) {
        d4 = ((const int4*)(dst + base))[tid];
        s4 = ((const int4*)(src + base))[tid];
        atomicAdd(&hist[d4.x >> 8], 1);
        atomicAdd(&hist[d4.y >> 8], 1);
        atomicAdd(&hist[d4.z >> 8], 1);
        atomicAdd(&hist[d4.w >> 8], 1);
    }
    __syncthreads();
    if (tid < NBUCK && hist[tid])
        gbase[tid] = atomicAdd(&bcntp[tid * 16], hist[tid]);
    __syncthreads();
    if (act) {
        int d[4] = {d4.x, d4.y, d4.z, d4.w};
        int s[4] = {s4.x, s4.y, s4.z, s4.w};
#pragma unroll
        for (int k = 0; k < 4; ++k) {
            int b = d[k] >> 8;
            int r = atomicAdd(&rnk[b], 1);
            int slot = gbase[b] + r;
            if (slot < CAP)    // statistically never; memory-safety clamp
                staging[(size_t)b * CAP + slot] =
                    ((unsigned)(d[k] & 255) << 16) | (unsigned)s[k];
        }
    }
}

// ---- layer-0 GEMM (MFMA) + bucket-scan block. 64 nodes/block. -------------
#define HS_STRIDE 136   // 128 + 8 f16 pad
#define D0_STRIDE 132   // 128 + 4 f32 pad
__global__ __launch_bounds__(256) void k_gemm0(
    const float* __restrict__ h, const h8* __restrict__ Wp0,
    const float* __restrict__ al0, const float* __restrict__ ar0,
    _Float16* __restrict__ feat0, float* __restrict__ el0, float* __restrict__ er0,
    const int* __restrict__ bcntp, int* __restrict__ bexc, int* __restrict__ off)
{
    int tid = threadIdx.x;
    __shared__ char smem[64 * D0_STRIDE * 4];      // union: hs / ds2 / scan
    if (blockIdx.x == GB0) {
        int* s = (int*)smem;
        int v = (tid < NBUCK) ? bcntp[tid * 16] : 0;
        s[tid] = v;
        __syncthreads();
        for (int o = 1; o < 256; o <<= 1) {
            int u = (tid >= o) ? s[tid - o] : 0;
            __syncthreads();
            s[tid] += u;
            __syncthreads();
        }
        if (tid < NBUCK) bexc[tid] = s[tid] - v;
        if (tid == 0) off[0] = 0;
        return;
    }
    _Float16* hs = (_Float16*)smem;
    float* ds2 = (float*)smem;
    int n0 = blockIdx.x * 64;
#pragma unroll
    for (int r = 0; r < 8; ++r) {
        int f = tid + 256 * r;
        int node = f >> 5, kc = f & 31;
        int n = n0 + node;
        float4 v = {0.f, 0.f, 0.f, 0.f};
        if (n < NN) v = ((const float4*)h)[(size_t)n * 32 + kc];
        h4 hv; hv[0] = (_Float16)v.x; hv[1] = (_Float16)v.y;
        hv[2] = (_Float16)v.z; hv[3] = (_Float16)v.w;
        *(h4*)&hs[node * HS_STRIDE + kc * 4] = hv;
    }
    __syncthreads();
    int w = tid >> 6, lane = tid & 63;
    int m = lane & 15, q = lane >> 4;
    h8 aF[4];
#pragma unroll
    for (int kk = 0; kk < 4; ++kk)
        aF[kk] = *(const h8*)&hs[(w * 16 + m) * HS_STRIDE + kk * 32 + q * 8];
    __syncthreads();                                // hs dead; reuse as ds2
#pragma unroll
    for (int t = 0; t < 8; ++t) {
        f32x4 acc = {0.f, 0.f, 0.f, 0.f};
#pragma unroll
        for (int kk = 0; kk < 4; ++kk) {
            h8 bF = Wp0[(t * 4 + kk) * 64 + lane];
            acc = __builtin_amdgcn_mfma_f32_16x16x32_f16(aF[kk], bF, acc, 0, 0, 0);
        }
#pragma unroll
        for (int r = 0; r < 4; ++r)
            ds2[(w * 16 + q * 4 + r) * D0_STRIDE + t * 16 + m] = acc[r];
    }
    __syncthreads();
#pragma unroll
    for (int r = 0; r < 4; ++r) {
        int f = tid + 256 * r;
        int node = f >> 4, c8 = f & 15;
        int n = n0 + node;
        if (n < NN) {
            float4 a = *(const float4*)&ds2[node * D0_STRIDE + c8 * 8];
            float4 b = *(const float4*)&ds2[node * D0_STRIDE + c8 * 8 + 4];
            h8 v;
            v[0] = (_Float16)a.x; v[1] = (_Float16)a.y; v[2] = (_Float16)a.z; v[3] = (_Float16)a.w;
            v[4] = (_Float16)b.x; v[5] = (_Float16)b.y; v[6] = (_Float16)b.z; v[7] = (_Float16)b.w;
            ((h8*)feat0)[(size_t)n * 16 + c8] = v;
        }
    }
    {
        int node = tid >> 2, qq = tid & 3;
        int n = n0 + node;
        float pl = 0.f, pr = 0.f;
#pragma unroll
        for (int i = 0; i < 8; ++i) {
            float4 v = *(const float4*)&ds2[node * D0_STRIDE + qq * 32 + i * 4];
            float4 a = ((const float4*)al0)[qq * 8 + i];
            float4 r = ((const float4*)ar0)[qq * 8 + i];
            pl += v.x * a.x + v.y * a.y + v.z * a.z + v.w * a.w;
            pr += v.x * r.x + v.y * r.y + v.z * r.z + v.w * r.w;
        }
        pl += __shfl_xor(pl, 1, 4); pr += __shfl_xor(pr, 1, 4);
        if (n < NN) {
            if (qq == 0) { el0[n * 2] = pl;     er0[n * 2] = pr; }
            if (qq == 2) { el0[n * 2 + 1] = pl; er0[n * 2 + 1] = pr; }
        }
    }
}

// ---- pass 2: LDS counting sort per bucket; writes off[n+1] + u16 ssort ----
__global__ __launch_bounds__(256) void k_final(
    const unsigned int* __restrict__ staging, const int* __restrict__ bcntp,
    const int* __restrict__ bexc, int* __restrict__ off,
    unsigned short* __restrict__ ssort)
{
    int b = blockIdx.x;
    int tid = threadIdx.x;
    int cnt = bcntp[b * 16]; if (cnt > CAP) cnt = CAP;
    size_t base = (size_t)b * CAP;
    int lo = bexc[b];
    __shared__ unsigned short buf[CAP];
    __shared__ int hist[256];
    __shared__ int sc[256];
    hist[tid] = 0;
    __syncthreads();
    for (int i = tid; i < cnt; i += 256)
        atomicAdd(&hist[staging[base + i] >> 16], 1);
    __syncthreads();
    int hv = hist[tid];
    sc[tid] = hv;
    __syncthreads();
    for (int o = 1; o < 256; o <<= 1) {
        int u = (tid >= o) ? sc[tid - o] : 0;
        __syncthreads();
        sc[tid] += u;
        __syncthreads();
    }
    int nlo = b << 8;
    int nrem = NN - nlo; if (nrem > 256) nrem = 256;
    if (tid < nrem) off[nlo + tid + 1] = lo + sc[tid];
    hist[tid] = sc[tid] - hv;          // exclusive offset -> LDS cursor
    __syncthreads();
    for (int i = tid; i < cnt; i += 256) {
        unsigned rec = staging[base + i];
        int r = atomicAdd(&hist[rec >> 16], 1);
        buf[r] = (unsigned short)(rec & 0xFFFFu);
    }
    __syncthreads();
    for (int i = tid; i < cnt; i += 256)
        ssort[lo + i] = buf[i];
}

// ---- FUSED layer-0 agg (+bias+relu+LN) -> LDS x -> layer-1 GEMM (MFMA) ----
// 1024 thr, 64 nodes/block. Agg: wave w16 handles 4 nodes (one at a time);
// per-chunk edge records (s,p0,p1) broadcast via per-wave LDS (esc).
#define D1_STRIDE 68    // 64 + 4 f32 pad
__global__ __launch_bounds__(1024) void k_aggemm(
    const int* __restrict__ off, const unsigned short* __restrict__ ssort,
    const float* __restrict__ el0, const float* __restrict__ er0,
    const _Float16* __restrict__ feat0, const float* __restrict__ b0,
    const float* __restrict__ g0, const float* __restrict__ be0,
    const h8* __restrict__ Wp1, const float* __restrict__ al1,
    const float* __restrict__ ar1,
    _Float16* __restrict__ feat1, float* __restrict__ el1, float* __restrict__ er1)
{
    int tid = threadIdx.x;
    int w16 = tid >> 6, lane = tid & 63;
    int grp = lane >> 4, c = lane & 15;
    int n0 = blockIdx.x * 64;
    __shared__ char smem[64 * HS_STRIDE * 2 > 64 * D1_STRIDE * 4
                         ? 64 * HS_STRIDE * 2 : 64 * D1_STRIDE * 4];
    __shared__ int4 esc[16][64];                // per-wave edge records
    _Float16* xs = (_Float16*)smem;
    float* ds2 = (float*)smem;
    const h8* fb = (const h8*)feat0;            // row = 16 h8 chunks
    // ---- phase 1: aggregate 4 nodes per wave into xs (f16) ----
    for (int i = 0; i < 4; ++i) {
        int nl = w16 * 4 + i;
        int n = n0 + nl;
        if (n < NN) {
            int beg = off[n], end = off[n + 1];
            float2 ern2 = ((const float2*)er0)[n];
            float acc[8] = {};
            float den0 = 0.f, den1 = 0.f;
            for (int cb = beg; cb < end; cb += 64) {
                int m = end - cb; if (m > 64) m = 64;
                int s_reg = 0; float p0 = 0.f, p1 = 0.f;
                if (lane < m) {
                    s_reg = ssort[cb + lane];
                    float2 el2 = ((const float2*)el0)[s_reg];
                    float v0 = el2.x + ern2.x; v0 = v0 > 0.f ? v0 : 0.2f * v0;
                    float v1 = el2.y + ern2.y; v1 = v1 > 0.f ? v1 : 0.2f * v1;
                    p0 = __expf(v0); p1 = __expf(v1);
                }
                den0 += p0; den1 += p1;
                // publish records (wave-coherent LDS; zero for inactive lanes)
                esc[w16][lane] = make_int4(s_reg, __float_as_int(p0),
                                           __float_as_int(p1), 0);
                for (int ii = 0; ii < m; ii += 4) {
                    int4 rec = esc[w16][ii + grp];    // 16-lane broadcast
                    float qj = (c < 8) ? __int_as_float(rec.y)
                                       : __int_as_float(rec.z);
                    h8 f8 = fb[(size_t)rec.x * 16 + c];
#pragma unroll
                    for (int k = 0; k < 8; ++k) acc[k] = fmaf(qj, (float)f8[k], acc[k]);
                }
            }
#pragma unroll
            for (int k = 0; k < 8; ++k) {
                acc[k] += __shfl_down(acc[k], 32);
                acc[k] += __shfl_down(acc[k], 16);
            }
#pragma unroll
            for (int o = 32; o > 0; o >>= 1) { den0 += __shfl_down(den0, o); den1 += __shfl_down(den1, o); }
            den0 = __shfl(den0, 0); den1 = __shfl(den1, 0);
            float den = (c < 8) ? den0 : den1;
            float inv = (end > beg) ? 1.f / den : 0.f;
            float4 ba = ((const float4*)b0)[c * 2];
            float4 bb = ((const float4*)b0)[c * 2 + 1];
            float val[8];
            val[0] = fmaxf(acc[0] * inv + ba.x, 0.f);
            val[1] = fmaxf(acc[1] * inv + ba.y, 0.f);
            val[2] = fmaxf(acc[2] * inv + ba.z, 0.f);
            val[3] = fmaxf(acc[3] * inv + ba.w, 0.f);
            val[4] = fmaxf(acc[4] * inv + bb.x, 0.f);
            val[5] = fmaxf(acc[5] * inv + bb.y, 0.f);
            val[6] = fmaxf(acc[6] * inv + bb.z, 0.f);
            val[7] = fmaxf(acc[7] * inv + bb.w, 0.f);
            float s1 = 0.f, s2 = 0.f;
#pragma unroll
            for (int k = 0; k < 8; ++k) { s1 += val[k]; s2 += val[k] * val[k]; }
#pragma unroll
            for (int o = 1; o < 16; o <<= 1) { s1 += __shfl_xor(s1, o, 16); s2 += __shfl_xor(s2, o, 16); }
            float mu = s1 * (1.f / 128.f);
            float var = s2 * (1.f / 128.f) - mu * mu;
            float rs = rsqrtf(var + 1e-5f);
            if (grp == 0) {
                float4 ga = ((const float4*)g0)[c * 2];
                float4 gb = ((const float4*)g0)[c * 2 + 1];
                float4 ea = ((const float4*)be0)[c * 2];
                float4 eb = ((const float4*)be0)[c * 2 + 1];
                h8 xv;
                xv[0] = (_Float16)((val[0] - mu) * rs * ga.x + ea.x);
                xv[1] = (_Float16)((val[1] - mu) * rs * ga.y + ea.y);
                xv[2] = (_Float16)((val[2] - mu) * rs * ga.z + ea.z);
                xv[3] = (_Float16)((val[3] - mu) * rs * ga.w + ea.w);
                xv[4] = (_Float16)((val[4] - mu) * rs * gb.x + eb.x);
                xv[5] = (_Float16)((val[5] - mu) * rs * gb.y + eb.y);
                xv[6] = (_Float16)((val[6] - mu) * rs * gb.z + eb.z);
                xv[7] = (_Float16)((val[7] - mu) * rs * gb.w + eb.w);
                *(h8*)&xs[nl * HS_STRIDE + c * 8] = xv;
            }
        } else if (grp == 0) {
            h8 z = {};
            *(h8*)&xs[nl * HS_STRIDE + c * 8] = z;
        }
    }
    __syncthreads();
    // ---- phase 2: gemm1 (MFMA). wave = (rg, t). ----
    int rg = w16 & 3, t = w16 >> 2;
    int m = lane & 15, q = lane >> 4;
    h8 aF[4];
#pragma unroll
    for (int kk = 0; kk < 4; ++kk)
        aF[kk] = *(const h8*)&xs[(rg * 16 + m) * HS_STRIDE + kk * 32 + q * 8];
    __syncthreads();                                // xs dead; reuse as ds2
    f32x4 acc1 = {0.f, 0.f, 0.f, 0.f};
#pragma unroll
    for (int kk = 0; kk < 4; ++kk) {
        h8 bF = Wp1[(t * 4 + kk) * 64 + lane];
        acc1 = __builtin_amdgcn_mfma_f32_16x16x32_f16(aF[kk], bF, acc1, 0, 0, 0);
    }
#pragma unroll
    for (int r = 0; r < 4; ++r)
        ds2[(rg * 16 + q * 4 + r) * D1_STRIDE + t * 16 + m] = acc1[r];
    __syncthreads();
    if (tid < 512) {
        int node = tid >> 3, c8 = tid & 7;
        int n = n0 + node;
        if (n < NN) {
            float4 a = *(const float4*)&ds2[node * D1_STRIDE + c8 * 8];
            float4 b = *(const float4*)&ds2[node * D1_STRIDE + c8 * 8 + 4];
            h8 v;
            v[0] = (_Float16)a.x; v[1] = (_Float16)a.y; v[2] = (_Float16)a.z; v[3] = (_Float16)a.w;
            v[4] = (_Float16)b.x; v[5] = (_Float16)b.y; v[6] = (_Float16)b.z; v[7] = (_Float16)b.w;
            ((h8*)feat1)[(size_t)n * 8 + c8] = v;
        }
    } else if (tid < 768) {
        int t2 = tid - 512;
        int node = t2 >> 2, qq = t2 & 3;
        int n = n0 + node;
        float pl = 0.f, pr = 0.f;
#pragma unroll
        for (int i = 0; i < 4; ++i) {
            float4 v = *(const float4*)&ds2[node * D1_STRIDE + qq * 16 + i * 4];
            float4 a = ((const float4*)al1)[qq * 4 + i];
            float4 r = ((const float4*)ar1)[qq * 4 + i];
            pl += v.x * a.x + v.y * a.y + v.z * a.z + v.w * a.w;
            pr += v.x * r.x + v.y * r.y + v.z * r.z + v.w * r.w;
        }
        pl += __shfl_xor(pl, 1, 4); pr += __shfl_xor(pr, 1, 4);
        pl += __shfl_xor(pl, 2, 4); pr += __shfl_xor(pr, 2, 4);
        if (qq == 0 && n < NN) { el1[n] = pl; er1[n] = pr; }
    }
}

// ------- layer-1 agg + bias + LN -> out (f32). 1 node per wave. ------------
__global__ __launch_bounds__(256) void k_agg1(
    const int* __restrict__ off, const unsigned short* __restrict__ ssort,
    const float* __restrict__ el1, const float* __restrict__ er1,
    const _Float16* __restrict__ feat1, const float* __restrict__ b1,
    const float* __restrict__ g1, const float* __restrict__ be1,
    float* __restrict__ out)
{
    int w = threadIdx.x >> 6, lane = threadIdx.x & 63;
    int grp = lane >> 3, c = lane & 7;
    int n = blockIdx.x * 4 + w;
    int beg = off[n], end = off[n + 1];
    float ern = er1[n];
    const h8* fb = (const h8*)feat1;         // row = 8 h8
    __shared__ int2 esc[4][64];
    float acc[8] = {};
    float den = 0.f;
    for (int cb = beg; cb < end; cb += 64) {
        int m = end - cb; if (m > 64) m = 64;
        int s_reg = 0; float p_reg = 0.f;
        if (lane < m) {
            s_reg = ssort[cb + lane];
            float v = el1[s_reg] + ern;
            v = v > 0.f ? v : 0.2f * v;
            p_reg = __expf(v);
        }
        den += p_reg;
        esc[w][lane] = make_int2(s_reg, __float_as_int(p_reg));
        for (int i = 0; i < m; i += 8) {
            int2 rec = esc[w][i + grp];        // 8-lane broadcast
            float qj = __int_as_float(rec.y);
            h8 f8 = fb[(size_t)rec.x * 8 + c];
#pragma unroll
            for (int k = 0; k < 8; ++k) acc[k] = fmaf(qj, (float)f8[k], acc[k]);
        }
    }
#pragma unroll
    for (int k = 0; k < 8; ++k) {
        acc[k] += __shfl_down(acc[k], 32);
        acc[k] += __shfl_down(acc[k], 16);
        acc[k] += __shfl_down(acc[k], 8);
    }
#pragma unroll
    for (int o = 32; o > 0; o >>= 1) den += __shfl_down(den, o);
    den = __shfl(den, 0);
    float inv = (end > beg) ? 1.f / den : 0.f;
    float4 ba = ((const float4*)b1)[c * 2];
    float4 bb = ((const float4*)b1)[c * 2 + 1];
    float val[8];
    val[0] = acc[0] * inv + ba.x; val[1] = acc[1] * inv + ba.y;
    val[2] = acc[2] * inv + ba.z; val[3] = acc[3] * inv + ba.w;
    val[4] = acc[4] * inv + bb.x; val[5] = acc[5] * inv + bb.y;
    val[6] = acc[6] * inv + bb.z; val[7] = acc[7] * inv + bb.w;
    float s1 = 0.f, s2 = 0.f;
#pragma unroll
    for (int k = 0; k < 8; ++k) { s1 += val[k]; s2 += val[k] * val[k]; }
#pragma unroll
    for (int o = 1; o < 8; o <<= 1) { s1 += __shfl_xor(s1, o, 8); s2 += __shfl_xor(s2, o, 8); }
    float mu = s1 * (1.f / 64.f);
    float var = s2 * (1.f / 64.f) - mu * mu;
    float rs = rsqrtf(var + 1e-5f);
    if (lane < 8) {
        float4 ga = ((const float4*)g1)[c * 2];
        float4 gb = ((const float4*)g1)[c * 2 + 1];
        float4 ea = ((const float4*)be1)[c * 2];
        float4 eb = ((const float4*)be1)[c * 2 + 1];
        float4 oa, ob;
        oa.x = (val[0] - mu) * rs * ga.x + ea.x;
        oa.y = (val[1] - mu) * rs * ga.y + ea.y;
        oa.z = (val[2] - mu) * rs * ga.z + ea.z;
        oa.w = (val[3] - mu) * rs * ga.w + ea.w;
        ob.x = (val[4] - mu) * rs * gb.x + eb.x;
        ob.y = (val[5] - mu) * rs * gb.y + eb.y;
        ob.z = (val[6] - mu) * rs * gb.z + eb.z;
        ob.w = (val[7] - mu) * rs * gb.w + eb.w;
        float4* orow = (float4*)(out + (size_t)n * 64);
        orow[c * 2] = oa;
        orow[c * 2 + 1] = ob;
    }
}

extern "C" void kernel_launch(void* const* d_in, const int* in_sizes, int n_in,
                              void* d_out, int out_size, void* d_ws, size_t ws_size,
                              hipStream_t stream)
{
    const float* h   = (const float*)d_in[0];
    const float* W0  = (const float*)d_in[1];
    const float* al0 = (const float*)d_in[2];
    const float* ar0 = (const float*)d_in[3];
    const float* b0  = (const float*)d_in[4];
    const float* W1  = (const float*)d_in[5];
    const float* al1 = (const float*)d_in[6];
    const float* ar1 = (const float*)d_in[7];
    const float* b1  = (const float*)d_in[8];
    const float* g0  = (const float*)d_in[9];
    const float* be0 = (const float*)d_in[10];
    const float* g1  = (const float*)d_in[11];
    const float* be1 = (const float*)d_in[12];
    const int*   src = (const int*)d_in[13];
    const int*   dst = (const int*)d_in[14];
    float* out = (float*)d_out;

    char* p = (char*)d_ws;
    auto alloc = [&](size_t bytes) -> char* {
        char* r = p;
        p += (bytes + 255) & ~(size_t)255;
        return r;
    };
    _Float16* feat0 = (_Float16*)alloc((size_t)NN * 128 * sizeof(_Float16));
    float* el0   = (float*)alloc((size_t)NN * 2 * sizeof(float));
    float* er0   = (float*)alloc((size_t)NN * 2 * sizeof(float));
    _Float16* feat1 = (_Float16*)alloc((size_t)NN * 64 * sizeof(_Float16));
    float* el1   = (float*)alloc((size_t)NN * sizeof(float));
    float* er1   = (float*)alloc((size_t)NN * sizeof(float));
    int*   bcntp = (int*)alloc((size_t)NBUCK * 16 * sizeof(int));   // padded: 1/line
    int*   bexc  = (int*)alloc((size_t)NBUCK * sizeof(int));
    int*   off   = (int*)alloc((size_t)(NN + 1) * sizeof(int));
    unsigned int*   staging = (unsigned int*)alloc((size_t)NBUCK * CAP * sizeof(unsigned int));
    unsigned short* ssort   = (unsigned short*)alloc((size_t)EE * sizeof(unsigned short));
    h8*    Wp0   = (h8*)alloc(2048 * sizeof(h8));
    h8*    Wp1   = (h8*)alloc(1024 * sizeof(h8));

    hipMemsetAsync(bcntp, 0, (size_t)NBUCK * 16 * sizeof(int), stream);

    const int NBBIN = (EE + CHUNK - 1) / CHUNK;    // 196
    k_bin<<<NBBIN + 3, 1024, 0, stream>>>(src, dst, bcntp, staging, W0, W1, Wp0, Wp1);
    k_gemm0<<<GB0 + 1, 256, 0, stream>>>(h, Wp0, al0, ar0, feat0, el0, er0,
                                         bcntp, bexc, off);
    k_final<<<NBUCK, 256, 0, stream>>>(staging, bcntp, bexc, off, ssort);
    k_aggemm<<<(NN + 63) / 64, 1024, 0, stream>>>(off, ssort, el0, er0, feat0,
                                                  b0, g0, be0, Wp1, al1, ar1,
                                                  feat1, el1, er1);
    k_agg1<<<NN / 4, 256, 0, stream>>>(off, ssort, el1, er1, feat1, b1, g1, be1, out);
}

// Round 13
// 208.803 us; speedup vs baseline: 2.5599x; 1.0253x over previous
//
#include <hip/hip_runtime.h>
#include <hip/hip_bf16.h>

// GAT 2-layer: N=50000, E=800000, DN=128, D=64, H=2 (layer0). All f32 I/O.
// R13: agg inner loops use v_dot2_f32_f16 2-edge pairing. Edge records in
// LDS carry (s, p0p1 packed f16x2); per edge PAIR: 1 ds_read_b128 (2 recs),
// 1 v_perm builds the (qA,qB) head-selected f16 pair, 2 h8 gathers, 8
// v_perm column-pairs, 8 v_dot2_f32_f16 (16 MACs, f32 acc). Replaces R12's
// 16 cvt + 16 fma per 2 edges -> ~1.7x fewer inner-loop VALU ops.
// Rest as R12: fused agg0+gemm1 (x in LDS), W-pack/bucket-scan ride on
// k_bin/gemm0, LDS counting-sort k_final, MFMA f16 GEMMs, u16 ssort.

#define NN 50000
#define EE 800000
#define NBUCK 196            // ceil(NN/256)
#define CHUNK 4096           // edges per k_bin block
#define CAP 8192             // staging slots per bucket (mean 4096, std ~64)
#define GB0 ((NN + 63) / 64) // 782 gemm0 blocks; block GB0 = bucket scan

typedef _Float16 h2 __attribute__((ext_vector_type(2)));
typedef _Float16 h4 __attribute__((ext_vector_type(4)));
typedef _Float16 h8 __attribute__((ext_vector_type(8)));
typedef float f32x4 __attribute__((ext_vector_type(4)));

__device__ __forceinline__ h2 i2h(int v) { union { int i; h2 h; } u; u.i = v; return u.h; }
__device__ __forceinline__ int h2i(h2 v) { union { h2 h; int i; } u; u.h = v; return u.i; }

// selector constants for v_perm_b32 (pool: bytes0-3 = S1, bytes4-7 = S0)
#define SEL_LO 0x01000504u   // result = (S0.lo16, S1.lo16)
#define SEL_HI 0x03020706u   // result = (S0.hi16, S1.hi16)

// ---- pass 1: bin edges into fixed-base bucket staging (+ W pack blocks) ---
__global__ __launch_bounds__(1024) void k_bin(
    const int* __restrict__ src, const int* __restrict__ dst,
    int* __restrict__ bcntp, unsigned int* __restrict__ staging,
    const float* __restrict__ W0, const float* __restrict__ W1,
    h8* __restrict__ Wp0, h8* __restrict__ Wp1)
{
    int tid = threadIdx.x;
    if (blockIdx.x >= (EE + CHUNK - 1) / CHUNK) {
        int idx = (blockIdx.x - (EE + CHUNK - 1) / CHUNK) * 1024 + tid;
        if (idx < 2048) {
            int lane = idx & 63, kk = (idx >> 6) & 3, tt = idx >> 8;
            int q = lane >> 4, c = lane & 15;
            h8 v;
#pragma unroll
            for (int j = 0; j < 8; ++j)
                v[j] = (_Float16)W0[(kk * 32 + q * 8 + j) * 128 + tt * 16 + c];
            Wp0[idx] = v;
        } else if (idx < 3072) {
            int i2_ = idx - 2048;
            int lane = i2_ & 63, kk = (i2_ >> 6) & 3, tt = i2_ >> 8;
            int q = lane >> 4, c = lane & 15;
            h8 v;
#pragma unroll
            for (int j = 0; j < 8; ++j)
                v[j] = (_Float16)W1[(kk * 32 + q * 8 + j) * 64 + tt * 16 + c];
            Wp1[i2_] = v;
        }
        return;
    }
    __shared__ int hist[NBUCK];
    __shared__ int rnk[NBUCK];
    __shared__ int gbase[NBUCK];
    int base = blockIdx.x * CHUNK;
    int m = EE - base; if (m > CHUNK) m = CHUNK;   // multiple of 4
    if (tid < NBUCK) { hist[tid] = 0; rnk[tid] = 0; }
    __syncthreads();
    int e0 = tid * 4;
    bool act = e0 < m;
    int4 d4 = {0, 0, 0, 0}, s4 = {0, 0, 0, 0};
    if (act) {
        d4 = ((const int4*)(dst + base))[tid];
        s4 = ((const int4*)(src + base))[tid];
        atomicAdd(&hist[d4.x >> 8], 1);
        atomicAdd(&hist[d4.y >> 8], 1);
        atomicAdd(&hist[d4.z >> 8], 1);
        atomicAdd(&hist[d4.w >> 8], 1);
    }
    __syncthreads();
    if (tid < NBUCK && hist[tid])
        gbase[tid] = atomicAdd(&bcntp[tid * 16], hist[tid]);
    __syncthreads();
    if (act) {
        int d[4] = {d4.x, d4.y, d4.z, d4.w};
        int s[4] = {s4.x, s4.y, s4.z, s4.w};
#pragma unroll
        for (int k = 0; k < 4; ++k) {
            int b = d[k] >> 8;
            int r = atomicAdd(&rnk[b], 1);
            int slot = gbase[b] + r;
            if (slot < CAP)    // statistically never; memory-safety clamp
                staging[(size_t)b * CAP + slot] =
                    ((unsigned)(d[k] & 255) << 16) | (unsigned)s[k];
        }
    }
}

// ---- layer-0 GEMM (MFMA) + bucket-scan block. 64 nodes/block. -------------
#define HS_STRIDE 136   // 128 + 8 f16 pad
#define D0_STRIDE 132   // 128 + 4 f32 pad
__global__ __launch_bounds__(256) void k_gemm0(
    const float* __restrict__ h, const h8* __restrict__ Wp0,
    const float* __restrict__ al0, const float* __restrict__ ar0,
    _Float16* __restrict__ feat0, float* __restrict__ el0, float* __restrict__ er0,
    const int* __restrict__ bcntp, int* __restrict__ bexc, int* __restrict__ off)
{
    int tid = threadIdx.x;
    __shared__ char smem[64 * D0_STRIDE * 4];      // union: hs / ds2 / scan
    if (blockIdx.x == GB0) {
        int* s = (int*)smem;
        int v = (tid < NBUCK) ? bcntp[tid * 16] : 0;
        s[tid] = v;
        __syncthreads();
        for (int o = 1; o < 256; o <<= 1) {
            int u = (tid >= o) ? s[tid - o] : 0;
            __syncthreads();
            s[tid] += u;
            __syncthreads();
        }
        if (tid < NBUCK) bexc[tid] = s[tid] - v;
        if (tid == 0) off[0] = 0;
        return;
    }
    _Float16* hs = (_Float16*)smem;
    float* ds2 = (float*)smem;
    int n0 = blockIdx.x * 64;
#pragma unroll
    for (int r = 0; r < 8; ++r) {
        int f = tid + 256 * r;
        int node = f >> 5, kc = f & 31;
        int n = n0 + node;
        float4 v = {0.f, 0.f, 0.f, 0.f};
        if (n < NN) v = ((const float4*)h)[(size_t)n * 32 + kc];
        h4 hv; hv[0] = (_Float16)v.x; hv[1] = (_Float16)v.y;
        hv[2] = (_Float16)v.z; hv[3] = (_Float16)v.w;
        *(h4*)&hs[node * HS_STRIDE + kc * 4] = hv;
    }
    __syncthreads();
    int w = tid >> 6, lane = tid & 63;
    int m = lane & 15, q = lane >> 4;
    h8 aF[4];
#pragma unroll
    for (int kk = 0; kk < 4; ++kk)
        aF[kk] = *(const h8*)&hs[(w * 16 + m) * HS_STRIDE + kk * 32 + q * 8];
    __syncthreads();                                // hs dead; reuse as ds2
#pragma unroll
    for (int t = 0; t < 8; ++t) {
        f32x4 acc = {0.f, 0.f, 0.f, 0.f};
#pragma unroll
        for (int kk = 0; kk < 4; ++kk) {
            h8 bF = Wp0[(t * 4 + kk) * 64 + lane];
            acc = __builtin_amdgcn_mfma_f32_16x16x32_f16(aF[kk], bF, acc, 0, 0, 0);
        }
#pragma unroll
        for (int r = 0; r < 4; ++r)
            ds2[(w * 16 + q * 4 + r) * D0_STRIDE + t * 16 + m] = acc[r];
    }
    __syncthreads();
#pragma unroll
    for (int r = 0; r < 4; ++r) {
        int f = tid + 256 * r;
        int node = f >> 4, c8 = f & 15;
        int n = n0 + node;
        if (n < NN) {
            float4 a = *(const float4*)&ds2[node * D0_STRIDE + c8 * 8];
            float4 b = *(const float4*)&ds2[node * D0_STRIDE + c8 * 8 + 4];
            h8 v;
            v[0] = (_Float16)a.x; v[1] = (_Float16)a.y; v[2] = (_Float16)a.z; v[3] = (_Float16)a.w;
            v[4] = (_Float16)b.x; v[5] = (_Float16)b.y; v[6] = (_Float16)b.z; v[7] = (_Float16)b.w;
            ((h8*)feat0)[(size_t)n * 16 + c8] = v;
        }
    }
    {
        int node = tid >> 2, qq = tid & 3;
        int n = n0 + node;
        float pl = 0.f, pr = 0.f;
#pragma unroll
        for (int i = 0; i < 8; ++i) {
            float4 v = *(const float4*)&ds2[node * D0_STRIDE + qq * 32 + i * 4];
            float4 a = ((const float4*)al0)[qq * 8 + i];
            float4 r = ((const float4*)ar0)[qq * 8 + i];
            pl += v.x * a.x + v.y * a.y + v.z * a.z + v.w * a.w;
            pr += v.x * r.x + v.y * r.y + v.z * r.z + v.w * r.w;
        }
        pl += __shfl_xor(pl, 1, 4); pr += __shfl_xor(pr, 1, 4);
        if (n < NN) {
            if (qq == 0) { el0[n * 2] = pl;     er0[n * 2] = pr; }
            if (qq == 2) { el0[n * 2 + 1] = pl; er0[n * 2 + 1] = pr; }
        }
    }
}

// ---- pass 2: LDS counting sort per bucket; writes off[n+1] + u16 ssort ----
__global__ __launch_bounds__(256) void k_final(
    const unsigned int* __restrict__ staging, const int* __restrict__ bcntp,
    const int* __restrict__ bexc, int* __restrict__ off,
    unsigned short* __restrict__ ssort)
{
    int b = blockIdx.x;
    int tid = threadIdx.x;
    int cnt = bcntp[b * 16]; if (cnt > CAP) cnt = CAP;
    size_t base = (size_t)b * CAP;
    int lo = bexc[b];
    __shared__ unsigned short buf[CAP];
    __shared__ int hist[256];
    __shared__ int sc[256];
    hist[tid] = 0;
    __syncthreads();
    for (int i = tid; i < cnt; i += 256)
        atomicAdd(&hist[staging[base + i] >> 16], 1);
    __syncthreads();
    int hv = hist[tid];
    sc[tid] = hv;
    __syncthreads();
    for (int o = 1; o < 256; o <<= 1) {
        int u = (tid >= o) ? sc[tid - o] : 0;
        __syncthreads();
        sc[tid] += u;
        __syncthreads();
    }
    int nlo = b << 8;
    int nrem = NN - nlo; if (nrem > 256) nrem = 256;
    if (tid < nrem) off[nlo + tid + 1] = lo + sc[tid];
    hist[tid] = sc[tid] - hv;          // exclusive offset -> LDS cursor
    __syncthreads();
    for (int i = tid; i < cnt; i += 256) {
        unsigned rec = staging[base + i];
        int r = atomicAdd(&hist[rec >> 16], 1);
        buf[r] = (unsigned short)(rec & 0xFFFFu);
    }
    __syncthreads();
    for (int i = tid; i < cnt; i += 256)
        ssort[lo + i] = buf[i];
}

// ---- FUSED layer-0 agg (+bias+relu+LN) -> LDS x -> layer-1 GEMM (MFMA) ----
// 1024 thr, 64 nodes/block. Agg: wave w16 = 4 nodes; per-chunk records
// (s, p0p1 f16x2) in per-wave LDS; inner loop = 2-edge dot2 pairing.
#define D1_STRIDE 68    // 64 + 4 f32 pad
__global__ __launch_bounds__(1024) void k_aggemm(
    const int* __restrict__ off, const unsigned short* __restrict__ ssort,
    const float* __restrict__ el0, const float* __restrict__ er0,
    const _Float16* __restrict__ feat0, const float* __restrict__ b0,
    const float* __restrict__ g0, const float* __restrict__ be0,
    const h8* __restrict__ Wp1, const float* __restrict__ al1,
    const float* __restrict__ ar1,
    _Float16* __restrict__ feat1, float* __restrict__ el1, float* __restrict__ er1)
{
    int tid = threadIdx.x;
    int w16 = tid >> 6, lane = tid & 63;
    int grp = lane >> 4, c = lane & 15;
    int n0 = blockIdx.x * 64;
    __shared__ char smem[64 * HS_STRIDE * 2 > 64 * D1_STRIDE * 4
                         ? 64 * HS_STRIDE * 2 : 64 * D1_STRIDE * 4];
    __shared__ int2 esc[16][64];                // per-wave edge records
    _Float16* xs = (_Float16*)smem;
    float* ds2 = (float*)smem;
    const int4* fb = (const int4*)feat0;        // row = 16 int4 chunks
    unsigned qsel = (c < 8) ? SEL_LO : SEL_HI;  // head-select for q pair
    // ---- phase 1: aggregate 4 nodes per wave into xs (f16) ----
    for (int i = 0; i < 4; ++i) {
        int nl = w16 * 4 + i;
        int n = n0 + nl;
        if (n < NN) {
            int beg = off[n], end = off[n + 1];
            float2 ern2 = ((const float2*)er0)[n];
            float acc[8] = {};
            float den0 = 0.f, den1 = 0.f;
            for (int cb = beg; cb < end; cb += 64) {
                int m = end - cb; if (m > 64) m = 64;
                int s_reg = 0; float p0 = 0.f, p1 = 0.f;
                if (lane < m) {
                    s_reg = ssort[cb + lane];
                    float2 el2 = ((const float2*)el0)[s_reg];
                    float v0 = el2.x + ern2.x; v0 = v0 > 0.f ? v0 : 0.2f * v0;
                    float v1 = el2.y + ern2.y; v1 = v1 > 0.f ? v1 : 0.2f * v1;
                    p0 = __expf(v0); p1 = __expf(v1);
                }
                den0 += p0; den1 += p1;
                h2 pp; pp[0] = (_Float16)p0; pp[1] = (_Float16)p1;
                esc[w16][lane] = make_int2(s_reg, h2i(pp));
                for (int ii = 0; ii < m; ii += 8) {
                    int4 rr = *(const int4*)&esc[w16][ii + grp * 2]; // 2 records
                    int qp = __builtin_amdgcn_perm(rr.y, rr.w, qsel); // (qA,qB)
                    int4 iA = fb[(size_t)rr.x * 16 + c];
                    int4 iB = fb[(size_t)rr.z * 16 + c];
                    h2 q2 = i2h(qp);
                    int pe, po;
                    pe = __builtin_amdgcn_perm(iA.x, iB.x, SEL_LO);
                    po = __builtin_amdgcn_perm(iA.x, iB.x, SEL_HI);
                    acc[0] = __builtin_amdgcn_fdot2(i2h(pe), q2, acc[0], false);
                    acc[1] = __builtin_amdgcn_fdot2(i2h(po), q2, acc[1], false);
                    pe = __builtin_amdgcn_perm(iA.y, iB.y, SEL_LO);
                    po = __builtin_amdgcn_perm(iA.y, iB.y, SEL_HI);
                    acc[2] = __builtin_amdgcn_fdot2(i2h(pe), q2, acc[2], false);
                    acc[3] = __builtin_amdgcn_fdot2(i2h(po), q2, acc[3], false);
                    pe = __builtin_amdgcn_perm(iA.z, iB.z, SEL_LO);
                    po = __builtin_amdgcn_perm(iA.z, iB.z, SEL_HI);
                    acc[4] = __builtin_amdgcn_fdot2(i2h(pe), q2, acc[4], false);
                    acc[5] = __builtin_amdgcn_fdot2(i2h(po), q2, acc[5], false);
                    pe = __builtin_amdgcn_perm(iA.w, iB.w, SEL_LO);
                    po = __builtin_amdgcn_perm(iA.w, iB.w, SEL_HI);
                    acc[6] = __builtin_amdgcn_fdot2(i2h(pe), q2, acc[6], false);
                    acc[7] = __builtin_amdgcn_fdot2(i2h(po), q2, acc[7], false);
                }
            }
#pragma unroll
            for (int k = 0; k < 8; ++k) {
                acc[k] += __shfl_down(acc[k], 32);
                acc[k] += __shfl_down(acc[k], 16);
            }
#pragma unroll
            for (int o = 32; o > 0; o >>= 1) { den0 += __shfl_down(den0, o); den1 += __shfl_down(den1, o); }
            den0 = __shfl(den0, 0); den1 = __shfl(den1, 0);
            float den = (c < 8) ? den0 : den1;
            float inv = (end > beg) ? 1.f / den : 0.f;
            float4 ba = ((const float4*)b0)[c * 2];
            float4 bb = ((const float4*)b0)[c * 2 + 1];
            float val[8];
            val[0] = fmaxf(acc[0] * inv + ba.x, 0.f);
            val[1] = fmaxf(acc[1] * inv + ba.y, 0.f);
            val[2] = fmaxf(acc[2] * inv + ba.z, 0.f);
            val[3] = fmaxf(acc[3] * inv + ba.w, 0.f);
            val[4] = fmaxf(acc[4] * inv + bb.x, 0.f);
            val[5] = fmaxf(acc[5] * inv + bb.y, 0.f);
            val[6] = fmaxf(acc[6] * inv + bb.z, 0.f);
            val[7] = fmaxf(acc[7] * inv + bb.w, 0.f);
            float s1 = 0.f, s2 = 0.f;
#pragma unroll
            for (int k = 0; k < 8; ++k) { s1 += val[k]; s2 += val[k] * val[k]; }
#pragma unroll
            for (int o = 1; o < 16; o <<= 1) { s1 += __shfl_xor(s1, o, 16); s2 += __shfl_xor(s2, o, 16); }
            float mu = s1 * (1.f / 128.f);
            float var = s2 * (1.f / 128.f) - mu * mu;
            float rs = rsqrtf(var + 1e-5f);
            if (grp == 0) {
                float4 ga = ((const float4*)g0)[c * 2];
                float4 gb = ((const float4*)g0)[c * 2 + 1];
                float4 ea = ((const float4*)be0)[c * 2];
                float4 eb = ((const float4*)be0)[c * 2 + 1];
                h8 xv;
                xv[0] = (_Float16)((val[0] - mu) * rs * ga.x + ea.x);
                xv[1] = (_Float16)((val[1] - mu) * rs * ga.y + ea.y);
                xv[2] = (_Float16)((val[2] - mu) * rs * ga.z + ea.z);
                xv[3] = (_Float16)((val[3] - mu) * rs * ga.w + ea.w);
                xv[4] = (_Float16)((val[4] - mu) * rs * gb.x + eb.x);
                xv[5] = (_Float16)((val[5] - mu) * rs * gb.y + eb.y);
                xv[6] = (_Float16)((val[6] - mu) * rs * gb.z + eb.z);
                xv[7] = (_Float16)((val[7] - mu) * rs * gb.w + eb.w);
                *(h8*)&xs[nl * HS_STRIDE + c * 8] = xv;
            }
        } else if (grp == 0) {
            h8 z = {};
            *(h8*)&xs[nl * HS_STRIDE + c * 8] = z;
        }
    }
    __syncthreads();
    // ---- phase 2: gemm1 (MFMA). wave = (rg, t). ----
    int rg = w16 & 3, t = w16 >> 2;
    int m = lane & 15, q = lane >> 4;
    h8 aF[4];
#pragma unroll
    for (int kk = 0; kk < 4; ++kk)
        aF[kk] = *(const h8*)&xs[(rg * 16 + m) * HS_STRIDE + kk * 32 + q * 8];
    __syncthreads();                                // xs dead; reuse as ds2
    f32x4 acc1 = {0.f, 0.f, 0.f, 0.f};
#pragma unroll
    for (int kk = 0; kk < 4; ++kk) {
        h8 bF = Wp1[(t * 4 + kk) * 64 + lane];
        acc1 = __builtin_amdgcn_mfma_f32_16x16x32_f16(aF[kk], bF, acc1, 0, 0, 0);
    }
#pragma unroll
    for (int r = 0; r < 4; ++r)
        ds2[(rg * 16 + q * 4 + r) * D1_STRIDE + t * 16 + m] = acc1[r];
    __syncthreads();
    if (tid < 512) {
        int node = tid >> 3, c8 = tid & 7;
        int n = n0 + node;
        if (n < NN) {
            float4 a = *(const float4*)&ds2[node * D1_STRIDE + c8 * 8];
            float4 b = *(const float4*)&ds2[node * D1_STRIDE + c8 * 8 + 4];
            h8 v;
            v[0] = (_Float16)a.x; v[1] = (_Float16)a.y; v[2] = (_Float16)a.z; v[3] = (_Float16)a.w;
            v[4] = (_Float16)b.x; v[5] = (_Float16)b.y; v[6] = (_Float16)b.z; v[7] = (_Float16)b.w;
            ((h8*)feat1)[(size_t)n * 8 + c8] = v;
        }
    } else if (tid < 768) {
        int t2 = tid - 512;
        int node = t2 >> 2, qq = t2 & 3;
        int n = n0 + node;
        float pl = 0.f, pr = 0.f;
#pragma unroll
        for (int i = 0; i < 4; ++i) {
            float4 v = *(const float4*)&ds2[node * D1_STRIDE + qq * 16 + i * 4];
            float4 a = ((const float4*)al1)[qq * 4 + i];
            float4 r = ((const float4*)ar1)[qq * 4 + i];
            pl += v.x * a.x + v.y * a.y + v.z * a.z + v.w * a.w;
            pr += v.x * r.x + v.y * r.y + v.z * r.z + v.w * r.w;
        }
        pl += __shfl_xor(pl, 1, 4); pr += __shfl_xor(pr, 1, 4);
        pl += __shfl_xor(pl, 2, 4); pr += __shfl_xor(pr, 2, 4);
        if (qq == 0 && n < NN) { el1[n] = pl; er1[n] = pr; }
    }
}

// ------- layer-1 agg + bias + LN -> out (f32). 1 node per wave. ------------
__global__ __launch_bounds__(256) void k_agg1(
    const int* __restrict__ off, const unsigned short* __restrict__ ssort,
    const float* __restrict__ el1, const float* __restrict__ er1,
    const _Float16* __restrict__ feat1, const float* __restrict__ b1,
    const float* __restrict__ g1, const float* __restrict__ be1,
    float* __restrict__ out)
{
    int w = threadIdx.x >> 6, lane = threadIdx.x & 63;
    int grp = lane >> 3, c = lane & 7;
    int n = blockIdx.x * 4 + w;
    int beg = off[n], end = off[n + 1];
    float ern = er1[n];
    const int4* fb = (const int4*)feat1;     // row = 8 int4
    __shared__ int2 esc[4][64];
    float acc[8] = {};
    float den = 0.f;
    for (int cb = beg; cb < end; cb += 64) {
        int m = end - cb; if (m > 64) m = 64;
        int s_reg = 0; float p_reg = 0.f;
        if (lane < m) {
            s_reg = ssort[cb + lane];
            float v = el1[s_reg] + ern;
            v = v > 0.f ? v : 0.2f * v;
            p_reg = __expf(v);
        }
        den += p_reg;
        h2 pp; pp[0] = (_Float16)p_reg; pp[1] = (_Float16)0.f;
        esc[w][lane] = make_int2(s_reg, h2i(pp));
        for (int i = 0; i < m; i += 16) {
            int4 rr = *(const int4*)&esc[w][i + grp * 2];   // 2 records
            int qp = __builtin_amdgcn_perm(rr.y, rr.w, SEL_LO);  // (qA,qB)
            int4 iA = fb[(size_t)rr.x * 8 + c];
            int4 iB = fb[(size_t)rr.z * 8 + c];
            h2 q2 = i2h(qp);
            int pe, po;
            pe = __builtin_amdgcn_perm(iA.x, iB.x, SEL_LO);
            po = __builtin_amdgcn_perm(iA.x, iB.x, SEL_HI);
            acc[0] = __builtin_amdgcn_fdot2(i2h(pe), q2, acc[0], false);
            acc[1] = __builtin_amdgcn_fdot2(i2h(po), q2, acc[1], false);
            pe = __builtin_amdgcn_perm(iA.y, iB.y, SEL_LO);
            po = __builtin_amdgcn_perm(iA.y, iB.y, SEL_HI);
            acc[2] = __builtin_amdgcn_fdot2(i2h(pe), q2, acc[2], false);
            acc[3] = __builtin_amdgcn_fdot2(i2h(po), q2, acc[3], false);
            pe = __builtin_amdgcn_perm(iA.z, iB.z, SEL_LO);
            po = __builtin_amdgcn_perm(iA.z, iB.z, SEL_HI);
            acc[4] = __builtin_amdgcn_fdot2(i2h(pe), q2, acc[4], false);
            acc[5] = __builtin_amdgcn_fdot2(i2h(po), q2, acc[5], false);
            pe = __builtin_amdgcn_perm(iA.w, iB.w, SEL_LO);
            po = __builtin_amdgcn_perm(iA.w, iB.w, SEL_HI);
            acc[6] = __builtin_amdgcn_fdot2(i2h(pe), q2, acc[6], false);
            acc[7] = __builtin_amdgcn_fdot2(i2h(po), q2, acc[7], false);
        }
    }
#pragma unroll
    for (int k = 0; k < 8; ++k) {
        acc[k] += __shfl_down(acc[k], 32);
        acc[k] += __shfl_down(acc[k], 16);
        acc[k] += __shfl_down(acc[k], 8);
    }
#pragma unroll
    for (int o = 32; o > 0; o >>= 1) den += __shfl_down(den, o);
    den = __shfl(den, 0);
    float inv = (end > beg) ? 1.f / den : 0.f;
    float4 ba = ((const float4*)b1)[c * 2];
    float4 bb = ((const float4*)b1)[c * 2 + 1];
    float val[8];
    val[0] = acc[0] * inv + ba.x; val[1] = acc[1] * inv + ba.y;
    val[2] = acc[2] * inv + ba.z; val[3] = acc[3] * inv + ba.w;
    val[4] = acc[4] * inv + bb.x; val[5] = acc[5] * inv + bb.y;
    val[6] = acc[6] * inv + bb.z; val[7] = acc[7] * inv + bb.w;
    float s1 = 0.f, s2 = 0.f;
#pragma unroll
    for (int k = 0; k < 8; ++k) { s1 += val[k]; s2 += val[k] * val[k]; }
#pragma unroll
    for (int o = 1; o < 8; o <<= 1) { s1 += __shfl_xor(s1, o, 8); s2 += __shfl_xor(s2, o, 8); }
    float mu = s1 * (1.f / 64.f);
    float var = s2 * (1.f / 64.f) - mu * mu;
    float rs = rsqrtf(var + 1e-5f);
    if (lane < 8) {
        float4 ga = ((const float4*)g1)[c * 2];
        float4 gb = ((const float4*)g1)[c * 2 + 1];
        float4 ea = ((const float4*)be1)[c * 2];
        float4 eb = ((const float4*)be1)[c * 2 + 1];
        float4 oa, ob;
        oa.x = (val[0] - mu) * rs * ga.x + ea.x;
        oa.y = (val[1] - mu) * rs * ga.y + ea.y;
        oa.z = (val[2] - mu) * rs * ga.z + ea.z;
        oa.w = (val[3] - mu) * rs * ga.w + ea.w;
        ob.x = (val[4] - mu) * rs * gb.x + eb.x;
        ob.y = (val[5] - mu) * rs * gb.y + eb.y;
        ob.z = (val[6] - mu) * rs * gb.z + eb.z;
        ob.w = (val[7] - mu) * rs * gb.w + eb.w;
        float4* orow = (float4*)(out + (size_t)n * 64);
        orow[c * 2] = oa;
        orow[c * 2 + 1] = ob;
    }
}

extern "C" void kernel_launch(void* const* d_in, const int* in_sizes, int n_in,
                              void* d_out, int out_size, void* d_ws, size_t ws_size,
                              hipStream_t stream)
{
    const float* h   = (const float*)d_in[0];
    const float* W0  = (const float*)d_in[1];
    const float* al0 = (const float*)d_in[2];
    const float* ar0 = (const float*)d_in[3];
    const float* b0  = (const float*)d_in[4];
    const float* W1  = (const float*)d_in[5];
    const float* al1 = (const float*)d_in[6];
    const float* ar1 = (const float*)d_in[7];
    const float* b1  = (const float*)d_in[8];
    const float* g0  = (const float*)d_in[9];
    const float* be0 = (const float*)d_in[10];
    const float* g1  = (const float*)d_in[11];
    const float* be1 = (const float*)d_in[12];
    const int*   src = (const int*)d_in[13];
    const int*   dst = (const int*)d_in[14];
    float* out = (float*)d_out;

    char* p = (char*)d_ws;
    auto alloc = [&](size_t bytes) -> char* {
        char* r = p;
        p += (bytes + 255) & ~(size_t)255;
        return r;
    };
    _Float16* feat0 = (_Float16*)alloc((size_t)NN * 128 * sizeof(_Float16));
    float* el0   = (float*)alloc((size_t)NN * 2 * sizeof(float));
    float* er0   = (float*)alloc((size_t)NN * 2 * sizeof(float));
    _Float16* feat1 = (_Float16*)alloc((size_t)NN * 64 * sizeof(_Float16));
    float* el1   = (float*)alloc((size_t)NN * sizeof(float));
    float* er1   = (float*)alloc((size_t)NN * sizeof(float));
    int*   bcntp = (int*)alloc((size_t)NBUCK * 16 * sizeof(int));   // padded: 1/line
    int*   bexc  = (int*)alloc((size_t)NBUCK * sizeof(int));
    int*   off   = (int*)alloc((size_t)(NN + 1) * sizeof(int));
    unsigned int*   staging = (unsigned int*)alloc((size_t)NBUCK * CAP * sizeof(unsigned int));
    unsigned short* ssort   = (unsigned short*)alloc((size_t)EE * sizeof(unsigned short));
    h8*    Wp0   = (h8*)alloc(2048 * sizeof(h8));
    h8*    Wp1   = (h8*)alloc(1024 * sizeof(h8));

    hipMemsetAsync(bcntp, 0, (size_t)NBUCK * 16 * sizeof(int), stream);

    const int NBBIN = (EE + CHUNK - 1) / CHUNK;    // 196
    k_bin<<<NBBIN + 3, 1024, 0, stream>>>(src, dst, bcntp, staging, W0, W1, Wp0, Wp1);
    k_gemm0<<<GB0 + 1, 256, 0, stream>>>(h, Wp0, al0, ar0, feat0, el0, er0,
                                         bcntp, bexc, off);
    k_final<<<NBUCK, 256, 0, stream>>>(staging, bcntp, bexc, off, ssort);
    k_aggemm<<<(NN + 63) / 64, 1024, 0, stream>>>(off, ssort, el0, er0, feat0,
                                                  b0, g0, be0, Wp1, al1, ar1,
                                                  feat1, el1, er1);
    k_agg1<<<NN / 4, 256, 0, stream>>>(off, ssort, el1, er1, feat1, b1, g1, be1, out);
}

// Round 14
// 187.203 us; speedup vs baseline: 2.8552x; 1.1154x over previous
//
#include <hip/hip_runtime.h>
#include <hip/hip_bf16.h>

// GAT 2-layer: N=50000, E=800000, DN=128, D=64, H=2 (layer0). All f32 I/O.
// R14: (1) agg loops use PARALLEL node groups: mean degree is only 16, so
// R13's one-node-per-wave layout left 75% of prologue lanes idle and paid
// 4 serial prologues + 112 reduction shfls per wave. Now aggemm = 16
// lanes/node x 4 nodes/wave (lane owns its 8 cols -> NO acc reduction;
// den/LN butterflies width-16); agg1 = 8 lanes/node x 8 nodes/wave.
// (2) k_bin and gemm0 are independent -> fused into ONE launch (k_work:
// blocks 0..195 bin, 196..977 gemm0 at 1024 thr); W-pack+bcnt-zero move to
// k_init, bucket-scan moves into k_final (self-scan). 5 launches total.
// Rest: dot2 2-edge pairing, LDS counting-sort k_final, MFMA f16 GEMMs,
// u16 ssort, f16 feat0/feat1, x lives in LDS, no-max softmax.

#define NN 50000
#define EE 800000
#define NBUCK 196            // ceil(NN/256)
#define CHUNK 4096           // edges per bin block
#define CAP 8192             // staging slots per bucket (mean 4096, std ~64)
#define NBBIN 196            // bin blocks in k_work

typedef _Float16 h2 __attribute__((ext_vector_type(2)));
typedef _Float16 h4 __attribute__((ext_vector_type(4)));
typedef _Float16 h8 __attribute__((ext_vector_type(8)));
typedef float f32x4 __attribute__((ext_vector_type(4)));

__device__ __forceinline__ h2 i2h(int v) { union { int i; h2 h; } u; u.i = v; return u.h; }
__device__ __forceinline__ int h2i(h2 v) { union { h2 h; int i; } u; u.h = v; return u.i; }

// selector constants for v_perm_b32 (pool: bytes0-3 = S1, bytes4-7 = S0)
#define SEL_LO 0x01000504u   // result = (S0.lo16, S1.lo16)
#define SEL_HI 0x03020706u   // result = (S0.hi16, S1.hi16)

// ---- init: pack W0/W1 into B-fragment order + zero bcntp ------------------
// Wp[t][kk][lane][j] = W[(kk*32 + (lane>>4)*8 + j)][t*16 + (lane&15)]  (f16)
__global__ __launch_bounds__(1024) void k_init(
    const float* __restrict__ W0, const float* __restrict__ W1,
    h8* __restrict__ Wp0, h8* __restrict__ Wp1, int* __restrict__ bcntp)
{
    int tid = threadIdx.x;
    int b = blockIdx.x;
    if (b < 2) {
        int idx = b * 1024 + tid;    // 0..2047
        int lane = idx & 63, kk = (idx >> 6) & 3, tt = idx >> 8;
        int q = lane >> 4, c = lane & 15;
        h8 v;
#pragma unroll
        for (int j = 0; j < 8; ++j)
            v[j] = (_Float16)W0[(kk * 32 + q * 8 + j) * 128 + tt * 16 + c];
        Wp0[idx] = v;
    } else if (b == 2) {
        int idx = tid;               // 0..1023
        int lane = idx & 63, kk = (idx >> 6) & 3, tt = idx >> 8;
        int q = lane >> 4, c = lane & 15;
        h8 v;
#pragma unroll
        for (int j = 0; j < 8; ++j)
            v[j] = (_Float16)W1[(kk * 32 + q * 8 + j) * 64 + tt * 16 + c];
        Wp1[idx] = v;
    } else {
        for (int i = tid; i < NBUCK * 16; i += 1024) bcntp[i] = 0;
    }
}

// ---- k_work: blocks 0..195 = edge binning; 196..977 = layer-0 GEMM -------
#define HS_STRIDE 136   // 128 + 8 f16 pad
#define D0_STRIDE 132   // 128 + 4 f32 pad
__global__ __launch_bounds__(1024) void k_work(
    const int* __restrict__ src, const int* __restrict__ dst,
    int* __restrict__ bcntp, unsigned int* __restrict__ staging,
    const float* __restrict__ h, const h8* __restrict__ Wp0,
    const float* __restrict__ al0, const float* __restrict__ ar0,
    _Float16* __restrict__ feat0, float* __restrict__ el0, float* __restrict__ er0)
{
    int tid = threadIdx.x;
    __shared__ char smem[64 * D0_STRIDE * 4];      // union: hs (f16) / ds2 (f32)
    __shared__ int hist[NBUCK];
    __shared__ int rnk[NBUCK];
    __shared__ int gbase[NBUCK];
    if (blockIdx.x < NBBIN) {
        // ---- binning (as R10/R13, 1024 thr, int4 loads) ----
        int base = blockIdx.x * CHUNK;
        int m = EE - base; if (m > CHUNK) m = CHUNK;   // multiple of 4
        if (tid < NBUCK) { hist[tid] = 0; rnk[tid] = 0; }
        __syncthreads();
        int e0 = tid * 4;
        bool act = e0 < m;
        int4 d4 = {0, 0, 0, 0}, s4 = {0, 0, 0, 0};
        if (act) {
            d4 = ((const int4*)(dst + base))[tid];
            s4 = ((const int4*)(src + base))[tid];
            atomicAdd(&hist[d4.x >> 8], 1);
            atomicAdd(&hist[d4.y >> 8], 1);
            atomicAdd(&hist[d4.z >> 8], 1);
            atomicAdd(&hist[d4.w >> 8], 1);
        }
        __syncthreads();
        if (tid < NBUCK && hist[tid])
            gbase[tid] = atomicAdd(&bcntp[tid * 16], hist[tid]);
        __syncthreads();
        if (act) {
            int d[4] = {d4.x, d4.y, d4.z, d4.w};
            int s[4] = {s4.x, s4.y, s4.z, s4.w};
#pragma unroll
            for (int k = 0; k < 4; ++k) {
                int b = d[k] >> 8;
                int r = atomicAdd(&rnk[b], 1);
                int slot = gbase[b] + r;
                if (slot < CAP)    // statistically never; memory-safety clamp
                    staging[(size_t)b * CAP + slot] =
                        ((unsigned)(d[k] & 255) << 16) | (unsigned)s[k];
            }
        }
        return;
    }
    // ---- gemm0: 64 nodes/block, 1024 thr (16 waves: 4 rowgrp x 4 tilegrp) --
    _Float16* hs = (_Float16*)smem;
    float* ds2 = (float*)smem;
    int n0 = (blockIdx.x - NBBIN) * 64;
#pragma unroll
    for (int r = 0; r < 2; ++r) {
        int f = tid + 1024 * r;
        int node = f >> 5, kc = f & 31;
        int n = n0 + node;
        float4 v = {0.f, 0.f, 0.f, 0.f};
        if (n < NN) v = ((const float4*)h)[(size_t)n * 32 + kc];
        h4 hv; hv[0] = (_Float16)v.x; hv[1] = (_Float16)v.y;
        hv[2] = (_Float16)v.z; hv[3] = (_Float16)v.w;
        *(h4*)&hs[node * HS_STRIDE + kc * 4] = hv;
    }
    __syncthreads();
    int w16 = tid >> 6, lane = tid & 63;
    int rg = w16 & 3, tt = w16 >> 2;
    int m = lane & 15, q = lane >> 4;
    h8 aF[4];
#pragma unroll
    for (int kk = 0; kk < 4; ++kk)
        aF[kk] = *(const h8*)&hs[(rg * 16 + m) * HS_STRIDE + kk * 32 + q * 8];
    __syncthreads();                                // hs dead; reuse as ds2
#pragma unroll
    for (int t2 = 0; t2 < 2; ++t2) {
        int t = tt * 2 + t2;
        f32x4 acc = {0.f, 0.f, 0.f, 0.f};
#pragma unroll
        for (int kk = 0; kk < 4; ++kk) {
            h8 bF = Wp0[(t * 4 + kk) * 64 + lane];
            acc = __builtin_amdgcn_mfma_f32_16x16x32_f16(aF[kk], bF, acc, 0, 0, 0);
        }
#pragma unroll
        for (int r = 0; r < 4; ++r)
            ds2[(rg * 16 + q * 4 + r) * D0_STRIDE + t * 16 + m] = acc[r];
    }
    __syncthreads();
    {   // feat0 stores: 1024 h8-groups, 1 per thread
        int node = tid >> 4, c8 = tid & 15;
        int n = n0 + node;
        if (n < NN) {
            float4 a = *(const float4*)&ds2[node * D0_STRIDE + c8 * 8];
            float4 b = *(const float4*)&ds2[node * D0_STRIDE + c8 * 8 + 4];
            h8 v;
            v[0] = (_Float16)a.x; v[1] = (_Float16)a.y; v[2] = (_Float16)a.z; v[3] = (_Float16)a.w;
            v[4] = (_Float16)b.x; v[5] = (_Float16)b.y; v[6] = (_Float16)b.z; v[7] = (_Float16)b.w;
            ((h8*)feat0)[(size_t)n * 16 + c8] = v;
        }
    }
    if (tid < 256) {   // el/er: (node, qq)
        int node = tid >> 2, qq = tid & 3;
        int n = n0 + node;
        float pl = 0.f, pr = 0.f;
#pragma unroll
        for (int i = 0; i < 8; ++i) {
            float4 v = *(const float4*)&ds2[node * D0_STRIDE + qq * 32 + i * 4];
            float4 a = ((const float4*)al0)[qq * 8 + i];
            float4 r = ((const float4*)ar0)[qq * 8 + i];
            pl += v.x * a.x + v.y * a.y + v.z * a.z + v.w * a.w;
            pr += v.x * r.x + v.y * r.y + v.z * r.z + v.w * r.w;
        }
        pl += __shfl_xor(pl, 1, 4); pr += __shfl_xor(pr, 1, 4);
        if (n < NN) {
            if (qq == 0) { el0[n * 2] = pl;     er0[n * 2] = pr; }
            if (qq == 2) { el0[n * 2 + 1] = pl; er0[n * 2 + 1] = pr; }
        }
    }
}

// ---- k_final: self-scan bucket counts; LDS counting sort; off + ssort -----
__global__ __launch_bounds__(256) void k_final(
    const unsigned int* __restrict__ staging, const int* __restrict__ bcntp,
    int* __restrict__ off, unsigned short* __restrict__ ssort)
{
    int b = blockIdx.x;
    int tid = threadIdx.x;
    int cnt = bcntp[b * 16]; if (cnt > CAP) cnt = CAP;
    size_t base = (size_t)b * CAP;
    __shared__ unsigned short buf[CAP];
    __shared__ int hist[256];
    __shared__ int sc[256];
    // self prefix-scan of bucket counts -> lo
    int bv = (tid < NBUCK) ? bcntp[tid * 16] : 0;
    sc[tid] = bv;
    __syncthreads();
    for (int o = 1; o < 256; o <<= 1) {
        int u = (tid >= o) ? sc[tid - o] : 0;
        __syncthreads();
        sc[tid] += u;
        __syncthreads();
    }
    int lo = (b > 0) ? sc[b - 1] : 0;
    if (b == 0 && tid == 0) off[0] = 0;
    __syncthreads();
    // per-node histogram
    hist[tid] = 0;
    __syncthreads();
    for (int i = tid; i < cnt; i += 256)
        atomicAdd(&hist[staging[base + i] >> 16], 1);
    __syncthreads();
    int hv = hist[tid];
    sc[tid] = hv;
    __syncthreads();
    for (int o = 1; o < 256; o <<= 1) {
        int u = (tid >= o) ? sc[tid - o] : 0;
        __syncthreads();
        sc[tid] += u;
        __syncthreads();
    }
    int nlo = b << 8;
    int nrem = NN - nlo; if (nrem > 256) nrem = 256;
    if (tid < nrem) off[nlo + tid + 1] = lo + sc[tid];
    hist[tid] = sc[tid] - hv;          // exclusive offset -> LDS cursor
    __syncthreads();
    for (int i = tid; i < cnt; i += 256) {
        unsigned rec = staging[base + i];
        int r = atomicAdd(&hist[rec >> 16], 1);
        buf[r] = (unsigned short)(rec & 0xFFFFu);
    }
    __syncthreads();
    for (int i = tid; i < cnt; i += 256)
        ssort[lo + i] = buf[i];
}

// ---- FUSED layer-0 agg (+bias+relu+LN) -> LDS x -> layer-1 GEMM (MFMA) ----
// 1024 thr, 64 nodes/block. Agg: 16 lanes/node x 4 nodes/wave (parallel);
// lane owns 8 cols -> no acc reduction. dot2 2-edge pairing via LDS records.
#define D1_STRIDE 68    // 64 + 4 f32 pad
__global__ __launch_bounds__(1024) void k_aggemm(
    const int* __restrict__ off, const unsigned short* __restrict__ ssort,
    const float* __restrict__ el0, const float* __restrict__ er0,
    const _Float16* __restrict__ feat0, const float* __restrict__ b0,
    const float* __restrict__ g0, const float* __restrict__ be0,
    const h8* __restrict__ Wp1, const float* __restrict__ al1,
    const float* __restrict__ ar1,
    _Float16* __restrict__ feat1, float* __restrict__ el1, float* __restrict__ er1)
{
    int tid = threadIdx.x;
    int w16 = tid >> 6, lane = tid & 63;
    int g = lane >> 4, c = lane & 15;
    int n0 = blockIdx.x * 64;
    __shared__ char smem[64 * HS_STRIDE * 2 > 64 * D1_STRIDE * 4
                         ? 64 * HS_STRIDE * 2 : 64 * D1_STRIDE * 4];
    __shared__ int2 esc[16][4][18];             // [wave][group][16 recs + pad]
    _Float16* xs = (_Float16*)smem;
    float* ds2 = (float*)smem;
    const int4* fb = (const int4*)feat0;        // row = 16 int4 chunks
    unsigned qsel = (c < 8) ? SEL_LO : SEL_HI;  // head-select for q pair
    // ---- phase 1: 4 nodes per wave IN PARALLEL (16-lane groups) ----
    {
        int nl = w16 * 4 + g;
        int n = n0 + nl;
        if (n < NN) {
            int beg = off[n], end = off[n + 1];
            float2 ern2 = ((const float2*)er0)[n];
            float acc[8] = {};
            float den0 = 0.f, den1 = 0.f;
            for (int cb = beg; cb < end; cb += 16) {
                int m = end - cb; if (m > 16) m = 16;
                int s_reg = 0; float p0 = 0.f, p1 = 0.f;
                if (c < m) {
                    s_reg = ssort[cb + c];
                    float2 el2 = ((const float2*)el0)[s_reg];
                    float v0 = el2.x + ern2.x; v0 = v0 > 0.f ? v0 : 0.2f * v0;
                    float v1 = el2.y + ern2.y; v1 = v1 > 0.f ? v1 : 0.2f * v1;
                    p0 = __expf(v0); p1 = __expf(v1);
                }
                den0 += p0; den1 += p1;
                h2 pp; pp[0] = (_Float16)p0; pp[1] = (_Float16)p1;
                esc[w16][g][c] = make_int2(s_reg, h2i(pp));
                for (int ii = 0; ii < m; ii += 2) {
                    int4 rr = *(const int4*)&esc[w16][g][ii]; // 2 recs, bcast
                    int qp = __builtin_amdgcn_perm(rr.y, rr.w, qsel);
                    int4 iA = fb[(size_t)rr.x * 16 + c];
                    int4 iB = fb[(size_t)rr.z * 16 + c];
                    h2 q2 = i2h(qp);
                    int pe, po;
                    pe = __builtin_amdgcn_perm(iA.x, iB.x, SEL_LO);
                    po = __builtin_amdgcn_perm(iA.x, iB.x, SEL_HI);
                    acc[0] = __builtin_amdgcn_fdot2(i2h(pe), q2, acc[0], false);
                    acc[1] = __builtin_amdgcn_fdot2(i2h(po), q2, acc[1], false);
                    pe = __builtin_amdgcn_perm(iA.y, iB.y, SEL_LO);
                    po = __builtin_amdgcn_perm(iA.y, iB.y, SEL_HI);
                    acc[2] = __builtin_amdgcn_fdot2(i2h(pe), q2, acc[2], false);
                    acc[3] = __builtin_amdgcn_fdot2(i2h(po), q2, acc[3], false);
                    pe = __builtin_amdgcn_perm(iA.z, iB.z, SEL_LO);
                    po = __builtin_amdgcn_perm(iA.z, iB.z, SEL_HI);
                    acc[4] = __builtin_amdgcn_fdot2(i2h(pe), q2, acc[4], false);
                    acc[5] = __builtin_amdgcn_fdot2(i2h(po), q2, acc[5], false);
                    pe = __builtin_amdgcn_perm(iA.w, iB.w, SEL_LO);
                    po = __builtin_amdgcn_perm(iA.w, iB.w, SEL_HI);
                    acc[6] = __builtin_amdgcn_fdot2(i2h(pe), q2, acc[6], false);
                    acc[7] = __builtin_amdgcn_fdot2(i2h(po), q2, acc[7], false);
                }
            }
            // den butterflies within the 16-lane group
#pragma unroll
            for (int o = 1; o < 16; o <<= 1) {
                den0 += __shfl_xor(den0, o, 16);
                den1 += __shfl_xor(den1, o, 16);
            }
            float den = (c < 8) ? den0 : den1;
            float inv = (end > beg) ? 1.f / den : 0.f;
            float4 ba = ((const float4*)b0)[c * 2];
            float4 bb = ((const float4*)b0)[c * 2 + 1];
            float val[8];
            val[0] = fmaxf(acc[0] * inv + ba.x, 0.f);
            val[1] = fmaxf(acc[1] * inv + ba.y, 0.f);
            val[2] = fmaxf(acc[2] * inv + ba.z, 0.f);
            val[3] = fmaxf(acc[3] * inv + ba.w, 0.f);
            val[4] = fmaxf(acc[4] * inv + bb.x, 0.f);
            val[5] = fmaxf(acc[5] * inv + bb.y, 0.f);
            val[6] = fmaxf(acc[6] * inv + bb.z, 0.f);
            val[7] = fmaxf(acc[7] * inv + bb.w, 0.f);
            float s1 = 0.f, s2 = 0.f;
#pragma unroll
            for (int k = 0; k < 8; ++k) { s1 += val[k]; s2 += val[k] * val[k]; }
#pragma unroll
            for (int o = 1; o < 16; o <<= 1) { s1 += __shfl_xor(s1, o, 16); s2 += __shfl_xor(s2, o, 16); }
            float mu = s1 * (1.f / 128.f);
            float var = s2 * (1.f / 128.f) - mu * mu;
            float rs = rsqrtf(var + 1e-5f);
            float4 ga = ((const float4*)g0)[c * 2];
            float4 gb = ((const float4*)g0)[c * 2 + 1];
            float4 ea = ((const float4*)be0)[c * 2];
            float4 eb = ((const float4*)be0)[c * 2 + 1];
            h8 xv;
            xv[0] = (_Float16)((val[0] - mu) * rs * ga.x + ea.x);
            xv[1] = (_Float16)((val[1] - mu) * rs * ga.y + ea.y);
            xv[2] = (_Float16)((val[2] - mu) * rs * ga.z + ea.z);
            xv[3] = (_Float16)((val[3] - mu) * rs * ga.w + ea.w);
            xv[4] = (_Float16)((val[4] - mu) * rs * gb.x + eb.x);
            xv[5] = (_Float16)((val[5] - mu) * rs * gb.y + eb.y);
            xv[6] = (_Float16)((val[6] - mu) * rs * gb.z + eb.z);
            xv[7] = (_Float16)((val[7] - mu) * rs * gb.w + eb.w);
            *(h8*)&xs[nl * HS_STRIDE + c * 8] = xv;
        } else {
            h8 z = {};
            *(h8*)&xs[nl * HS_STRIDE + c * 8] = z;
        }
    }
    __syncthreads();
    // ---- phase 2: gemm1 (MFMA). wave = (rg, t). ----
    int rg = w16 & 3, t = w16 >> 2;
    int m = lane & 15, q = lane >> 4;
    h8 aF[4];
#pragma unroll
    for (int kk = 0; kk < 4; ++kk)
        aF[kk] = *(const h8*)&xs[(rg * 16 + m) * HS_STRIDE + kk * 32 + q * 8];
    __syncthreads();                                // xs dead; reuse as ds2
    f32x4 acc1 = {0.f, 0.f, 0.f, 0.f};
#pragma unroll
    for (int kk = 0; kk < 4; ++kk) {
        h8 bF = Wp1[(t * 4 + kk) * 64 + lane];
        acc1 = __builtin_amdgcn_mfma_f32_16x16x32_f16(aF[kk], bF, acc1, 0, 0, 0);
    }
#pragma unroll
    for (int r = 0; r < 4; ++r)
        ds2[(rg * 16 + q * 4 + r) * D1_STRIDE + t * 16 + m] = acc1[r];
    __syncthreads();
    if (tid < 512) {
        int node = tid >> 3, c8 = tid & 7;
        int n = n0 + node;
        if (n < NN) {
            float4 a = *(const float4*)&ds2[node * D1_STRIDE + c8 * 8];
            float4 b = *(const float4*)&ds2[node * D1_STRIDE + c8 * 8 + 4];
            h8 v;
            v[0] = (_Float16)a.x; v[1] = (_Float16)a.y; v[2] = (_Float16)a.z; v[3] = (_Float16)a.w;
            v[4] = (_Float16)b.x; v[5] = (_Float16)b.y; v[6] = (_Float16)b.z; v[7] = (_Float16)b.w;
            ((h8*)feat1)[(size_t)n * 8 + c8] = v;
        }
    } else if (tid < 768) {
        int t2 = tid - 512;
        int node = t2 >> 2, qq = t2 & 3;
        int n = n0 + node;
        float pl = 0.f, pr = 0.f;
#pragma unroll
        for (int i = 0; i < 4; ++i) {
            float4 v = *(const float4*)&ds2[node * D1_STRIDE + qq * 16 + i * 4];
            float4 a = ((const float4*)al1)[qq * 4 + i];
            float4 r = ((const float4*)ar1)[qq * 4 + i];
            pl += v.x * a.x + v.y * a.y + v.z * a.z + v.w * a.w;
            pr += v.x * r.x + v.y * r.y + v.z * r.z + v.w * r.w;
        }
        pl += __shfl_xor(pl, 1, 4); pr += __shfl_xor(pr, 1, 4);
        pl += __shfl_xor(pl, 2, 4); pr += __shfl_xor(pr, 2, 4);
        if (qq == 0 && n < NN) { el1[n] = pl; er1[n] = pr; }
    }
}

// ------- layer-1 agg + bias + LN -> out (f32). 8 lanes/node x 8/wave. ------
__global__ __launch_bounds__(256) void k_agg1(
    const int* __restrict__ off, const unsigned short* __restrict__ ssort,
    const float* __restrict__ el1, const float* __restrict__ er1,
    const _Float16* __restrict__ feat1, const float* __restrict__ b1,
    const float* __restrict__ g1, const float* __restrict__ be1,
    float* __restrict__ out)
{
    int w = threadIdx.x >> 6, lane = threadIdx.x & 63;
    int g = lane >> 3, c = lane & 7;
    int n = blockIdx.x * 32 + w * 8 + g;
    __shared__ int2 esc[4][8][10];              // [wave][group][8 recs + pad]
    const int4* fb = (const int4*)feat1;        // row = 8 int4
    if (n >= NN) return;
    int beg = off[n], end = off[n + 1];
    float ern = er1[n];
    float acc[8] = {};
    float den = 0.f;
    for (int cb = beg; cb < end; cb += 8) {
        int m = end - cb; if (m > 8) m = 8;
        int s_reg = 0; float p_reg = 0.f;
        if (c < m) {
            s_reg = ssort[cb + c];
            float v = el1[s_reg] + ern;
            v = v > 0.f ? v : 0.2f * v;
            p_reg = __expf(v);
        }
        den += p_reg;
        h2 pp; pp[0] = (_Float16)p_reg; pp[1] = (_Float16)0.f;
        esc[w][g][c] = make_int2(s_reg, h2i(pp));
        for (int ii = 0; ii < m; ii += 2) {
            int4 rr = *(const int4*)&esc[w][g][ii];   // 2 records, bcast
            int qp = __builtin_amdgcn_perm(rr.y, rr.w, SEL_LO);
            int4 iA = fb[(size_t)rr.x * 8 + c];
            int4 iB = fb[(size_t)rr.z * 8 + c];
            h2 q2 = i2h(qp);
            int pe, po;
            pe = __builtin_amdgcn_perm(iA.x, iB.x, SEL_LO);
            po = __builtin_amdgcn_perm(iA.x, iB.x, SEL_HI);
            acc[0] = __builtin_amdgcn_fdot2(i2h(pe), q2, acc[0], false);
            acc[1] = __builtin_amdgcn_fdot2(i2h(po), q2, acc[1], false);
            pe = __builtin_amdgcn_perm(iA.y, iB.y, SEL_LO);
            po = __builtin_amdgcn_perm(iA.y, iB.y, SEL_HI);
            acc[2] = __builtin_amdgcn_fdot2(i2h(pe), q2, acc[2], false);
            acc[3] = __builtin_amdgcn_fdot2(i2h(po), q2, acc[3], false);
            pe = __builtin_amdgcn_perm(iA.z, iB.z, SEL_LO);
            po = __builtin_amdgcn_perm(iA.z, iB.z, SEL_HI);
            acc[4] = __builtin_amdgcn_fdot2(i2h(pe), q2, acc[4], false);
            acc[5] = __builtin_amdgcn_fdot2(i2h(po), q2, acc[5], false);
            pe = __builtin_amdgcn_perm(iA.w, iB.w, SEL_LO);
            po = __builtin_amdgcn_perm(iA.w, iB.w, SEL_HI);
            acc[6] = __builtin_amdgcn_fdot2(i2h(pe), q2, acc[6], false);
            acc[7] = __builtin_amdgcn_fdot2(i2h(po), q2, acc[7], false);
        }
    }
#pragma unroll
    for (int o = 1; o < 8; o <<= 1) den += __shfl_xor(den, o, 8);
    float inv = (end > beg) ? 1.f / den : 0.f;
    float4 ba = ((const float4*)b1)[c * 2];
    float4 bb = ((const float4*)b1)[c * 2 + 1];
    float val[8];
    val[0] = acc[0] * inv + ba.x; val[1] = acc[1] * inv + ba.y;
    val[2] = acc[2] * inv + ba.z; val[3] = acc[3] * inv + ba.w;
    val[4] = acc[4] * inv + bb.x; val[5] = acc[5] * inv + bb.y;
    val[6] = acc[6] * inv + bb.z; val[7] = acc[7] * inv + bb.w;
    float s1 = 0.f, s2 = 0.f;
#pragma unroll
    for (int k = 0; k < 8; ++k) { s1 += val[k]; s2 += val[k] * val[k]; }
#pragma unroll
    for (int o = 1; o < 8; o <<= 1) { s1 += __shfl_xor(s1, o, 8); s2 += __shfl_xor(s2, o, 8); }
    float mu = s1 * (1.f / 64.f);
    float var = s2 * (1.f / 64.f) - mu * mu;
    float rs = rsqrtf(var + 1e-5f);
    float4 ga = ((const float4*)g1)[c * 2];
    float4 gb = ((const float4*)g1)[c * 2 + 1];
    float4 ea = ((const float4*)be1)[c * 2];
    float4 eb = ((const float4*)be1)[c * 2 + 1];
    float4 oa, ob;
    oa.x = (val[0] - mu) * rs * ga.x + ea.x;
    oa.y = (val[1] - mu) * rs * ga.y + ea.y;
    oa.z = (val[2] - mu) * rs * ga.z + ea.z;
    oa.w = (val[3] - mu) * rs * ga.w + ea.w;
    ob.x = (val[4] - mu) * rs * gb.x + eb.x;
    ob.y = (val[5] - mu) * rs * gb.y + eb.y;
    ob.z = (val[6] - mu) * rs * gb.z + eb.z;
    ob.w = (val[7] - mu) * rs * gb.w + eb.w;
    float4* orow = (float4*)(out + (size_t)n * 64);
    orow[c * 2] = oa;
    orow[c * 2 + 1] = ob;
}

extern "C" void kernel_launch(void* const* d_in, const int* in_sizes, int n_in,
                              void* d_out, int out_size, void* d_ws, size_t ws_size,
                              hipStream_t stream)
{
    const float* h   = (const float*)d_in[0];
    const float* W0  = (const float*)d_in[1];
    const float* al0 = (const float*)d_in[2];
    const float* ar0 = (const float*)d_in[3];
    const float* b0  = (const float*)d_in[4];
    const float* W1  = (const float*)d_in[5];
    const float* al1 = (const float*)d_in[6];
    const float* ar1 = (const float*)d_in[7];
    const float* b1  = (const float*)d_in[8];
    const float* g0  = (const float*)d_in[9];
    const float* be0 = (const float*)d_in[10];
    const float* g1  = (const float*)d_in[11];
    const float* be1 = (const float*)d_in[12];
    const int*   src = (const int*)d_in[13];
    const int*   dst = (const int*)d_in[14];
    float* out = (float*)d_out;

    char* p = (char*)d_ws;
    auto alloc = [&](size_t bytes) -> char* {
        char* r = p;
        p += (bytes + 255) & ~(size_t)255;
        return r;
    };
    _Float16* feat0 = (_Float16*)alloc((size_t)NN * 128 * sizeof(_Float16));
    float* el0   = (float*)alloc((size_t)NN * 2 * sizeof(float));
    float* er0   = (float*)alloc((size_t)NN * 2 * sizeof(float));
    _Float16* feat1 = (_Float16*)alloc((size_t)NN * 64 * sizeof(_Float16));
    float* el1   = (float*)alloc((size_t)NN * sizeof(float));
    float* er1   = (float*)alloc((size_t)NN * sizeof(float));
    int*   bcntp = (int*)alloc((size_t)NBUCK * 16 * sizeof(int));   // padded: 1/line
    int*   off   = (int*)alloc((size_t)(NN + 1) * sizeof(int));
    unsigned int*   staging = (unsigned int*)alloc((size_t)NBUCK * CAP * sizeof(unsigned int));
    unsigned short* ssort   = (unsigned short*)alloc((size_t)EE * sizeof(unsigned short));
    h8*    Wp0   = (h8*)alloc(2048 * sizeof(h8));
    h8*    Wp1   = (h8*)alloc(1024 * sizeof(h8));

    const int GB0 = (NN + 63) / 64;   // 782 gemm0 blocks
    k_init<<<4, 1024, 0, stream>>>(W0, W1, Wp0, Wp1, bcntp);
    k_work<<<NBBIN + GB0, 1024, 0, stream>>>(src, dst, bcntp, staging,
                                             h, Wp0, al0, ar0, feat0, el0, er0);
    k_final<<<NBUCK, 256, 0, stream>>>(staging, bcntp, off, ssort);
    k_aggemm<<<(NN + 63) / 64, 1024, 0, stream>>>(off, ssort, el0, er0, feat0,
                                                  b0, g0, be0, Wp1, al1, ar1,
                                                  feat1, el1, er1);
    k_agg1<<<(NN + 31) / 32, 256, 0, stream>>>(off, ssort, el1, er1, feat1,
                                               b1, g1, be1, out);
}